// Round 10
// baseline (36356.921 us; speedup 1.0000x reference)
//
#include <hip/hip_runtime.h>
#include <math.h>

#define T_Q    2000
#define N_M    100000
#define D_DIM  1024
#define QTILES 16
#define NTILES 782          // ceil(100000/128)
#define MPAD   (NTILES * 128)   // 100096 zero-padded fp16 M rows
#define BK     32
#define KSTEPS (D_DIM / BK) // 32
#define LDH    40           // middle-path A/B LDS row stride in halves (80 B)
#define SSW    72           // score tile row stride in halves (144 B)
#define NC     16           // rescore candidate superset per query
#define QPAD   2048

typedef _Float16 f16x8 __attribute__((ext_vector_type(8)));
typedef _Float16 f16x4 __attribute__((ext_vector_type(4)));
typedef float    f32x4 __attribute__((ext_vector_type(4)));
typedef unsigned int u32;

struct __align__(8) Cand { float v; int i; };
static_assert(sizeof(Cand) == 8, "cand size");

__device__ __forceinline__ bool better(float av, int ai, float bv, int bi) {
    return (av > bv) || (av == bv && ai < bi);
}

__device__ __forceinline__ f32x4 zero4() {
    f32x4 z; z[0] = 0.f; z[1] = 0.f; z[2] = 0.f; z[3] = 0.f; return z;
}

// async global->LDS, 16 B per lane (dest pattern: wave-uniform base + lane*16)
__device__ __forceinline__ void gload16(const _Float16* g, _Float16* l) {
    const __attribute__((address_space(1))) u32* gp =
        (const __attribute__((address_space(1))) u32*)g;
    __attribute__((address_space(3))) u32* lp =
        (__attribute__((address_space(3))) u32*)l;
    __builtin_amdgcn_global_load_lds(gp, lp, 16, 0, 0);
}

// ---------------------------------------------------------------------------
// Kernel Q: convert query matrix to fp16 once (rows >= T_Q zero-filled).
// ---------------------------------------------------------------------------
__global__ __launch_bounds__(256)
void knn_qcvt(const float* __restrict__ Qm, _Float16* __restrict__ Qh)
{
    const size_t base = (size_t)blockIdx.x * 2048 + (size_t)threadIdx.x * 8;
    const int row = (int)(base >> 10);
    f16x8 h;
    if (row < T_Q) {
        f32x4 a = *(const f32x4*)(Qm + base);
        f32x4 b = *(const f32x4*)(Qm + base + 4);
#pragma unroll
        for (int j = 0; j < 4; ++j) { h[j] = (_Float16)a[j]; h[4 + j] = (_Float16)b[j]; }
    } else {
#pragma unroll
        for (int j = 0; j < 8; ++j) h[j] = (_Float16)0.f;
    }
    *(f16x8*)(Qh + base) = h;
}

// ---------------------------------------------------------------------------
// Kernel M: fused norm + prescale + fp16 convert + zero-pad of M.
// ---------------------------------------------------------------------------
__global__ __launch_bounds__(256)
void knn_mcvt(const float* __restrict__ Mm, _Float16* __restrict__ Mh)
{
    const int wid  = threadIdx.x >> 6;
    const int lane = threadIdx.x & 63;
    const int r    = blockIdx.x * 4 + wid;   // grid covers MPAD rows
    f16x8 h0, h1;
    if (r < N_M) {
        const f32x4* mp = (const f32x4*)(Mm + (size_t)r * D_DIM) + lane * 4;
        f32x4 v0 = mp[0], v1 = mp[1], v2 = mp[2], v3 = mp[3];
        float ss = 0.f;
#pragma unroll
        for (int u = 0; u < 4; ++u)
            ss += v0[u] * v0[u] + v1[u] * v1[u] + v2[u] * v2[u] + v3[u] * v3[u];
#pragma unroll
        for (int off = 1; off <= 32; off <<= 1) ss += __shfl_xor(ss, off, 64);
        const float inv = ss > 0.f ? rsqrtf(ss) : 0.f;
#pragma unroll
        for (int u = 0; u < 4; ++u) {
            h0[u]     = (_Float16)(v0[u] * inv);
            h0[4 + u] = (_Float16)(v1[u] * inv);
            h1[u]     = (_Float16)(v2[u] * inv);
            h1[4 + u] = (_Float16)(v3[u] * inv);
        }
    } else {
#pragma unroll
        for (int j = 0; j < 8; ++j) { h0[j] = (_Float16)0.f; h1[j] = (_Float16)0.f; }
    }
    _Float16* dst = Mh + (size_t)r * D_DIM + lane * 16;
    *(f16x8*)dst       = h0;
    *(f16x8*)(dst + 8) = h1;
}

// ---------------------------------------------------------------------------
// Kernel 1 (main): fp16 MFMA scores via global_load_lds, XCD-grouped sups
// (a sup's 16 qtile-sharers land on ONE XCD -> M panel fetched once per L2).
// Requires nsuper % 8 == 0. Select epilogue proven (absmax 0.0).
// ---------------------------------------------------------------------------
__global__ __launch_bounds__(256)
void knn_gemm_select_h(const _Float16* __restrict__ Qh,
                       const _Float16* __restrict__ Mh,
                       Cand* __restrict__ cand, int tpbn, int nsuper)
{
    __shared__ _Float16 As[128][32];    //  8192 B
    __shared__ _Float16 Bs[128][32];    //  8192 B
    __shared__ _Float16 Ss[128][SSW];   // 18432 B  (total 34816 B)

    // XCD-aware mapping: hardware assigns bid%8 -> XCD (round-robin).
    const int bid   = blockIdx.x;
    const int c8    = bid & 7;          // XCD slot
    const int j     = bid >> 3;
    const int qtile = j & 15;           // 16 sharers of a sup are 8 bids apart
    const int sup   = c8 + 8 * (j >> 4);

    const int nt0 = sup * tpbn;
    int nt1 = nt0 + tpbn;
    if (nt1 > NTILES) nt1 = NTILES;

    const int tid  = threadIdx.x;
    const int lane = tid & 63;
    const int wid  = tid >> 6;
    const int wr   = wid >> 1;
    const int wc   = wid & 1;
    const int l15  = lane & 15;
    const int lg   = lane >> 4;

    const int arow = tid >> 2;          // 0..63
    const int acol = (tid & 3) * 8;     // halves

    _Float16* Adst0 = &As[arow][acol];
    _Float16* Adst1 = &As[64 + arow][acol];
    _Float16* Bdst0 = &Bs[arow][acol];
    _Float16* Bdst1 = &Bs[64 + arow][acol];

    const _Float16* Bb = Qh + ((size_t)(qtile * 128 + arow) << 10) + acol;

    float rv[NC]; int ri[NC];
#pragma unroll
    for (int k = 0; k < NC; ++k) { rv[k] = -INFINITY; ri[k] = 0; }

#pragma unroll 1
    for (int ntile = nt0; ntile < nt1; ++ntile) {
        const _Float16* Ab = Mh + ((size_t)(ntile * 128 + arow) << 10) + acol;

        f32x4 acc[4][4];
#pragma unroll
        for (int i = 0; i < 4; ++i)
#pragma unroll
            for (int jj = 0; jj < 4; ++jj) acc[i][jj] = zero4();

        for (int t = 0; t < KSTEPS; ++t) {   // compiler free to unroll/schedule
            const int k0 = t * BK;
            gload16(Ab + k0, Adst0);
            gload16(Ab + k0 + (64 << 10), Adst1);
            gload16(Bb + k0, Bdst0);
            gload16(Bb + k0 + (64 << 10), Bdst1);

            __syncthreads();

            f16x8 af[4], bf[4];
#pragma unroll
            for (int f = 0; f < 4; ++f) {
                af[f] = *(const f16x8*)&As[wr * 64 + f * 16 + l15][lg * 8];
                bf[f] = *(const f16x8*)&Bs[wc * 64 + f * 16 + l15][lg * 8];
            }
#pragma unroll
            for (int i = 0; i < 4; ++i)
#pragma unroll
                for (int jj = 0; jj < 4; ++jj)
                    acc[i][jj] = __builtin_amdgcn_mfma_f32_16x16x32_f16(
                        af[i], bf[jj], acc[i][jj], 0, 0, 0);

            __syncthreads();
        }

        // two half-tile dump+scan rounds
#pragma unroll 1
        for (int h = 0; h < 2; ++h) {
            __syncthreads();
            if (wr == h) {
#pragma unroll
                for (int fr = 0; fr < 4; ++fr)
#pragma unroll
                    for (int fc = 0; fc < 4; ++fc) {
                        f16x4 v;
#pragma unroll
                        for (int r = 0; r < 4; ++r) v[r] = (_Float16)acc[fr][fc][r];
                        *(f16x4*)&Ss[wc * 64 + fc * 16 + l15][fr * 16 + lg * 4] = v;
                    }
            }
            __syncthreads();

            if (tid < 128) {
                const int base = ntile * 128 + h * 64;
                int nval = N_M - base;
                if (nval > 64) nval = 64;
#pragma unroll 1
                for (int cc = 0; cc < nval; cc += 8) {
                    f16x8 sv = *(const f16x8*)&Ss[tid][cc];
                    const int lim = (nval - cc >= 8) ? 8 : (nval - cc);
                    float s[8];
#pragma unroll
                    for (int jj = 0; jj < 8; ++jj) s[jj] = (float)sv[jj];
                    if (lim < 8)
#pragma unroll
                        for (int jj = 0; jj < 8; ++jj)
                            if (jj >= lim) s[jj] = -INFINITY;
                    float m01 = fmaxf(s[0], s[1]), m23 = fmaxf(s[2], s[3]);
                    float m45 = fmaxf(s[4], s[5]), m67 = fmaxf(s[6], s[7]);
                    float mx = fmaxf(fmaxf(m01, m23), fmaxf(m45, m67));
                    if (mx >= rv[NC - 1]) {
#pragma unroll 1
                        for (int jj = 0; jj < 8; ++jj) {
                            if (jj >= lim) break;
                            float cv = s[jj]; int ci = base + cc + jj;
                            if (better(cv, ci, rv[NC - 1], ri[NC - 1])) {
#pragma unroll
                                for (int k = 0; k < NC; ++k) {
                                    bool b = better(cv, ci, rv[k], ri[k]);
                                    float nv = b ? cv : rv[k]; int ni = b ? ci : ri[k];
                                    float ov = b ? rv[k] : cv; int oi = b ? ri[k] : ci;
                                    rv[k] = nv; ri[k] = ni; cv = ov; ci = oi;
                                }
                            }
                        }
                    }
                }
            }
        }
    }

    if (tid < 128) {
        const int qg = qtile * 128 + tid;
        Cand* dst = cand + ((size_t)qg * nsuper + sup) * NC;
#pragma unroll
        for (int k = 0; k < NC; ++k) { Cand cde; cde.v = rv[k]; cde.i = ri[k]; dst[k] = cde; }
    }
}

// ---------------------------------------------------------------------------
// Probe kernels (diagnostics; write to scratch only).
// MODE 0: K-loop full, no epilogue. MODE 1: loads+barriers only.
// MODE 2: ds_read+MFMA only (no global loads).
// ---------------------------------------------------------------------------
template<int MODE>
__global__ __launch_bounds__(256)
void knn_probe(const _Float16* __restrict__ Qh, const _Float16* __restrict__ Mh,
               float* __restrict__ pout, int tpbn)
{
    __shared__ _Float16 As[128][32];
    __shared__ _Float16 Bs[128][32];

    const int bid   = blockIdx.x;
    const int c8    = bid & 7;
    const int j     = bid >> 3;
    const int qtile = j & 15;
    const int sup   = c8 + 8 * (j >> 4);
    const int nt0   = sup * tpbn;
    int nt1 = nt0 + tpbn;
    if (nt1 > NTILES) nt1 = NTILES;

    const int tid  = threadIdx.x;
    const int lane = tid & 63;
    const int wid  = tid >> 6;
    const int wr   = wid >> 1;
    const int wc   = wid & 1;
    const int l15  = lane & 15;
    const int lg   = lane >> 4;
    const int arow = tid >> 2;
    const int acol = (tid & 3) * 8;

    if (MODE == 2) {
        for (int i = tid; i < 128 * 16; i += 256) {
            ((float*)As)[i] = 0.f; ((float*)Bs)[i] = 0.f;
        }
        __syncthreads();
    }

    _Float16* Adst0 = &As[arow][acol];
    _Float16* Adst1 = &As[64 + arow][acol];
    _Float16* Bdst0 = &Bs[arow][acol];
    _Float16* Bdst1 = &Bs[64 + arow][acol];
    const _Float16* Bb = Qh + ((size_t)(qtile * 128 + arow) << 10) + acol;

    f32x4 acc[4][4];
#pragma unroll
    for (int i = 0; i < 4; ++i)
#pragma unroll
        for (int jj = 0; jj < 4; ++jj) acc[i][jj] = zero4();
    float xk = 0.f;

#pragma unroll 1
    for (int ntile = nt0; ntile < nt1; ++ntile) {
        const _Float16* Ab = Mh + ((size_t)(ntile * 128 + arow) << 10) + acol;
        for (int t = 0; t < KSTEPS; ++t) {
            if (MODE != 2) {
                const int k0 = t * BK;
                gload16(Ab + k0, Adst0);
                gload16(Ab + k0 + (64 << 10), Adst1);
                gload16(Bb + k0, Bdst0);
                gload16(Bb + k0 + (64 << 10), Bdst1);
            }
            __syncthreads();
            if (MODE == 1) {
                xk += (float)As[0][tid & 31];
            } else {
                f16x8 af[4], bf[4];
#pragma unroll
                for (int f = 0; f < 4; ++f) {
                    af[f] = *(const f16x8*)&As[wr * 64 + f * 16 + l15][lg * 8];
                    bf[f] = *(const f16x8*)&Bs[wc * 64 + f * 16 + l15][lg * 8];
                }
#pragma unroll
                for (int i = 0; i < 4; ++i)
#pragma unroll
                    for (int jj = 0; jj < 4; ++jj)
                        acc[i][jj] = __builtin_amdgcn_mfma_f32_16x16x32_f16(
                            af[i], bf[jj], acc[i][jj], 0, 0, 0);
            }
            __syncthreads();
            asm volatile("" ::: "memory");
        }
    }

    float s = xk;
#pragma unroll
    for (int i = 0; i < 4; ++i)
#pragma unroll
        for (int jj = 0; jj < 4; ++jj)
#pragma unroll
            for (int r = 0; r < 4; ++r) s += acc[i][jj][r];
    pout[(size_t)bid * 256 + tid] = s;
}

// dur encodes nsuper (~33 us per unit): decodes grid size from the profile
__global__ __launch_bounds__(64)
void knn_spin(int ns, float* __restrict__ out)
{
    float x = 1.0f + (float)threadIdx.x;
    const int iters = ns * 20000;
#pragma unroll 1
    for (int i = 0; i < iters; ++i) x = __builtin_fmaf(x, 0.9999999f, 1e-7f);
    if (x < 0.f) out[0] = x;
}

// ---------------------------------------------------------------------------
// Middle path (round-7 verbatim, proven): norms + fp32-staged GEMM select.
// ---------------------------------------------------------------------------
__global__ __launch_bounds__(256)
void knn_norms(const float* __restrict__ Mm, float* __restrict__ invn)
{
    const int wid  = threadIdx.x >> 6;
    const int lane = threadIdx.x & 63;
    const int r    = blockIdx.x * 4 + wid;
    if (r >= N_M) return;
    const f32x4* mp = (const f32x4*)(Mm + (size_t)r * D_DIM) + lane * 4;
    float ss = 0.f;
#pragma unroll
    for (int j = 0; j < 4; ++j) {
        f32x4 v = mp[j];
#pragma unroll
        for (int u = 0; u < 4; ++u) ss += v[u] * v[u];
    }
#pragma unroll
    for (int off = 1; off <= 32; off <<= 1) ss += __shfl_xor(ss, off, 64);
    if (lane == 0) invn[r] = ss > 0.f ? rsqrtf(ss) : 0.f;
}

__global__ __launch_bounds__(256)
void knn_gemm_select(const _Float16* __restrict__ Qh, const float* __restrict__ Mm,
                     const float* __restrict__ invn, Cand* __restrict__ cand,
                     int tpbn, int nsuper)
{
    __shared__ _Float16 As[128][LDH];
    __shared__ _Float16 Bs[128][LDH];
    __shared__ _Float16 Ss[128][SSW];
    __shared__ float    sinv[128];

    const int qtile = blockIdx.x & (QTILES - 1);
    const int sup   = blockIdx.x >> 4;
    const int nt0   = sup * tpbn;
    int nt1 = nt0 + tpbn;
    if (nt1 > NTILES) nt1 = NTILES;

    const int tid = threadIdx.x;
    const int row = tid >> 1;
    const int kh  = tid & 1;

    const int qrow_g = qtile * 128 + row;
    const _Float16* bbase = Qh + (size_t)qrow_g * D_DIM + kh * 16;

    const int lane = tid & 63;
    const int wid  = tid >> 6;
    const int wr   = wid >> 1;
    const int wc   = wid & 1;
    const int l15  = lane & 15;
    const int lg   = lane >> 4;

    float rv[NC]; int ri[NC];
#pragma unroll
    for (int k = 0; k < NC; ++k) { rv[k] = -INFINITY; ri[k] = 0; }

#pragma unroll 1
    for (int ntile = nt0; ntile < nt1; ++ntile) {
        const int nrow_g = ntile * 128 + row;
        const bool a_ok  = nrow_g < N_M;
        const float* abase = Mm + (size_t)nrow_g * D_DIM + kh * 16;

        f32x4 acc[4][4];
#pragma unroll
        for (int i = 0; i < 4; ++i)
#pragma unroll
            for (int j = 0; j < 4; ++j) acc[i][j] = zero4();

        f32x4 ar[4];
        f16x8 brh[2];
#pragma unroll
        for (int i = 0; i < 4; ++i) ar[i] = a_ok ? ((const f32x4*)abase)[i] : zero4();
        brh[0] = *(const f16x8*)(bbase);
        brh[1] = *(const f16x8*)(bbase + 8);

#pragma unroll 1
        for (int t = 0; t < KSTEPS; ++t) {
            __syncthreads();

            f16x8 ha0, ha1;
#pragma unroll
            for (int i = 0; i < 2; ++i)
#pragma unroll
                for (int j = 0; j < 4; ++j) {
                    ha0[i * 4 + j] = (_Float16)ar[i][j];
                    ha1[i * 4 + j] = (_Float16)ar[i + 2][j];
                }
            *(f16x8*)&As[row][kh * 16]     = ha0;
            *(f16x8*)&As[row][kh * 16 + 8] = ha1;
            *(f16x8*)&Bs[row][kh * 16]     = brh[0];
            *(f16x8*)&Bs[row][kh * 16 + 8] = brh[1];

            __syncthreads();

            if (t + 1 < KSTEPS) {
                const float*    ap = abase + (t + 1) * BK;
                const _Float16* bp = bbase + (t + 1) * BK;
#pragma unroll
                for (int i = 0; i < 4; ++i) ar[i] = a_ok ? ((const f32x4*)ap)[i] : zero4();
                brh[0] = *(const f16x8*)(bp);
                brh[1] = *(const f16x8*)(bp + 8);
            }

            f16x8 af[4], bf[4];
#pragma unroll
            for (int f = 0; f < 4; ++f) {
                af[f] = *(const f16x8*)&As[wr * 64 + f * 16 + l15][lg * 8];
                bf[f] = *(const f16x8*)&Bs[wc * 64 + f * 16 + l15][lg * 8];
            }
#pragma unroll
            for (int i = 0; i < 4; ++i)
#pragma unroll
                for (int j = 0; j < 4; ++j)
                    acc[i][j] = __builtin_amdgcn_mfma_f32_16x16x32_f16(
                        af[i], bf[j], acc[i][j], 0, 0, 0);
        }

        if (tid < 128) {
            const int r = ntile * 128 + tid;
            sinv[tid] = (r < N_M) ? invn[r] : 0.f;
        }

#pragma unroll 1
        for (int h = 0; h < 2; ++h) {
            __syncthreads();
            if (wr == h) {
#pragma unroll
                for (int fr = 0; fr < 4; ++fr)
#pragma unroll
                    for (int fc = 0; fc < 4; ++fc) {
                        f16x4 v;
#pragma unroll
                        for (int r = 0; r < 4; ++r) v[r] = (_Float16)acc[fr][fc][r];
                        *(f16x4*)&Ss[wc * 64 + fc * 16 + l15][fr * 16 + lg * 4] = v;
                    }
            }
            __syncthreads();

            if (tid < 128) {
                const int base = ntile * 128 + h * 64;
                int nval = N_M - base;
                if (nval > 64) nval = 64;
#pragma unroll 1
                for (int c = 0; c < nval; c += 8) {
                    f16x8 sv = *(const f16x8*)&Ss[tid][c];
                    f32x4 sa = *(const f32x4*)&sinv[h * 64 + c];
                    f32x4 sb = *(const f32x4*)&sinv[h * 64 + c + 4];
                    const int lim = (nval - c >= 8) ? 8 : (nval - c);
                    float s[8];
#pragma unroll
                    for (int j = 0; j < 4; ++j) {
                        s[j]     = (float)sv[j] * sa[j];
                        s[4 + j] = (float)sv[4 + j] * sb[j];
                    }
                    if (lim < 8)
#pragma unroll
                        for (int j = 0; j < 8; ++j)
                            if (j >= lim) s[j] = -INFINITY;
                    float m01 = fmaxf(s[0], s[1]), m23 = fmaxf(s[2], s[3]);
                    float m45 = fmaxf(s[4], s[5]), m67 = fmaxf(s[6], s[7]);
                    float mx = fmaxf(fmaxf(m01, m23), fmaxf(m45, m67));
                    if (mx >= rv[NC - 1]) {
#pragma unroll 1
                        for (int j = 0; j < 8; ++j) {
                            if (j >= lim) break;
                            float cv = s[j]; int ci = base + c + j;
                            if (better(cv, ci, rv[NC - 1], ri[NC - 1])) {
#pragma unroll
                                for (int k = 0; k < NC; ++k) {
                                    bool b = better(cv, ci, rv[k], ri[k]);
                                    float nv = b ? cv : rv[k]; int ni = b ? ci : ri[k];
                                    float ov = b ? rv[k] : cv; int oi = b ? ri[k] : ci;
                                    rv[k] = nv; ri[k] = ni; cv = ov; ci = oi;
                                }
                            }
                        }
                    }
                }
            }
        }
    }

    if (tid < 128) {
        const int qg = qtile * 128 + tid;
        Cand* dst = cand + ((size_t)qg * nsuper + sup) * NC;
#pragma unroll
        for (int k = 0; k < NC; ++k) { Cand c; c.v = rv[k]; c.i = ri[k]; dst[k] = c; }
    }
}

// ---------------------------------------------------------------------------
// Kernel 2: per query, reduce nsuper*16 candidates to global approx top-16.
// ---------------------------------------------------------------------------
__global__ __launch_bounds__(64)
void knn_top16(const Cand* __restrict__ cand, int* __restrict__ top_idx, int ncand)
{
    __shared__ float lv[64][NC];
    __shared__ int   li[64][NC];

    const int q = blockIdx.x;
    const int lane = threadIdx.x;
    const Cand* rowp = cand + (size_t)q * ncand;

    float tv[NC]; int ti[NC];
#pragma unroll
    for (int k = 0; k < NC; ++k) { tv[k] = -INFINITY; ti[k] = 0; }

#pragma unroll 1
    for (int e = lane; e < ncand; e += 64) {
        Cand c = rowp[e];
        if (better(c.v, c.i, tv[NC - 1], ti[NC - 1])) {
            float cv = c.v; int ci = c.i;
#pragma unroll
            for (int k = 0; k < NC; ++k) {
                bool b = better(cv, ci, tv[k], ti[k]);
                float nv = b ? cv : tv[k]; int ni = b ? ci : ti[k];
                float ov = b ? tv[k] : cv; int oi = b ? ti[k] : ci;
                tv[k] = nv; ti[k] = ni; cv = ov; ci = oi;
            }
        }
    }

#pragma unroll
    for (int k = 0; k < NC; ++k) { lv[lane][k] = tv[k]; li[lane][k] = ti[k]; }
    __syncthreads();

    if (lane == 0) {
#pragma unroll 1
        for (int l = 1; l < 64; ++l) {
#pragma unroll 1
            for (int k = 0; k < NC; ++k) {
                float v = lv[l][k]; int i = li[l][k];
                if (!better(v, i, tv[NC - 1], ti[NC - 1])) break;
                float cv = v; int ci = i;
#pragma unroll
                for (int kk = 0; kk < NC; ++kk) {
                    bool b = better(cv, ci, tv[kk], ti[kk]);
                    float nv = b ? cv : tv[kk]; int ni = b ? ci : ti[kk];
                    float ov = b ? tv[kk] : cv; int oi = b ? ti[kk] : ci;
                    tv[kk] = nv; ti[kk] = ni; cv = ov; ci = oi;
                }
            }
        }
#pragma unroll
        for (int k = 0; k < NC; ++k) top_idx[q * NC + k] = ti[k];
    }
}

// ---------------------------------------------------------------------------
// Kernel 3: exact fp64 rescore of the 16 candidates, top-k, gather-average.
// ---------------------------------------------------------------------------
__global__ __launch_bounds__(256)
void knn_rescore(const float* __restrict__ Qm, const float* __restrict__ Mm,
                 const float* __restrict__ Sm, const int* __restrict__ topk_p,
                 const int* __restrict__ top_idx, float* __restrict__ outp)
{
    const int q   = blockIdx.x;
    const int tid = threadIdx.x;
    const int wid = tid >> 6, lane = tid & 63;

    __shared__ double sval[NC];
    __shared__ int    sidx[NC];
    __shared__ int    chosen[NC];

    int k = *topk_p;
    if (k > NC) k = NC;
    if (k < 1)  k = 1;

    const float* qrow = Qm + (size_t)q * D_DIM;
#pragma unroll 1
    for (int ci = wid; ci < NC; ci += 4) {
        int idx = top_idx[q * NC + ci];
        if (idx < 0)    idx = 0;
        if (idx >= N_M) idx = N_M - 1;
        const f32x4* mp = (const f32x4*)(Mm + (size_t)idx * D_DIM) + lane * 4;
        const f32x4* qp = (const f32x4*)qrow + lane * 4;
        double dot = 0.0, ss = 0.0;
#pragma unroll
        for (int j = 0; j < 4; ++j) {
            f32x4 mv = mp[j], qv = qp[j];
#pragma unroll
            for (int u = 0; u < 4; ++u) {
                dot += (double)mv[u] * (double)qv[u];
                ss  += (double)mv[u] * (double)mv[u];
            }
        }
#pragma unroll
        for (int off = 1; off <= 32; off <<= 1) {
            dot += __shfl_xor(dot, off, 64);
            ss  += __shfl_xor(ss, off, 64);
        }
        if (lane == 0) { sval[ci] = ss > 0.0 ? dot / sqrt(ss) : -1e300; sidx[ci] = idx; }
    }
    __syncthreads();

    if (tid == 0) {
        unsigned used = 0;
        for (int j = 0; j < k; ++j) {
            int best = -1;
            for (int i = 0; i < NC; ++i) {
                if (used & (1u << i)) continue;
                if (best < 0 || sval[i] > sval[best] ||
                    (sval[i] == sval[best] && sidx[i] < sidx[best])) best = i;
            }
            used |= 1u << best;
            chosen[j] = sidx[best];
        }
    }
    __syncthreads();

    const int d0 = tid * 4;
    f32x4 a = zero4();
    for (int j = 0; j < k; ++j) {
        f32x4 s4 = *(const f32x4*)(Sm + (size_t)chosen[j] * D_DIM + d0);
        a = a + s4;
    }
    const float inv = 1.0f / (float)k;
    a = a * inv;
    *(f32x4*)(outp + (size_t)q * D_DIM + d0) = a;
}

// ---------------------------------------------------------------------------
// Fallback: round-5 brute force, verbatim (proven: passed, absmax 0.0).
// ---------------------------------------------------------------------------
#define FNC 8
__global__ __launch_bounds__(256)
void knn_all(const float* __restrict__ Qm, const float* __restrict__ Mm,
             const float* __restrict__ Sm, const int* __restrict__ topk_p,
             float* __restrict__ outp)
{
    __shared__ float  qs[D_DIM];
    __shared__ float  wv[4][FNC];
    __shared__ int    wi[4][FNC];
    __shared__ int    cand8[FNC];
    __shared__ double dval[FNC];
    __shared__ int    chosen[FNC];
    __shared__ int    sk;

    const int q    = blockIdx.x;
    const int tid  = threadIdx.x;
    const int wid  = tid >> 6;
    const int lane = tid & 63;

    for (int i = tid; i < D_DIM / 4; i += 256)
        ((f32x4*)qs)[i] = ((const f32x4*)(Qm + (size_t)q * D_DIM))[i];
    __syncthreads();

    float tv[FNC]; int ti[FNC];
#pragma unroll
    for (int k = 0; k < FNC; ++k) { tv[k] = -INFINITY; ti[k] = 0; }

    for (int r = wid; r < N_M; r += 4) {
        const f32x4* mp = (const f32x4*)(Mm + (size_t)r * D_DIM) + lane * 4;
        const f32x4* qp = (const f32x4*)qs + lane * 4;
        float dot = 0.f, ss = 0.f;
#pragma unroll
        for (int j = 0; j < 4; ++j) {
            f32x4 mv = mp[j], qv = qp[j];
#pragma unroll
            for (int u = 0; u < 4; ++u) { dot += mv[u] * qv[u]; ss += mv[u] * mv[u]; }
        }
#pragma unroll
        for (int off = 1; off <= 32; off <<= 1) {
            dot += __shfl_xor(dot, off, 64);
            ss  += __shfl_xor(ss,  off, 64);
        }
        float s = ss > 0.f ? dot * rsqrtf(ss) : -INFINITY;
        if (better(s, r, tv[FNC - 1], ti[FNC - 1])) {
            float cv = s; int ci = r;
#pragma unroll
            for (int k = 0; k < FNC; ++k) {
                bool b = better(cv, ci, tv[k], ti[k]);
                float nv = b ? cv : tv[k]; int ni = b ? ci : ti[k];
                float ov = b ? tv[k] : cv; int oi = b ? ti[k] : ci;
                tv[k] = nv; ti[k] = ni; cv = ov; ci = oi;
            }
        }
    }

    if (lane == 0)
#pragma unroll
        for (int k = 0; k < FNC; ++k) { wv[wid][k] = tv[k]; wi[wid][k] = ti[k]; }
    __syncthreads();

    if (tid == 0) {
        unsigned used = 0;
        for (int j = 0; j < FNC; ++j) {
            float bv = -INFINITY; int bi = 0; int bs = -1;
            for (int s = 0; s < 4 * FNC; ++s) {
                if (used & (1u << s)) continue;
                float v = wv[s >> 3][s & 7]; int i = wi[s >> 3][s & 7];
                if (bs < 0 || better(v, i, bv, bi)) { bv = v; bi = i; bs = s; }
            }
            used |= 1u << bs;
            cand8[j] = bi;
        }
        int kk = *topk_p;
        if (kk < 1) kk = 1;
        if (kk > FNC) kk = FNC;
        sk = kk;
    }
    __syncthreads();

    for (int ci = wid; ci < FNC; ci += 4) {
        int idx = cand8[ci];
        if (idx < 0)     idx = 0;
        if (idx >= N_M)  idx = N_M - 1;
        const f32x4* mp = (const f32x4*)(Mm + (size_t)idx * D_DIM) + lane * 4;
        const f32x4* qp = (const f32x4*)qs + lane * 4;
        double dot = 0.0, ss = 0.0;
#pragma unroll
        for (int j = 0; j < 4; ++j) {
            f32x4 mv = mp[j], qv = qp[j];
#pragma unroll
            for (int u = 0; u < 4; ++u) {
                dot += (double)mv[u] * (double)qv[u];
                ss  += (double)mv[u] * (double)mv[u];
            }
        }
#pragma unroll
        for (int off = 1; off <= 32; off <<= 1) {
            dot += __shfl_xor(dot, off, 64);
            ss  += __shfl_xor(ss, off, 64);
        }
        if (lane == 0) dval[ci] = ss > 0.0 ? dot / sqrt(ss) : -1e300;
    }
    __syncthreads();

    if (tid == 0) {
        int kk = sk;
        unsigned used = 0;
        for (int j = 0; j < kk; ++j) {
            int best = -1;
            for (int i = 0; i < FNC; ++i) {
                if (used & (1u << i)) continue;
                if (best < 0 || dval[i] > dval[best] ||
                    (dval[i] == dval[best] && cand8[i] < cand8[best])) best = i;
            }
            used |= 1u << best;
            chosen[j] = cand8[best];
        }
    }
    __syncthreads();

    const int kk = sk;
    const int d0 = tid * 4;
    f32x4 a = zero4();
    for (int j = 0; j < kk; ++j) {
        f32x4 s4 = *(const f32x4*)(Sm + (size_t)chosen[j] * D_DIM + d0);
        a = a + s4;
    }
    const float inv = 1.0f / (float)kk;
    a = a * inv;
    *(f32x4*)(outp + (size_t)q * D_DIM + d0) = a;
}

// ---------------------------------------------------------------------------
extern "C" void kernel_launch(void* const* d_in, const int* in_sizes, int n_in,
                              void* d_out, int out_size, void* d_ws, size_t ws_size,
                              hipStream_t stream)
{
    (void)in_sizes; (void)n_in; (void)out_size;

    const float* Qm   = (const float*)d_in[0];
    const float* Mm   = (const float*)d_in[1];
    const float* Sm   = (const float*)d_in[2];
    const int*   topk = (const int*)d_in[3];
    float*       outp = (float*)d_out;

    const size_t A511      = 511;
    const size_t mh_bytes  = (((size_t)MPAD * D_DIM * sizeof(_Float16)) + A511) & ~A511;
    const size_t qh_bytes  = (size_t)QPAD * D_DIM * sizeof(_Float16);                 // 4 MiB
    const size_t inv_bytes = ((size_t)N_M * sizeof(float) + A511) & ~A511;
    const size_t ti_bytes  = (((size_t)T_Q * NC * sizeof(int)) + A511) & ~A511;
    const size_t per_sup   = (size_t)QPAD * NC * sizeof(Cand);                        // 256 KiB

    if (d_ws != nullptr) {
        // ---- main path: ns must be a multiple of 8 (XCD grouping) ----
        const int ns_opts[5] = { 96, 48, 24, 16, 8 };
        int ns = 0;
        for (int i = 0; i < 5; ++i) {
            size_t need = mh_bytes + qh_bytes + ti_bytes + (size_t)ns_opts[i] * per_sup;
            if (need <= ws_size) { ns = ns_opts[i]; break; }
        }
        if (ns >= 8) {
            const int tpbn = (NTILES + ns - 1) / ns;

            _Float16* Mh      = (_Float16*)d_ws;
            _Float16* Qh      = (_Float16*)((char*)d_ws + mh_bytes);
            int*      top_idx = (int*)((char*)d_ws + mh_bytes + qh_bytes);
            Cand*     cand    = (Cand*)((char*)d_ws + mh_bytes + qh_bytes + ti_bytes);
            float*    pout    = (float*)Qh;   // probe scratch; qcvt rewrites each replay

            hipLaunchKernelGGL(knn_qcvt, dim3(QPAD * D_DIM / 2048), dim3(256), 0, stream,
                               Qm, Qh);
            hipLaunchKernelGGL(knn_mcvt, dim3(MPAD / 4), dim3(256), 0, stream,
                               Mm, Mh);
            hipLaunchKernelGGL(knn_gemm_select_h, dim3(QTILES * ns), dim3(256), 0, stream,
                               Qh, Mh, cand, tpbn, ns);
            hipLaunchKernelGGL(knn_top16, dim3(T_Q), dim3(64), 0, stream,
                               cand, top_idx, ns * NC);
            hipLaunchKernelGGL(knn_rescore, dim3(T_Q), dim3(256), 0, stream,
                               Qm, Mm, Sm, topk, top_idx, outp);

            // diagnostics (output already computed; probes write scratch only)
            hipLaunchKernelGGL((knn_probe<0>), dim3(QTILES * ns), dim3(256), 0, stream,
                               Qh, Mh, pout, tpbn);
            hipLaunchKernelGGL((knn_probe<1>), dim3(QTILES * ns), dim3(256), 0, stream,
                               Qh, Mh, pout, tpbn);
            hipLaunchKernelGGL((knn_probe<2>), dim3(QTILES * ns), dim3(256), 0, stream,
                               Qh, Mh, pout, tpbn);
            hipLaunchKernelGGL(knn_spin, dim3(1), dim3(64), 0, stream, ns, pout);
            return;
        }

        // ---- middle path: round-7 structure (~20 MB of workspace) ----
        long long avail = (long long)ws_size
                        - (long long)(inv_bytes + qh_bytes + ti_bytes);
        int ns2 = avail > 0 ? (int)(avail / (long long)per_sup) : 0;
        if (ns2 > 64) ns2 = 64;
        if (ns2 >= 1) {
            int tpbn = (NTILES + ns2 - 1) / ns2;
            ns2 = (NTILES + tpbn - 1) / tpbn;

            float*    invn    = (float*)d_ws;
            _Float16* Qh      = (_Float16*)((char*)d_ws + inv_bytes);
            int*      top_idx = (int*)((char*)d_ws + inv_bytes + qh_bytes);
            Cand*     cand    = (Cand*)((char*)d_ws + inv_bytes + qh_bytes + ti_bytes);

            hipLaunchKernelGGL(knn_qcvt, dim3(QPAD * D_DIM / 2048), dim3(256), 0, stream,
                               Qm, Qh);
            hipLaunchKernelGGL(knn_norms, dim3((N_M + 3) / 4), dim3(256), 0, stream,
                               Mm, invn);
            hipLaunchKernelGGL(knn_gemm_select, dim3(QTILES * ns2), dim3(256), 0, stream,
                               Qh, Mm, invn, cand, tpbn, ns2);
            hipLaunchKernelGGL(knn_top16, dim3(T_Q), dim3(64), 0, stream,
                               cand, top_idx, ns2 * NC);
            hipLaunchKernelGGL(knn_rescore, dim3(T_Q), dim3(256), 0, stream,
                               Qm, Mm, Sm, topk, top_idx, outp);
            return;
        }
    }

    // ---- last resort: zero-workspace brute force ----
    hipLaunchKernelGGL(knn_all, dim3(T_Q), dim3(256), 0, stream,
                       Qm, Mm, Sm, topk, outp);
}

// Round 11
// 3515.237 us; speedup vs baseline: 10.3427x; 10.3427x over previous
//
#include <hip/hip_runtime.h>
#include <math.h>

#define T_Q    2000
#define N_M    100000
#define D_DIM  1024
#define QTILES 16
#define NTILES 782          // ceil(100000/128)
#define MPAD   (NTILES * 128)   // 100096 zero-padded fp16 M rows
#define BK     32
#define KSTEPS (D_DIM / BK) // 32
#define LDH    40           // middle-path A/B LDS row stride in halves (80 B)
#define SSW    72           // score tile row stride in halves (144 B)
#define NC     16           // rescore candidate superset per query
#define QPAD   2048

typedef _Float16 f16x8 __attribute__((ext_vector_type(8)));
typedef _Float16 f16x4 __attribute__((ext_vector_type(4)));
typedef float    f32x4 __attribute__((ext_vector_type(4)));
typedef unsigned int u32;

struct __align__(8) Cand { float v; int i; };
static_assert(sizeof(Cand) == 8, "cand size");

__device__ __forceinline__ bool better(float av, int ai, float bv, int bi) {
    return (av > bv) || (av == bv && ai < bi);
}

__device__ __forceinline__ f32x4 zero4() {
    f32x4 z; z[0] = 0.f; z[1] = 0.f; z[2] = 0.f; z[3] = 0.f; return z;
}

// async global->LDS, 16 B per lane (dest pattern: wave-uniform base + lane*16)
__device__ __forceinline__ void gload16(const _Float16* g, _Float16* l) {
    const __attribute__((address_space(1))) u32* gp =
        (const __attribute__((address_space(1))) u32*)g;
    __attribute__((address_space(3))) u32* lp =
        (__attribute__((address_space(3))) u32*)l;
    __builtin_amdgcn_global_load_lds(gp, lp, 16, 0, 0);
}

// ---------------------------------------------------------------------------
// Kernel Q: convert query matrix to fp16 once (rows >= T_Q zero-filled).
// ---------------------------------------------------------------------------
__global__ __launch_bounds__(256)
void knn_qcvt(const float* __restrict__ Qm, _Float16* __restrict__ Qh)
{
    const size_t base = (size_t)blockIdx.x * 2048 + (size_t)threadIdx.x * 8;
    const int row = (int)(base >> 10);
    f16x8 h;
    if (row < T_Q) {
        f32x4 a = *(const f32x4*)(Qm + base);
        f32x4 b = *(const f32x4*)(Qm + base + 4);
#pragma unroll
        for (int j = 0; j < 4; ++j) { h[j] = (_Float16)a[j]; h[4 + j] = (_Float16)b[j]; }
    } else {
#pragma unroll
        for (int j = 0; j < 8; ++j) h[j] = (_Float16)0.f;
    }
    *(f16x8*)(Qh + base) = h;
}

// ---------------------------------------------------------------------------
// Kernel M: fused norm + prescale + fp16 convert + zero-pad of M.
// ---------------------------------------------------------------------------
__global__ __launch_bounds__(256)
void knn_mcvt(const float* __restrict__ Mm, _Float16* __restrict__ Mh)
{
    const int wid  = threadIdx.x >> 6;
    const int lane = threadIdx.x & 63;
    const int r    = blockIdx.x * 4 + wid;   // grid covers MPAD rows
    f16x8 h0, h1;
    if (r < N_M) {
        const f32x4* mp = (const f32x4*)(Mm + (size_t)r * D_DIM) + lane * 4;
        f32x4 v0 = mp[0], v1 = mp[1], v2 = mp[2], v3 = mp[3];
        float ss = 0.f;
#pragma unroll
        for (int u = 0; u < 4; ++u)
            ss += v0[u] * v0[u] + v1[u] * v1[u] + v2[u] * v2[u] + v3[u] * v3[u];
#pragma unroll
        for (int off = 1; off <= 32; off <<= 1) ss += __shfl_xor(ss, off, 64);
        const float inv = ss > 0.f ? rsqrtf(ss) : 0.f;
#pragma unroll
        for (int u = 0; u < 4; ++u) {
            h0[u]     = (_Float16)(v0[u] * inv);
            h0[4 + u] = (_Float16)(v1[u] * inv);
            h1[u]     = (_Float16)(v2[u] * inv);
            h1[4 + u] = (_Float16)(v3[u] * inv);
        }
    } else {
#pragma unroll
        for (int j = 0; j < 8; ++j) { h0[j] = (_Float16)0.f; h1[j] = (_Float16)0.f; }
    }
    _Float16* dst = Mh + (size_t)r * D_DIM + lane * 16;
    *(f16x8*)dst       = h0;
    *(f16x8*)(dst + 8) = h1;
}

// ---------------------------------------------------------------------------
// Kernel 1 (main): fp16 MFMA scores via global_load_lds, XCD-grouped sups
// (a sup's 16 qtile-sharers land on ONE XCD -> M panel fetched once per L2).
// Requires nsuper % 8 == 0. Select epilogue proven (absmax 0.0).
// ---------------------------------------------------------------------------
__global__ __launch_bounds__(256)
void knn_gemm_select_h(const _Float16* __restrict__ Qh,
                       const _Float16* __restrict__ Mh,
                       Cand* __restrict__ cand, int tpbn, int nsuper)
{
    __shared__ _Float16 As[128][32];    //  8192 B
    __shared__ _Float16 Bs[128][32];    //  8192 B
    __shared__ _Float16 Ss[128][SSW];   // 18432 B  (total 34816 B)

    // XCD-aware mapping: hardware assigns bid%8 -> XCD (round-robin).
    const int bid   = blockIdx.x;
    const int c8    = bid & 7;          // XCD slot
    const int j     = bid >> 3;
    const int qtile = j & 15;           // 16 sharers of a sup are 8 bids apart
    const int sup   = c8 + 8 * (j >> 4);

    const int nt0 = sup * tpbn;
    int nt1 = nt0 + tpbn;
    if (nt1 > NTILES) nt1 = NTILES;

    const int tid  = threadIdx.x;
    const int lane = tid & 63;
    const int wid  = tid >> 6;
    const int wr   = wid >> 1;
    const int wc   = wid & 1;
    const int l15  = lane & 15;
    const int lg   = lane >> 4;

    const int arow = tid >> 2;          // 0..63
    const int acol = (tid & 3) * 8;     // halves

    _Float16* Adst0 = &As[arow][acol];
    _Float16* Adst1 = &As[64 + arow][acol];
    _Float16* Bdst0 = &Bs[arow][acol];
    _Float16* Bdst1 = &Bs[64 + arow][acol];

    const _Float16* Bb = Qh + ((size_t)(qtile * 128 + arow) << 10) + acol;

    float rv[NC]; int ri[NC];
#pragma unroll
    for (int k = 0; k < NC; ++k) { rv[k] = -INFINITY; ri[k] = 0; }

#pragma unroll 1
    for (int ntile = nt0; ntile < nt1; ++ntile) {
        const _Float16* Ab = Mh + ((size_t)(ntile * 128 + arow) << 10) + acol;

        f32x4 acc[4][4];
#pragma unroll
        for (int i = 0; i < 4; ++i)
#pragma unroll
            for (int jj = 0; jj < 4; ++jj) acc[i][jj] = zero4();

        for (int t = 0; t < KSTEPS; ++t) {   // compiler free to unroll/schedule
            const int k0 = t * BK;
            gload16(Ab + k0, Adst0);
            gload16(Ab + k0 + (64 << 10), Adst1);
            gload16(Bb + k0, Bdst0);
            gload16(Bb + k0 + (64 << 10), Bdst1);

            __syncthreads();

            f16x8 af[4], bf[4];
#pragma unroll
            for (int f = 0; f < 4; ++f) {
                af[f] = *(const f16x8*)&As[wr * 64 + f * 16 + l15][lg * 8];
                bf[f] = *(const f16x8*)&Bs[wc * 64 + f * 16 + l15][lg * 8];
            }
#pragma unroll
            for (int i = 0; i < 4; ++i)
#pragma unroll
                for (int jj = 0; jj < 4; ++jj)
                    acc[i][jj] = __builtin_amdgcn_mfma_f32_16x16x32_f16(
                        af[i], bf[jj], acc[i][jj], 0, 0, 0);

            __syncthreads();
        }

        // two half-tile dump+scan rounds
#pragma unroll 1
        for (int h = 0; h < 2; ++h) {
            __syncthreads();
            if (wr == h) {
#pragma unroll
                for (int fr = 0; fr < 4; ++fr)
#pragma unroll
                    for (int fc = 0; fc < 4; ++fc) {
                        f16x4 v;
#pragma unroll
                        for (int r = 0; r < 4; ++r) v[r] = (_Float16)acc[fr][fc][r];
                        *(f16x4*)&Ss[wc * 64 + fc * 16 + l15][fr * 16 + lg * 4] = v;
                    }
            }
            __syncthreads();

            if (tid < 128) {
                const int base = ntile * 128 + h * 64;
                int nval = N_M - base;
                if (nval > 64) nval = 64;
#pragma unroll 1
                for (int cc = 0; cc < nval; cc += 8) {
                    f16x8 sv = *(const f16x8*)&Ss[tid][cc];
                    const int lim = (nval - cc >= 8) ? 8 : (nval - cc);
                    float s[8];
#pragma unroll
                    for (int jj = 0; jj < 8; ++jj) s[jj] = (float)sv[jj];
                    if (lim < 8)
#pragma unroll
                        for (int jj = 0; jj < 8; ++jj)
                            if (jj >= lim) s[jj] = -INFINITY;
                    float m01 = fmaxf(s[0], s[1]), m23 = fmaxf(s[2], s[3]);
                    float m45 = fmaxf(s[4], s[5]), m67 = fmaxf(s[6], s[7]);
                    float mx = fmaxf(fmaxf(m01, m23), fmaxf(m45, m67));
                    if (mx >= rv[NC - 1]) {
#pragma unroll 1
                        for (int jj = 0; jj < 8; ++jj) {
                            if (jj >= lim) break;
                            float cv = s[jj]; int ci = base + cc + jj;
                            if (better(cv, ci, rv[NC - 1], ri[NC - 1])) {
#pragma unroll
                                for (int k = 0; k < NC; ++k) {
                                    bool b = better(cv, ci, rv[k], ri[k]);
                                    float nv = b ? cv : rv[k]; int ni = b ? ci : ri[k];
                                    float ov = b ? rv[k] : cv; int oi = b ? ri[k] : ci;
                                    rv[k] = nv; ri[k] = ni; cv = ov; ci = oi;
                                }
                            }
                        }
                    }
                }
            }
        }
    }

    if (tid < 128) {
        const int qg = qtile * 128 + tid;
        Cand* dst = cand + ((size_t)qg * nsuper + sup) * NC;
#pragma unroll
        for (int k = 0; k < NC; ++k) { Cand cde; cde.v = rv[k]; cde.i = ri[k]; dst[k] = cde; }
    }
}

// ---------------------------------------------------------------------------
// Probe kernels (diagnostics at reduced tpbn; write to scratch only).
// MODE 0: K-loop full, no epilogue. MODE 1: loads+barriers only.
// MODE 2: ds_read+MFMA only (no global loads).
// ---------------------------------------------------------------------------
template<int MODE>
__global__ __launch_bounds__(256)
void knn_probe(const _Float16* __restrict__ Qh, const _Float16* __restrict__ Mh,
               float* __restrict__ pout, int tpbn)
{
    __shared__ _Float16 As[128][32];
    __shared__ _Float16 Bs[128][32];

    const int bid   = blockIdx.x;
    const int c8    = bid & 7;
    const int j     = bid >> 3;
    const int qtile = j & 15;
    const int sup   = c8 + 8 * (j >> 4);
    const int nt0   = sup * tpbn;
    int nt1 = nt0 + tpbn;
    if (nt1 > NTILES) nt1 = NTILES;

    const int tid  = threadIdx.x;
    const int lane = tid & 63;
    const int wid  = tid >> 6;
    const int wr   = wid >> 1;
    const int wc   = wid & 1;
    const int l15  = lane & 15;
    const int lg   = lane >> 4;
    const int arow = tid >> 2;
    const int acol = (tid & 3) * 8;

    if (MODE == 2) {
        for (int i = tid; i < 128 * 16; i += 256) {
            ((float*)As)[i] = 0.f; ((float*)Bs)[i] = 0.f;
        }
        __syncthreads();
    }

    _Float16* Adst0 = &As[arow][acol];
    _Float16* Adst1 = &As[64 + arow][acol];
    _Float16* Bdst0 = &Bs[arow][acol];
    _Float16* Bdst1 = &Bs[64 + arow][acol];
    const _Float16* Bb = Qh + ((size_t)(qtile * 128 + arow) << 10) + acol;

    f32x4 acc[4][4];
#pragma unroll
    for (int i = 0; i < 4; ++i)
#pragma unroll
        for (int jj = 0; jj < 4; ++jj) acc[i][jj] = zero4();
    float xk = 0.f;

#pragma unroll 1
    for (int ntile = nt0; ntile < nt1; ++ntile) {
        const _Float16* Ab = Mh + ((size_t)(ntile * 128 + arow) << 10) + acol;
        for (int t = 0; t < KSTEPS; ++t) {
            if (MODE != 2) {
                const int k0 = t * BK;
                gload16(Ab + k0, Adst0);
                gload16(Ab + k0 + (64 << 10), Adst1);
                gload16(Bb + k0, Bdst0);
                gload16(Bb + k0 + (64 << 10), Bdst1);
            }
            __syncthreads();
            if (MODE == 1) {
                xk += (float)As[0][tid & 31];
            } else {
                f16x8 af[4], bf[4];
#pragma unroll
                for (int f = 0; f < 4; ++f) {
                    af[f] = *(const f16x8*)&As[wr * 64 + f * 16 + l15][lg * 8];
                    bf[f] = *(const f16x8*)&Bs[wc * 64 + f * 16 + l15][lg * 8];
                }
#pragma unroll
                for (int i = 0; i < 4; ++i)
#pragma unroll
                    for (int jj = 0; jj < 4; ++jj)
                        acc[i][jj] = __builtin_amdgcn_mfma_f32_16x16x32_f16(
                            af[i], bf[jj], acc[i][jj], 0, 0, 0);
            }
            __syncthreads();
            asm volatile("" ::: "memory");
        }
    }

    float s = xk;
#pragma unroll
    for (int i = 0; i < 4; ++i)
#pragma unroll
        for (int jj = 0; jj < 4; ++jj)
#pragma unroll
            for (int r = 0; r < 4; ++r) s += acc[i][jj][r];
    pout[(size_t)bid * 256 + tid] = s;
}

// ---------------------------------------------------------------------------
// Middle path (round-7 verbatim, proven): norms + fp32-staged GEMM select.
// ---------------------------------------------------------------------------
__global__ __launch_bounds__(256)
void knn_norms(const float* __restrict__ Mm, float* __restrict__ invn)
{
    const int wid  = threadIdx.x >> 6;
    const int lane = threadIdx.x & 63;
    const int r    = blockIdx.x * 4 + wid;
    if (r >= N_M) return;
    const f32x4* mp = (const f32x4*)(Mm + (size_t)r * D_DIM) + lane * 4;
    float ss = 0.f;
#pragma unroll
    for (int j = 0; j < 4; ++j) {
        f32x4 v = mp[j];
#pragma unroll
        for (int u = 0; u < 4; ++u) ss += v[u] * v[u];
    }
#pragma unroll
    for (int off = 1; off <= 32; off <<= 1) ss += __shfl_xor(ss, off, 64);
    if (lane == 0) invn[r] = ss > 0.f ? rsqrtf(ss) : 0.f;
}

__global__ __launch_bounds__(256)
void knn_gemm_select(const _Float16* __restrict__ Qh, const float* __restrict__ Mm,
                     const float* __restrict__ invn, Cand* __restrict__ cand,
                     int tpbn, int nsuper)
{
    __shared__ _Float16 As[128][LDH];
    __shared__ _Float16 Bs[128][LDH];
    __shared__ _Float16 Ss[128][SSW];
    __shared__ float    sinv[128];

    const int qtile = blockIdx.x & (QTILES - 1);
    const int sup   = blockIdx.x >> 4;
    const int nt0   = sup * tpbn;
    int nt1 = nt0 + tpbn;
    if (nt1 > NTILES) nt1 = NTILES;

    const int tid = threadIdx.x;
    const int row = tid >> 1;
    const int kh  = tid & 1;

    const int qrow_g = qtile * 128 + row;
    const _Float16* bbase = Qh + (size_t)qrow_g * D_DIM + kh * 16;

    const int lane = tid & 63;
    const int wid  = tid >> 6;
    const int wr   = wid >> 1;
    const int wc   = wid & 1;
    const int l15  = lane & 15;
    const int lg   = lane >> 4;

    float rv[NC]; int ri[NC];
#pragma unroll
    for (int k = 0; k < NC; ++k) { rv[k] = -INFINITY; ri[k] = 0; }

#pragma unroll 1
    for (int ntile = nt0; ntile < nt1; ++ntile) {
        const int nrow_g = ntile * 128 + row;
        const bool a_ok  = nrow_g < N_M;
        const float* abase = Mm + (size_t)nrow_g * D_DIM + kh * 16;

        f32x4 acc[4][4];
#pragma unroll
        for (int i = 0; i < 4; ++i)
#pragma unroll
            for (int j = 0; j < 4; ++j) acc[i][j] = zero4();

        f32x4 ar[4];
        f16x8 brh[2];
#pragma unroll
        for (int i = 0; i < 4; ++i) ar[i] = a_ok ? ((const f32x4*)abase)[i] : zero4();
        brh[0] = *(const f16x8*)(bbase);
        brh[1] = *(const f16x8*)(bbase + 8);

#pragma unroll 1
        for (int t = 0; t < KSTEPS; ++t) {
            __syncthreads();

            f16x8 ha0, ha1;
#pragma unroll
            for (int i = 0; i < 2; ++i)
#pragma unroll
                for (int j = 0; j < 4; ++j) {
                    ha0[i * 4 + j] = (_Float16)ar[i][j];
                    ha1[i * 4 + j] = (_Float16)ar[i + 2][j];
                }
            *(f16x8*)&As[row][kh * 16]     = ha0;
            *(f16x8*)&As[row][kh * 16 + 8] = ha1;
            *(f16x8*)&Bs[row][kh * 16]     = brh[0];
            *(f16x8*)&Bs[row][kh * 16 + 8] = brh[1];

            __syncthreads();

            if (t + 1 < KSTEPS) {
                const float*    ap = abase + (t + 1) * BK;
                const _Float16* bp = bbase + (t + 1) * BK;
#pragma unroll
                for (int i = 0; i < 4; ++i) ar[i] = a_ok ? ((const f32x4*)ap)[i] : zero4();
                brh[0] = *(const f16x8*)(bp);
                brh[1] = *(const f16x8*)(bp + 8);
            }

            f16x8 af[4], bf[4];
#pragma unroll
            for (int f = 0; f < 4; ++f) {
                af[f] = *(const f16x8*)&As[wr * 64 + f * 16 + l15][lg * 8];
                bf[f] = *(const f16x8*)&Bs[wc * 64 + f * 16 + l15][lg * 8];
            }
#pragma unroll
            for (int i = 0; i < 4; ++i)
#pragma unroll
                for (int j = 0; j < 4; ++j)
                    acc[i][j] = __builtin_amdgcn_mfma_f32_16x16x32_f16(
                        af[i], bf[j], acc[i][j], 0, 0, 0);
        }

        if (tid < 128) {
            const int r = ntile * 128 + tid;
            sinv[tid] = (r < N_M) ? invn[r] : 0.f;
        }

#pragma unroll 1
        for (int h = 0; h < 2; ++h) {
            __syncthreads();
            if (wr == h) {
#pragma unroll
                for (int fr = 0; fr < 4; ++fr)
#pragma unroll
                    for (int fc = 0; fc < 4; ++fc) {
                        f16x4 v;
#pragma unroll
                        for (int r = 0; r < 4; ++r) v[r] = (_Float16)acc[fr][fc][r];
                        *(f16x4*)&Ss[wc * 64 + fc * 16 + l15][fr * 16 + lg * 4] = v;
                    }
            }
            __syncthreads();

            if (tid < 128) {
                const int base = ntile * 128 + h * 64;
                int nval = N_M - base;
                if (nval > 64) nval = 64;
#pragma unroll 1
                for (int c = 0; c < nval; c += 8) {
                    f16x8 sv = *(const f16x8*)&Ss[tid][c];
                    f32x4 sa = *(const f32x4*)&sinv[h * 64 + c];
                    f32x4 sb = *(const f32x4*)&sinv[h * 64 + c + 4];
                    const int lim = (nval - c >= 8) ? 8 : (nval - c);
                    float s[8];
#pragma unroll
                    for (int j = 0; j < 4; ++j) {
                        s[j]     = (float)sv[j] * sa[j];
                        s[4 + j] = (float)sv[4 + j] * sb[j];
                    }
                    if (lim < 8)
#pragma unroll
                        for (int j = 0; j < 8; ++j)
                            if (j >= lim) s[j] = -INFINITY;
                    float m01 = fmaxf(s[0], s[1]), m23 = fmaxf(s[2], s[3]);
                    float m45 = fmaxf(s[4], s[5]), m67 = fmaxf(s[6], s[7]);
                    float mx = fmaxf(fmaxf(m01, m23), fmaxf(m45, m67));
                    if (mx >= rv[NC - 1]) {
#pragma unroll 1
                        for (int j = 0; j < 8; ++j) {
                            if (j >= lim) break;
                            float cv = s[j]; int ci = base + c + j;
                            if (better(cv, ci, rv[NC - 1], ri[NC - 1])) {
#pragma unroll
                                for (int k = 0; k < NC; ++k) {
                                    bool b = better(cv, ci, rv[k], ri[k]);
                                    float nv = b ? cv : rv[k]; int ni = b ? ci : ri[k];
                                    float ov = b ? rv[k] : cv; int oi = b ? ri[k] : ci;
                                    rv[k] = nv; ri[k] = ni; cv = ov; ci = oi;
                                }
                            }
                        }
                    }
                }
            }
        }
    }

    if (tid < 128) {
        const int qg = qtile * 128 + tid;
        Cand* dst = cand + ((size_t)qg * nsuper + sup) * NC;
#pragma unroll
        for (int k = 0; k < NC; ++k) { Cand c; c.v = rv[k]; c.i = ri[k]; dst[k] = c; }
    }
}

// ---------------------------------------------------------------------------
// Kernel 2: per query, reduce nsuper*16 candidates to global approx top-16.
// ---------------------------------------------------------------------------
__global__ __launch_bounds__(64)
void knn_top16(const Cand* __restrict__ cand, int* __restrict__ top_idx, int ncand)
{
    __shared__ float lv[64][NC];
    __shared__ int   li[64][NC];

    const int q = blockIdx.x;
    const int lane = threadIdx.x;
    const Cand* rowp = cand + (size_t)q * ncand;

    float tv[NC]; int ti[NC];
#pragma unroll
    for (int k = 0; k < NC; ++k) { tv[k] = -INFINITY; ti[k] = 0; }

#pragma unroll 1
    for (int e = lane; e < ncand; e += 64) {
        Cand c = rowp[e];
        if (better(c.v, c.i, tv[NC - 1], ti[NC - 1])) {
            float cv = c.v; int ci = c.i;
#pragma unroll
            for (int k = 0; k < NC; ++k) {
                bool b = better(cv, ci, tv[k], ti[k]);
                float nv = b ? cv : tv[k]; int ni = b ? ci : ti[k];
                float ov = b ? tv[k] : cv; int oi = b ? ti[k] : ci;
                tv[k] = nv; ti[k] = ni; cv = ov; ci = oi;
            }
        }
    }

#pragma unroll
    for (int k = 0; k < NC; ++k) { lv[lane][k] = tv[k]; li[lane][k] = ti[k]; }
    __syncthreads();

    if (lane == 0) {
#pragma unroll 1
        for (int l = 1; l < 64; ++l) {
#pragma unroll 1
            for (int k = 0; k < NC; ++k) {
                float v = lv[l][k]; int i = li[l][k];
                if (!better(v, i, tv[NC - 1], ti[NC - 1])) break;
                float cv = v; int ci = i;
#pragma unroll
                for (int kk = 0; kk < NC; ++kk) {
                    bool b = better(cv, ci, tv[kk], ti[kk]);
                    float nv = b ? cv : tv[kk]; int ni = b ? ci : ti[kk];
                    float ov = b ? tv[kk] : cv; int oi = b ? ti[kk] : ci;
                    tv[kk] = nv; ti[kk] = ni; cv = ov; ci = oi;
                }
            }
        }
#pragma unroll
        for (int k = 0; k < NC; ++k) top_idx[q * NC + k] = ti[k];
    }
}

// ---------------------------------------------------------------------------
// Kernel 3: exact fp64 rescore of the 16 candidates, top-k, gather-average.
// ---------------------------------------------------------------------------
__global__ __launch_bounds__(256)
void knn_rescore(const float* __restrict__ Qm, const float* __restrict__ Mm,
                 const float* __restrict__ Sm, const int* __restrict__ topk_p,
                 const int* __restrict__ top_idx, float* __restrict__ outp)
{
    const int q   = blockIdx.x;
    const int tid = threadIdx.x;
    const int wid = tid >> 6, lane = tid & 63;

    __shared__ double sval[NC];
    __shared__ int    sidx[NC];
    __shared__ int    chosen[NC];

    int k = *topk_p;
    if (k > NC) k = NC;
    if (k < 1)  k = 1;

    const float* qrow = Qm + (size_t)q * D_DIM;
#pragma unroll 1
    for (int ci = wid; ci < NC; ci += 4) {
        int idx = top_idx[q * NC + ci];
        if (idx < 0)    idx = 0;
        if (idx >= N_M) idx = N_M - 1;
        const f32x4* mp = (const f32x4*)(Mm + (size_t)idx * D_DIM) + lane * 4;
        const f32x4* qp = (const f32x4*)qrow + lane * 4;
        double dot = 0.0, ss = 0.0;
#pragma unroll
        for (int j = 0; j < 4; ++j) {
            f32x4 mv = mp[j], qv = qp[j];
#pragma unroll
            for (int u = 0; u < 4; ++u) {
                dot += (double)mv[u] * (double)qv[u];
                ss  += (double)mv[u] * (double)mv[u];
            }
        }
#pragma unroll
        for (int off = 1; off <= 32; off <<= 1) {
            dot += __shfl_xor(dot, off, 64);
            ss  += __shfl_xor(ss, off, 64);
        }
        if (lane == 0) { sval[ci] = ss > 0.0 ? dot / sqrt(ss) : -1e300; sidx[ci] = idx; }
    }
    __syncthreads();

    if (tid == 0) {
        unsigned used = 0;
        for (int j = 0; j < k; ++j) {
            int best = -1;
            for (int i = 0; i < NC; ++i) {
                if (used & (1u << i)) continue;
                if (best < 0 || sval[i] > sval[best] ||
                    (sval[i] == sval[best] && sidx[i] < sidx[best])) best = i;
            }
            used |= 1u << best;
            chosen[j] = sidx[best];
        }
    }
    __syncthreads();

    const int d0 = tid * 4;
    f32x4 a = zero4();
    for (int j = 0; j < k; ++j) {
        f32x4 s4 = *(const f32x4*)(Sm + (size_t)chosen[j] * D_DIM + d0);
        a = a + s4;
    }
    const float inv = 1.0f / (float)k;
    a = a * inv;
    *(f32x4*)(outp + (size_t)q * D_DIM + d0) = a;
}

// ---------------------------------------------------------------------------
// Fallback: round-5 brute force, verbatim (proven: passed, absmax 0.0).
// ---------------------------------------------------------------------------
#define FNC 8
__global__ __launch_bounds__(256)
void knn_all(const float* __restrict__ Qm, const float* __restrict__ Mm,
             const float* __restrict__ Sm, const int* __restrict__ topk_p,
             float* __restrict__ outp)
{
    __shared__ float  qs[D_DIM];
    __shared__ float  wv[4][FNC];
    __shared__ int    wi[4][FNC];
    __shared__ int    cand8[FNC];
    __shared__ double dval[FNC];
    __shared__ int    chosen[FNC];
    __shared__ int    sk;

    const int q    = blockIdx.x;
    const int tid  = threadIdx.x;
    const int wid  = tid >> 6;
    const int lane = tid & 63;

    for (int i = tid; i < D_DIM / 4; i += 256)
        ((f32x4*)qs)[i] = ((const f32x4*)(Qm + (size_t)q * D_DIM))[i];
    __syncthreads();

    float tv[FNC]; int ti[FNC];
#pragma unroll
    for (int k = 0; k < FNC; ++k) { tv[k] = -INFINITY; ti[k] = 0; }

    for (int r = wid; r < N_M; r += 4) {
        const f32x4* mp = (const f32x4*)(Mm + (size_t)r * D_DIM) + lane * 4;
        const f32x4* qp = (const f32x4*)qs + lane * 4;
        float dot = 0.f, ss = 0.f;
#pragma unroll
        for (int j = 0; j < 4; ++j) {
            f32x4 mv = mp[j], qv = qp[j];
#pragma unroll
            for (int u = 0; u < 4; ++u) { dot += mv[u] * qv[u]; ss += mv[u] * mv[u]; }
        }
#pragma unroll
        for (int off = 1; off <= 32; off <<= 1) {
            dot += __shfl_xor(dot, off, 64);
            ss  += __shfl_xor(ss,  off, 64);
        }
        float s = ss > 0.f ? dot * rsqrtf(ss) : -INFINITY;
        if (better(s, r, tv[FNC - 1], ti[FNC - 1])) {
            float cv = s; int ci = r;
#pragma unroll
            for (int k = 0; k < FNC; ++k) {
                bool b = better(cv, ci, tv[k], ti[k]);
                float nv = b ? cv : tv[k]; int ni = b ? ci : ti[k];
                float ov = b ? tv[k] : cv; int oi = b ? ti[k] : ci;
                tv[k] = nv; ti[k] = ni; cv = ov; ci = oi;
            }
        }
    }

    if (lane == 0)
#pragma unroll
        for (int k = 0; k < FNC; ++k) { wv[wid][k] = tv[k]; wi[wid][k] = ti[k]; }
    __syncthreads();

    if (tid == 0) {
        unsigned used = 0;
        for (int j = 0; j < FNC; ++j) {
            float bv = -INFINITY; int bi = 0; int bs = -1;
            for (int s = 0; s < 4 * FNC; ++s) {
                if (used & (1u << s)) continue;
                float v = wv[s >> 3][s & 7]; int i = wi[s >> 3][s & 7];
                if (bs < 0 || better(v, i, bv, bi)) { bv = v; bi = i; bs = s; }
            }
            used |= 1u << bs;
            cand8[j] = bi;
        }
        int kk = *topk_p;
        if (kk < 1) kk = 1;
        if (kk > FNC) kk = FNC;
        sk = kk;
    }
    __syncthreads();

    for (int ci = wid; ci < FNC; ci += 4) {
        int idx = cand8[ci];
        if (idx < 0)     idx = 0;
        if (idx >= N_M)  idx = N_M - 1;
        const f32x4* mp = (const f32x4*)(Mm + (size_t)idx * D_DIM) + lane * 4;
        const f32x4* qp = (const f32x4*)qs + lane * 4;
        double dot = 0.0, ss = 0.0;
#pragma unroll
        for (int j = 0; j < 4; ++j) {
            f32x4 mv = mp[j], qv = qp[j];
#pragma unroll
            for (int u = 0; u < 4; ++u) {
                dot += (double)mv[u] * (double)qv[u];
                ss  += (double)mv[u] * (double)mv[u];
            }
        }
#pragma unroll
        for (int off = 1; off <= 32; off <<= 1) {
            dot += __shfl_xor(dot, off, 64);
            ss  += __shfl_xor(ss, off, 64);
        }
        if (lane == 0) dval[ci] = ss > 0.0 ? dot / sqrt(ss) : -1e300;
    }
    __syncthreads();

    if (tid == 0) {
        int kk = sk;
        unsigned used = 0;
        for (int j = 0; j < kk; ++j) {
            int best = -1;
            for (int i = 0; i < FNC; ++i) {
                if (used & (1u << i)) continue;
                if (best < 0 || dval[i] > dval[best] ||
                    (dval[i] == dval[best] && cand8[i] < cand8[best])) best = i;
            }
            used |= 1u << best;
            chosen[j] = cand8[best];
        }
    }
    __syncthreads();

    const int kk = sk;
    const int d0 = tid * 4;
    f32x4 a = zero4();
    for (int j = 0; j < kk; ++j) {
        f32x4 s4 = *(const f32x4*)(Sm + (size_t)chosen[j] * D_DIM + d0);
        a = a + s4;
    }
    const float inv = 1.0f / (float)kk;
    a = a * inv;
    *(f32x4*)(outp + (size_t)q * D_DIM + d0) = a;
}

// ---------------------------------------------------------------------------
extern "C" void kernel_launch(void* const* d_in, const int* in_sizes, int n_in,
                              void* d_out, int out_size, void* d_ws, size_t ws_size,
                              hipStream_t stream)
{
    (void)in_sizes; (void)n_in; (void)out_size;

    const float* Qm   = (const float*)d_in[0];
    const float* Mm   = (const float*)d_in[1];
    const float* Sm   = (const float*)d_in[2];
    const int*   topk = (const int*)d_in[3];
    float*       outp = (float*)d_out;

    const size_t A511      = 511;
    const size_t mh_bytes  = (((size_t)MPAD * D_DIM * sizeof(_Float16)) + A511) & ~A511;
    const size_t qh_bytes  = (size_t)QPAD * D_DIM * sizeof(_Float16);                 // 4 MiB
    const size_t inv_bytes = ((size_t)N_M * sizeof(float) + A511) & ~A511;
    const size_t ti_bytes  = (((size_t)T_Q * NC * sizeof(int)) + A511) & ~A511;
    const size_t per_sup   = (size_t)QPAD * NC * sizeof(Cand);                        // 256 KiB

    if (d_ws != nullptr) {
        // ---- main path: ns must be a multiple of 8 (XCD grouping) ----
        const int ns_opts[5] = { 96, 48, 24, 16, 8 };
        int ns = 0;
        for (int i = 0; i < 5; ++i) {
            size_t need = mh_bytes + qh_bytes + ti_bytes + (size_t)ns_opts[i] * per_sup;
            if (need <= ws_size) { ns = ns_opts[i]; break; }
        }
        if (ns >= 8) {
            const int tpbn = (NTILES + ns - 1) / ns;

            _Float16* Mh      = (_Float16*)d_ws;
            _Float16* Qh      = (_Float16*)((char*)d_ws + mh_bytes);
            int*      top_idx = (int*)((char*)d_ws + mh_bytes + qh_bytes);
            Cand*     cand    = (Cand*)((char*)d_ws + mh_bytes + qh_bytes + ti_bytes);
            float*    pout    = (float*)Qh;   // probe scratch; qcvt rewrites each replay

            hipLaunchKernelGGL(knn_qcvt, dim3(QPAD * D_DIM / 2048), dim3(256), 0, stream,
                               Qm, Qh);
            hipLaunchKernelGGL(knn_mcvt, dim3(MPAD / 4), dim3(256), 0, stream,
                               Mm, Mh);
            hipLaunchKernelGGL(knn_gemm_select_h, dim3(QTILES * ns), dim3(256), 0, stream,
                               Qh, Mh, cand, tpbn, ns);
            hipLaunchKernelGGL(knn_top16, dim3(T_Q), dim3(64), 0, stream,
                               cand, top_idx, ns * NC);
            hipLaunchKernelGGL(knn_rescore, dim3(T_Q), dim3(256), 0, stream,
                               Qm, Mm, Sm, topk, top_idx, outp);

            // diagnostics at quarter work (output computed above; scratch-only)
            const int tpbn_p = (tpbn + 3) / 4;
            hipLaunchKernelGGL((knn_probe<0>), dim3(QTILES * ns), dim3(256), 0, stream,
                               Qh, Mh, pout, tpbn_p);
            hipLaunchKernelGGL((knn_probe<1>), dim3(QTILES * ns), dim3(256), 0, stream,
                               Qh, Mh, pout, tpbn_p);
            hipLaunchKernelGGL((knn_probe<2>), dim3(QTILES * ns), dim3(256), 0, stream,
                               Qh, Mh, pout, tpbn_p);
            return;
        }

        // ---- middle path: round-7 structure (~20 MB of workspace) ----
        long long avail = (long long)ws_size
                        - (long long)(inv_bytes + qh_bytes + ti_bytes);
        int ns2 = avail > 0 ? (int)(avail / (long long)per_sup) : 0;
        if (ns2 > 64) ns2 = 64;
        if (ns2 >= 1) {
            int tpbn = (NTILES + ns2 - 1) / ns2;
            ns2 = (NTILES + tpbn - 1) / tpbn;

            float*    invn    = (float*)d_ws;
            _Float16* Qh      = (_Float16*)((char*)d_ws + inv_bytes);
            int*      top_idx = (int*)((char*)d_ws + inv_bytes + qh_bytes);
            Cand*     cand    = (Cand*)((char*)d_ws + inv_bytes + qh_bytes + ti_bytes);

            hipLaunchKernelGGL(knn_qcvt, dim3(QPAD * D_DIM / 2048), dim3(256), 0, stream,
                               Qm, Qh);
            hipLaunchKernelGGL(knn_norms, dim3((N_M + 3) / 4), dim3(256), 0, stream,
                               Mm, invn);
            hipLaunchKernelGGL(knn_gemm_select, dim3(QTILES * ns2), dim3(256), 0, stream,
                               Qh, Mm, invn, cand, tpbn, ns2);
            hipLaunchKernelGGL(knn_top16, dim3(T_Q), dim3(64), 0, stream,
                               cand, top_idx, ns2 * NC);
            hipLaunchKernelGGL(knn_rescore, dim3(T_Q), dim3(256), 0, stream,
                               Qm, Mm, Sm, topk, top_idx, outp);
            return;
        }
    }

    // ---- last resort: zero-workspace brute force ----
    hipLaunchKernelGGL(knn_all, dim3(T_Q), dim3(256), 0, stream,
                       Qm, Mm, Sm, topk, outp);
}

// Round 12
// 1421.028 us; speedup vs baseline: 25.5849x; 2.4737x over previous
//
#include <hip/hip_runtime.h>
#include <math.h>

#define T_Q    2000
#define N_M    100000
#define D_DIM  1024
#define QTILES 16
#define NTILES 782          // ceil(100000/128)
#define MPAD   (NTILES * 128)   // 100096 zero-padded fp16 M rows
#define BK     32
#define KSTEPS (D_DIM / BK) // 32
#define LDH    40           // middle-path A/B LDS row stride in halves (80 B)
#define SSW    72           // middle-path score tile row stride in halves
#define NC     16           // rescore candidate superset per query
#define QPAD   2048
#define TK     4            // per-thread per-query kept candidates (main path)

typedef _Float16 f16x8 __attribute__((ext_vector_type(8)));
typedef _Float16 f16x4 __attribute__((ext_vector_type(4)));
typedef float    f32x4 __attribute__((ext_vector_type(4)));
typedef unsigned int u32;

struct __align__(8) Cand { float v; int i; };
static_assert(sizeof(Cand) == 8, "cand size");

__device__ __forceinline__ bool better(float av, int ai, float bv, int bi) {
    return (av > bv) || (av == bv && ai < bi);
}

__device__ __forceinline__ f32x4 zero4() {
    f32x4 z; z[0] = 0.f; z[1] = 0.f; z[2] = 0.f; z[3] = 0.f; return z;
}

// async global->LDS, 16 B per lane (dest pattern: wave-uniform base + lane*16)
__device__ __forceinline__ void gload16(const _Float16* g, _Float16* l) {
    const __attribute__((address_space(1))) u32* gp =
        (const __attribute__((address_space(1))) u32*)g;
    __attribute__((address_space(3))) u32* lp =
        (__attribute__((address_space(3))) u32*)l;
    __builtin_amdgcn_global_load_lds(gp, lp, 16, 0, 0);
}

// ---------------------------------------------------------------------------
// Kernel Q: convert query matrix to fp16 once (rows >= T_Q zero-filled).
// ---------------------------------------------------------------------------
__global__ __launch_bounds__(256)
void knn_qcvt(const float* __restrict__ Qm, _Float16* __restrict__ Qh)
{
    const size_t base = (size_t)blockIdx.x * 2048 + (size_t)threadIdx.x * 8;
    const int row = (int)(base >> 10);
    f16x8 h;
    if (row < T_Q) {
        f32x4 a = *(const f32x4*)(Qm + base);
        f32x4 b = *(const f32x4*)(Qm + base + 4);
#pragma unroll
        for (int j = 0; j < 4; ++j) { h[j] = (_Float16)a[j]; h[4 + j] = (_Float16)b[j]; }
    } else {
#pragma unroll
        for (int j = 0; j < 8; ++j) h[j] = (_Float16)0.f;
    }
    *(f16x8*)(Qh + base) = h;
}

// ---------------------------------------------------------------------------
// Kernel M: fused norm + prescale + fp16 convert + zero-pad of M.
// ---------------------------------------------------------------------------
__global__ __launch_bounds__(256)
void knn_mcvt(const float* __restrict__ Mm, _Float16* __restrict__ Mh)
{
    const int wid  = threadIdx.x >> 6;
    const int lane = threadIdx.x & 63;
    const int r    = blockIdx.x * 4 + wid;   // grid covers MPAD rows
    f16x8 h0, h1;
    if (r < N_M) {
        const f32x4* mp = (const f32x4*)(Mm + (size_t)r * D_DIM) + lane * 4;
        f32x4 v0 = mp[0], v1 = mp[1], v2 = mp[2], v3 = mp[3];
        float ss = 0.f;
#pragma unroll
        for (int u = 0; u < 4; ++u)
            ss += v0[u] * v0[u] + v1[u] * v1[u] + v2[u] * v2[u] + v3[u] * v3[u];
#pragma unroll
        for (int off = 1; off <= 32; off <<= 1) ss += __shfl_xor(ss, off, 64);
        const float inv = ss > 0.f ? rsqrtf(ss) : 0.f;
#pragma unroll
        for (int u = 0; u < 4; ++u) {
            h0[u]     = (_Float16)(v0[u] * inv);
            h0[4 + u] = (_Float16)(v1[u] * inv);
            h1[u]     = (_Float16)(v2[u] * inv);
            h1[4 + u] = (_Float16)(v3[u] * inv);
        }
    } else {
#pragma unroll
        for (int j = 0; j < 8; ++j) { h0[j] = (_Float16)0.f; h1[j] = (_Float16)0.f; }
    }
    _Float16* dst = Mh + (size_t)r * D_DIM + lane * 16;
    *(f16x8*)dst       = h0;
    *(f16x8*)(dst + 8) = h1;
}

// ---------------------------------------------------------------------------
// Kernel 1 (main): fp16 MFMA scores via global_load_lds. Selection is a
// per-thread in-register running top-4 per query column (gated by a 15-fmax
// max test) — NO LDS dump, NO scan, NO epilogue barriers. Each thread writes
// its 4 sorted candidates per query straight to global; knn_top16 merges.
// ---------------------------------------------------------------------------
__global__ __launch_bounds__(256)
void knn_gemm_select_h(const _Float16* __restrict__ Qh,
                       const _Float16* __restrict__ Mh,
                       Cand* __restrict__ cand, int tpbn, int nsuper)
{
    __shared__ _Float16 As[128][32];    // 8192 B
    __shared__ _Float16 Bs[128][32];    // 8192 B   (total 16384 B)

    // XCD-aware mapping: hardware assigns bid%8 -> XCD (round-robin).
    const int bid   = blockIdx.x;
    const int c8    = bid & 7;          // XCD slot
    const int jj0   = bid >> 3;
    const int qtile = jj0 & 15;         // 16 sharers of a sup are 8 bids apart
    const int sup   = c8 + 8 * (jj0 >> 4);

    const int nt0 = sup * tpbn;
    int nt1 = nt0 + tpbn;
    if (nt1 > NTILES) nt1 = NTILES;

    const int tid  = threadIdx.x;
    const int lane = tid & 63;
    const int wid  = tid >> 6;
    const int wr   = wid >> 1;
    const int wc   = wid & 1;
    const int l15  = lane & 15;
    const int lg   = lane >> 4;

    const int arow = tid >> 2;          // 0..63
    const int acol = (tid & 3) * 8;     // halves

    _Float16* Adst0 = &As[arow][acol];
    _Float16* Adst1 = &As[64 + arow][acol];
    _Float16* Bdst0 = &Bs[arow][acol];
    _Float16* Bdst1 = &Bs[64 + arow][acol];

    const _Float16* Bb = Qh + ((size_t)(qtile * 128 + arow) << 10) + acol;

    // per-thread running top-4 for each of this thread's 4 query columns
    float rv[4][TK]; int ri[4][TK];
#pragma unroll
    for (int q = 0; q < 4; ++q)
#pragma unroll
        for (int k = 0; k < TK; ++k) { rv[q][k] = -INFINITY; ri[q][k] = 0; }

#pragma unroll 1
    for (int ntile = nt0; ntile < nt1; ++ntile) {
        const _Float16* Ab = Mh + ((size_t)(ntile * 128 + arow) << 10) + acol;

        f32x4 acc[4][4];
#pragma unroll
        for (int i = 0; i < 4; ++i)
#pragma unroll
            for (int j = 0; j < 4; ++j) acc[i][j] = zero4();

        for (int t = 0; t < KSTEPS; ++t) {
            const int k0 = t * BK;
            gload16(Ab + k0, Adst0);
            gload16(Ab + k0 + (64 << 10), Adst1);
            gload16(Bb + k0, Bdst0);
            gload16(Bb + k0 + (64 << 10), Bdst1);

            __syncthreads();

            f16x8 af[4], bf[4];
#pragma unroll
            for (int f = 0; f < 4; ++f) {
                af[f] = *(const f16x8*)&As[wr * 64 + f * 16 + l15][lg * 8];
                bf[f] = *(const f16x8*)&Bs[wc * 64 + f * 16 + l15][lg * 8];
            }
#pragma unroll
            for (int i = 0; i < 4; ++i)
#pragma unroll
                for (int j = 0; j < 4; ++j)
                    acc[i][j] = __builtin_amdgcn_mfma_f32_16x16x32_f16(
                        af[i], bf[j], acc[i][j], 0, 0, 0);

            __syncthreads();
        }

        // fold this tile's 16 scores per query into the running top-4.
        // row of acc[i][q][r] = rowbase + i*16 + r; query col = qcol(q).
        const int rowbase = ntile * 128 + wr * 64 + lg * 4;
#pragma unroll
        for (int q = 0; q < 4; ++q) {
            float mx = acc[0][q][0];
#pragma unroll
            for (int i = 0; i < 4; ++i)
#pragma unroll
                for (int r = 0; r < 4; ++r) mx = fmaxf(mx, acc[i][q][r]);
            if (mx >= rv[q][TK - 1]) {          // rare: tile can contribute
#pragma unroll
                for (int i = 0; i < 4; ++i)
#pragma unroll
                    for (int r = 0; r < 4; ++r) {
                        const int ng = rowbase + i * 16 + r;
                        float cv = acc[i][q][r];
                        if (ng < N_M && better(cv, ng, rv[q][TK - 1], ri[q][TK - 1])) {
                            int ci = ng;
#pragma unroll
                            for (int k = 0; k < TK; ++k) {
                                bool b = better(cv, ci, rv[q][k], ri[q][k]);
                                float nv = b ? cv : rv[q][k]; int ni = b ? ci : ri[q][k];
                                float ov = b ? rv[q][k] : cv; int oi = b ? ri[q][k] : ci;
                                rv[q][k] = nv; ri[q][k] = ni; cv = ov; ci = oi;
                            }
                        }
                    }
            }
        }
    }

    // write per-thread sorted-4 lists; 8 owner threads per query column.
    const int owner = wr * 4 + lg;      // 0..7
#pragma unroll
    for (int q = 0; q < 4; ++q) {
        const int qg = qtile * 128 + wc * 64 + q * 16 + l15;
        Cand* dst = cand + (((size_t)qg * nsuper + sup) * 8 + owner) * TK;
#pragma unroll
        for (int k = 0; k < TK; ++k) {
            Cand c; c.v = rv[q][k]; c.i = ri[q][k];
            dst[k] = c;
        }
    }
}

// ---------------------------------------------------------------------------
// Kernel 2: per query, reduce ncand candidates to global approx top-16.
// ---------------------------------------------------------------------------
__global__ __launch_bounds__(64)
void knn_top16(const Cand* __restrict__ cand, int* __restrict__ top_idx, int ncand)
{
    __shared__ float lv[64][NC];
    __shared__ int   li[64][NC];

    const int q = blockIdx.x;
    const int lane = threadIdx.x;
    const Cand* rowp = cand + (size_t)q * ncand;

    float tv[NC]; int ti[NC];
#pragma unroll
    for (int k = 0; k < NC; ++k) { tv[k] = -INFINITY; ti[k] = 0; }

#pragma unroll 1
    for (int e = lane; e < ncand; e += 64) {
        Cand c = rowp[e];
        if (better(c.v, c.i, tv[NC - 1], ti[NC - 1])) {
            float cv = c.v; int ci = c.i;
#pragma unroll
            for (int k = 0; k < NC; ++k) {
                bool b = better(cv, ci, tv[k], ti[k]);
                float nv = b ? cv : tv[k]; int ni = b ? ci : ti[k];
                float ov = b ? tv[k] : cv; int oi = b ? ti[k] : ci;
                tv[k] = nv; ti[k] = ni; cv = ov; ci = oi;
            }
        }
    }

#pragma unroll
    for (int k = 0; k < NC; ++k) { lv[lane][k] = tv[k]; li[lane][k] = ti[k]; }
    __syncthreads();

    if (lane == 0) {
#pragma unroll 1
        for (int l = 1; l < 64; ++l) {
#pragma unroll 1
            for (int k = 0; k < NC; ++k) {
                float v = lv[l][k]; int i = li[l][k];
                if (!better(v, i, tv[NC - 1], ti[NC - 1])) break; // lists sorted desc
                float cv = v; int ci = i;
#pragma unroll
                for (int kk = 0; kk < NC; ++kk) {
                    bool b = better(cv, ci, tv[kk], ti[kk]);
                    float nv = b ? cv : tv[kk]; int ni = b ? ci : ti[kk];
                    float ov = b ? tv[kk] : cv; int oi = b ? ti[kk] : ci;
                    tv[kk] = nv; ti[kk] = ni; cv = ov; ci = oi;
                }
            }
        }
#pragma unroll
        for (int k = 0; k < NC; ++k) top_idx[q * NC + k] = ti[k];
    }
}

// ---------------------------------------------------------------------------
// Kernel 3: exact fp64 rescore of the 16 candidates, top-k, gather-average.
// ---------------------------------------------------------------------------
__global__ __launch_bounds__(256)
void knn_rescore(const float* __restrict__ Qm, const float* __restrict__ Mm,
                 const float* __restrict__ Sm, const int* __restrict__ topk_p,
                 const int* __restrict__ top_idx, float* __restrict__ outp)
{
    const int q   = blockIdx.x;
    const int tid = threadIdx.x;
    const int wid = tid >> 6, lane = tid & 63;

    __shared__ double sval[NC];
    __shared__ int    sidx[NC];
    __shared__ int    chosen[NC];

    int k = *topk_p;
    if (k > NC) k = NC;
    if (k < 1)  k = 1;

    const float* qrow = Qm + (size_t)q * D_DIM;
#pragma unroll 1
    for (int ci = wid; ci < NC; ci += 4) {
        int idx = top_idx[q * NC + ci];
        if (idx < 0)    idx = 0;
        if (idx >= N_M) idx = N_M - 1;
        const f32x4* mp = (const f32x4*)(Mm + (size_t)idx * D_DIM) + lane * 4;
        const f32x4* qp = (const f32x4*)qrow + lane * 4;
        double dot = 0.0, ss = 0.0;
#pragma unroll
        for (int j = 0; j < 4; ++j) {
            f32x4 mv = mp[j], qv = qp[j];
#pragma unroll
            for (int u = 0; u < 4; ++u) {
                dot += (double)mv[u] * (double)qv[u];
                ss  += (double)mv[u] * (double)mv[u];
            }
        }
#pragma unroll
        for (int off = 1; off <= 32; off <<= 1) {
            dot += __shfl_xor(dot, off, 64);
            ss  += __shfl_xor(ss, off, 64);
        }
        if (lane == 0) { sval[ci] = ss > 0.0 ? dot / sqrt(ss) : -1e300; sidx[ci] = idx; }
    }
    __syncthreads();

    if (tid == 0) {
        unsigned used = 0;
        for (int j = 0; j < k; ++j) {
            int best = -1;
            for (int i = 0; i < NC; ++i) {
                if (used & (1u << i)) continue;
                if (best < 0 || sval[i] > sval[best] ||
                    (sval[i] == sval[best] && sidx[i] < sidx[best])) best = i;
            }
            used |= 1u << best;
            chosen[j] = sidx[best];
        }
    }
    __syncthreads();

    const int d0 = tid * 4;
    f32x4 a = zero4();
    for (int j = 0; j < k; ++j) {
        f32x4 s4 = *(const f32x4*)(Sm + (size_t)chosen[j] * D_DIM + d0);
        a = a + s4;
    }
    const float inv = 1.0f / (float)k;
    a = a * inv;
    *(f32x4*)(outp + (size_t)q * D_DIM + d0) = a;
}

// ---------------------------------------------------------------------------
// Middle path (round-7 verbatim, proven): norms + fp32-staged GEMM select.
// ---------------------------------------------------------------------------
__global__ __launch_bounds__(256)
void knn_norms(const float* __restrict__ Mm, float* __restrict__ invn)
{
    const int wid  = threadIdx.x >> 6;
    const int lane = threadIdx.x & 63;
    const int r    = blockIdx.x * 4 + wid;
    if (r >= N_M) return;
    const f32x4* mp = (const f32x4*)(Mm + (size_t)r * D_DIM) + lane * 4;
    float ss = 0.f;
#pragma unroll
    for (int j = 0; j < 4; ++j) {
        f32x4 v = mp[j];
#pragma unroll
        for (int u = 0; u < 4; ++u) ss += v[u] * v[u];
    }
#pragma unroll
    for (int off = 1; off <= 32; off <<= 1) ss += __shfl_xor(ss, off, 64);
    if (lane == 0) invn[r] = ss > 0.f ? rsqrtf(ss) : 0.f;
}

__global__ __launch_bounds__(256)
void knn_gemm_select(const _Float16* __restrict__ Qh, const float* __restrict__ Mm,
                     const float* __restrict__ invn, Cand* __restrict__ cand,
                     int tpbn, int nsuper)
{
    __shared__ _Float16 As[128][LDH];
    __shared__ _Float16 Bs[128][LDH];
    __shared__ _Float16 Ss[128][SSW];
    __shared__ float    sinv[128];

    const int qtile = blockIdx.x & (QTILES - 1);
    const int sup   = blockIdx.x >> 4;
    const int nt0   = sup * tpbn;
    int nt1 = nt0 + tpbn;
    if (nt1 > NTILES) nt1 = NTILES;

    const int tid = threadIdx.x;
    const int row = tid >> 1;
    const int kh  = tid & 1;

    const int qrow_g = qtile * 128 + row;
    const _Float16* bbase = Qh + (size_t)qrow_g * D_DIM + kh * 16;

    const int lane = tid & 63;
    const int wid  = tid >> 6;
    const int wr   = wid >> 1;
    const int wc   = wid & 1;
    const int l15  = lane & 15;
    const int lg   = lane >> 4;

    float rv[NC]; int ri[NC];
#pragma unroll
    for (int k = 0; k < NC; ++k) { rv[k] = -INFINITY; ri[k] = 0; }

#pragma unroll 1
    for (int ntile = nt0; ntile < nt1; ++ntile) {
        const int nrow_g = ntile * 128 + row;
        const bool a_ok  = nrow_g < N_M;
        const float* abase = Mm + (size_t)nrow_g * D_DIM + kh * 16;

        f32x4 acc[4][4];
#pragma unroll
        for (int i = 0; i < 4; ++i)
#pragma unroll
            for (int j = 0; j < 4; ++j) acc[i][j] = zero4();

        f32x4 ar[4];
        f16x8 brh[2];
#pragma unroll
        for (int i = 0; i < 4; ++i) ar[i] = a_ok ? ((const f32x4*)abase)[i] : zero4();
        brh[0] = *(const f16x8*)(bbase);
        brh[1] = *(const f16x8*)(bbase + 8);

#pragma unroll 1
        for (int t = 0; t < KSTEPS; ++t) {
            __syncthreads();

            f16x8 ha0, ha1;
#pragma unroll
            for (int i = 0; i < 2; ++i)
#pragma unroll
                for (int j = 0; j < 4; ++j) {
                    ha0[i * 4 + j] = (_Float16)ar[i][j];
                    ha1[i * 4 + j] = (_Float16)ar[i + 2][j];
                }
            *(f16x8*)&As[row][kh * 16]     = ha0;
            *(f16x8*)&As[row][kh * 16 + 8] = ha1;
            *(f16x8*)&Bs[row][kh * 16]     = brh[0];
            *(f16x8*)&Bs[row][kh * 16 + 8] = brh[1];

            __syncthreads();

            if (t + 1 < KSTEPS) {
                const float*    ap = abase + (t + 1) * BK;
                const _Float16* bp = bbase + (t + 1) * BK;
#pragma unroll
                for (int i = 0; i < 4; ++i) ar[i] = a_ok ? ((const f32x4*)ap)[i] : zero4();
                brh[0] = *(const f16x8*)(bp);
                brh[1] = *(const f16x8*)(bp + 8);
            }

            f16x8 af[4], bf[4];
#pragma unroll
            for (int f = 0; f < 4; ++f) {
                af[f] = *(const f16x8*)&As[wr * 64 + f * 16 + l15][lg * 8];
                bf[f] = *(const f16x8*)&Bs[wc * 64 + f * 16 + l15][lg * 8];
            }
#pragma unroll
            for (int i = 0; i < 4; ++i)
#pragma unroll
                for (int j = 0; j < 4; ++j)
                    acc[i][j] = __builtin_amdgcn_mfma_f32_16x16x32_f16(
                        af[i], bf[j], acc[i][j], 0, 0, 0);
        }

        if (tid < 128) {
            const int r = ntile * 128 + tid;
            sinv[tid] = (r < N_M) ? invn[r] : 0.f;
        }

#pragma unroll 1
        for (int h = 0; h < 2; ++h) {
            __syncthreads();
            if (wr == h) {
#pragma unroll
                for (int fr = 0; fr < 4; ++fr)
#pragma unroll
                    for (int fc = 0; fc < 4; ++fc) {
                        f16x4 v;
#pragma unroll
                        for (int r = 0; r < 4; ++r) v[r] = (_Float16)acc[fr][fc][r];
                        *(f16x4*)&Ss[wc * 64 + fc * 16 + l15][fr * 16 + lg * 4] = v;
                    }
            }
            __syncthreads();

            if (tid < 128) {
                const int base = ntile * 128 + h * 64;
                int nval = N_M - base;
                if (nval > 64) nval = 64;
#pragma unroll 1
                for (int c = 0; c < nval; c += 8) {
                    f16x8 sv = *(const f16x8*)&Ss[tid][c];
                    f32x4 sa = *(const f32x4*)&sinv[h * 64 + c];
                    f32x4 sb = *(const f32x4*)&sinv[h * 64 + c + 4];
                    const int lim = (nval - c >= 8) ? 8 : (nval - c);
                    float s[8];
#pragma unroll
                    for (int j = 0; j < 4; ++j) {
                        s[j]     = (float)sv[j] * sa[j];
                        s[4 + j] = (float)sv[4 + j] * sb[j];
                    }
                    if (lim < 8)
#pragma unroll
                        for (int j = 0; j < 8; ++j)
                            if (j >= lim) s[j] = -INFINITY;
                    float m01 = fmaxf(s[0], s[1]), m23 = fmaxf(s[2], s[3]);
                    float m45 = fmaxf(s[4], s[5]), m67 = fmaxf(s[6], s[7]);
                    float mx = fmaxf(fmaxf(m01, m23), fmaxf(m45, m67));
                    if (mx >= rv[NC - 1]) {
#pragma unroll 1
                        for (int j = 0; j < 8; ++j) {
                            if (j >= lim) break;
                            float cv = s[j]; int ci = base + c + j;
                            if (better(cv, ci, rv[NC - 1], ri[NC - 1])) {
#pragma unroll
                                for (int k = 0; k < NC; ++k) {
                                    bool b = better(cv, ci, rv[k], ri[k]);
                                    float nv = b ? cv : rv[k]; int ni = b ? ci : ri[k];
                                    float ov = b ? rv[k] : cv; int oi = b ? ri[k] : ci;
                                    rv[k] = nv; ri[k] = ni; cv = ov; ci = oi;
                                }
                            }
                        }
                    }
                }
            }
        }
    }

    if (tid < 128) {
        const int qg = qtile * 128 + tid;
        Cand* dst = cand + ((size_t)qg * nsuper + sup) * NC;
#pragma unroll
        for (int k = 0; k < NC; ++k) { Cand c; c.v = rv[k]; c.i = ri[k]; dst[k] = c; }
    }
}

// ---------------------------------------------------------------------------
// Fallback: round-5 brute force, verbatim (proven: passed, absmax 0.0).
// ---------------------------------------------------------------------------
#define FNC 8
__global__ __launch_bounds__(256)
void knn_all(const float* __restrict__ Qm, const float* __restrict__ Mm,
             const float* __restrict__ Sm, const int* __restrict__ topk_p,
             float* __restrict__ outp)
{
    __shared__ float  qs[D_DIM];
    __shared__ float  wv[4][FNC];
    __shared__ int    wi[4][FNC];
    __shared__ int    cand8[FNC];
    __shared__ double dval[FNC];
    __shared__ int    chosen[FNC];
    __shared__ int    sk;

    const int q    = blockIdx.x;
    const int tid  = threadIdx.x;
    const int wid  = tid >> 6;
    const int lane = tid & 63;

    for (int i = tid; i < D_DIM / 4; i += 256)
        ((f32x4*)qs)[i] = ((const f32x4*)(Qm + (size_t)q * D_DIM))[i];
    __syncthreads();

    float tv[FNC]; int ti[FNC];
#pragma unroll
    for (int k = 0; k < FNC; ++k) { tv[k] = -INFINITY; ti[k] = 0; }

    for (int r = wid; r < N_M; r += 4) {
        const f32x4* mp = (const f32x4*)(Mm + (size_t)r * D_DIM) + lane * 4;
        const f32x4* qp = (const f32x4*)qs + lane * 4;
        float dot = 0.f, ss = 0.f;
#pragma unroll
        for (int j = 0; j < 4; ++j) {
            f32x4 mv = mp[j], qv = qp[j];
#pragma unroll
            for (int u = 0; u < 4; ++u) { dot += mv[u] * qv[u]; ss += mv[u] * mv[u]; }
        }
#pragma unroll
        for (int off = 1; off <= 32; off <<= 1) {
            dot += __shfl_xor(dot, off, 64);
            ss  += __shfl_xor(ss,  off, 64);
        }
        float s = ss > 0.f ? dot * rsqrtf(ss) : -INFINITY;
        if (better(s, r, tv[FNC - 1], ti[FNC - 1])) {
            float cv = s; int ci = r;
#pragma unroll
            for (int k = 0; k < FNC; ++k) {
                bool b = better(cv, ci, tv[k], ti[k]);
                float nv = b ? cv : tv[k]; int ni = b ? ci : ti[k];
                float ov = b ? tv[k] : cv; int oi = b ? ti[k] : ci;
                tv[k] = nv; ti[k] = ni; cv = ov; ci = oi;
            }
        }
    }

    if (lane == 0)
#pragma unroll
        for (int k = 0; k < FNC; ++k) { wv[wid][k] = tv[k]; wi[wid][k] = ti[k]; }
    __syncthreads();

    if (tid == 0) {
        unsigned used = 0;
        for (int j = 0; j < FNC; ++j) {
            float bv = -INFINITY; int bi = 0; int bs = -1;
            for (int s = 0; s < 4 * FNC; ++s) {
                if (used & (1u << s)) continue;
                float v = wv[s >> 3][s & 7]; int i = wi[s >> 3][s & 7];
                if (bs < 0 || better(v, i, bv, bi)) { bv = v; bi = i; bs = s; }
            }
            used |= 1u << bs;
            cand8[j] = bi;
        }
        int kk = *topk_p;
        if (kk < 1) kk = 1;
        if (kk > FNC) kk = FNC;
        sk = kk;
    }
    __syncthreads();

    for (int ci = wid; ci < FNC; ci += 4) {
        int idx = cand8[ci];
        if (idx < 0)     idx = 0;
        if (idx >= N_M)  idx = N_M - 1;
        const f32x4* mp = (const f32x4*)(Mm + (size_t)idx * D_DIM) + lane * 4;
        const f32x4* qp = (const f32x4*)qs + lane * 4;
        double dot = 0.0, ss = 0.0;
#pragma unroll
        for (int j = 0; j < 4; ++j) {
            f32x4 mv = mp[j], qv = qp[j];
#pragma unroll
            for (int u = 0; u < 4; ++u) {
                dot += (double)mv[u] * (double)qv[u];
                ss  += (double)mv[u] * (double)mv[u];
            }
        }
#pragma unroll
        for (int off = 1; off <= 32; off <<= 1) {
            dot += __shfl_xor(dot, off, 64);
            ss  += __shfl_xor(ss, off, 64);
        }
        if (lane == 0) dval[ci] = ss > 0.0 ? dot / sqrt(ss) : -1e300;
    }
    __syncthreads();

    if (tid == 0) {
        int kk = sk;
        unsigned used = 0;
        for (int j = 0; j < kk; ++j) {
            int best = -1;
            for (int i = 0; i < FNC; ++i) {
                if (used & (1u << i)) continue;
                if (best < 0 || dval[i] > dval[best] ||
                    (dval[i] == dval[best] && cand8[i] < cand8[best])) best = i;
            }
            used |= 1u << best;
            chosen[j] = cand8[best];
        }
    }
    __syncthreads();

    const int kk = sk;
    const int d0 = tid * 4;
    f32x4 a = zero4();
    for (int j = 0; j < kk; ++j) {
        f32x4 s4 = *(const f32x4*)(Sm + (size_t)chosen[j] * D_DIM + d0);
        a = a + s4;
    }
    const float inv = 1.0f / (float)kk;
    a = a * inv;
    *(f32x4*)(outp + (size_t)q * D_DIM + d0) = a;
}

// ---------------------------------------------------------------------------
extern "C" void kernel_launch(void* const* d_in, const int* in_sizes, int n_in,
                              void* d_out, int out_size, void* d_ws, size_t ws_size,
                              hipStream_t stream)
{
    (void)in_sizes; (void)n_in; (void)out_size;

    const float* Qm   = (const float*)d_in[0];
    const float* Mm   = (const float*)d_in[1];
    const float* Sm   = (const float*)d_in[2];
    const int*   topk = (const int*)d_in[3];
    float*       outp = (float*)d_out;

    const size_t A511      = 511;
    const size_t mh_bytes  = (((size_t)MPAD * D_DIM * sizeof(_Float16)) + A511) & ~A511;
    const size_t qh_bytes  = (size_t)QPAD * D_DIM * sizeof(_Float16);                 // 4 MiB
    const size_t inv_bytes = ((size_t)N_M * sizeof(float) + A511) & ~A511;
    const size_t ti_bytes  = (((size_t)T_Q * NC * sizeof(int)) + A511) & ~A511;
    const size_t per_sup_m = (size_t)QPAD * 8 * TK * sizeof(Cand);    // main: 512 KiB
    const size_t per_sup_s = (size_t)QPAD * NC * sizeof(Cand);        // middle: 256 KiB

    if (d_ws != nullptr) {
        // ---- main path: ns must be a multiple of 8 (XCD grouping) ----
        const int ns_opts[4] = { 48, 24, 16, 8 };
        int ns = 0;
        for (int i = 0; i < 4; ++i) {
            size_t need = mh_bytes + qh_bytes + ti_bytes + (size_t)ns_opts[i] * per_sup_m;
            if (need <= ws_size) { ns = ns_opts[i]; break; }
        }
        if (ns >= 8) {
            const int tpbn = (NTILES + ns - 1) / ns;

            _Float16* Mh      = (_Float16*)d_ws;
            _Float16* Qh      = (_Float16*)((char*)d_ws + mh_bytes);
            int*      top_idx = (int*)((char*)d_ws + mh_bytes + qh_bytes);
            Cand*     cand    = (Cand*)((char*)d_ws + mh_bytes + qh_bytes + ti_bytes);

            hipLaunchKernelGGL(knn_qcvt, dim3(QPAD * D_DIM / 2048), dim3(256), 0, stream,
                               Qm, Qh);
            hipLaunchKernelGGL(knn_mcvt, dim3(MPAD / 4), dim3(256), 0, stream,
                               Mm, Mh);
            hipLaunchKernelGGL(knn_gemm_select_h, dim3(QTILES * ns), dim3(256), 0, stream,
                               Qh, Mh, cand, tpbn, ns);
            hipLaunchKernelGGL(knn_top16, dim3(T_Q), dim3(64), 0, stream,
                               cand, top_idx, ns * 8 * TK);
            hipLaunchKernelGGL(knn_rescore, dim3(T_Q), dim3(256), 0, stream,
                               Qm, Mm, Sm, topk, top_idx, outp);
            return;
        }

        // ---- middle path: round-7 structure (~20 MB of workspace) ----
        long long avail = (long long)ws_size
                        - (long long)(inv_bytes + qh_bytes + ti_bytes);
        int ns2 = avail > 0 ? (int)(avail / (long long)per_sup_s) : 0;
        if (ns2 > 64) ns2 = 64;
        if (ns2 >= 1) {
            int tpbn = (NTILES + ns2 - 1) / ns2;
            ns2 = (NTILES + tpbn - 1) / tpbn;

            float*    invn    = (float*)d_ws;
            _Float16* Qh      = (_Float16*)((char*)d_ws + inv_bytes);
            int*      top_idx = (int*)((char*)d_ws + inv_bytes + qh_bytes);
            Cand*     cand    = (Cand*)((char*)d_ws + inv_bytes + qh_bytes + ti_bytes);

            hipLaunchKernelGGL(knn_qcvt, dim3(QPAD * D_DIM / 2048), dim3(256), 0, stream,
                               Qm, Qh);
            hipLaunchKernelGGL(knn_norms, dim3((N_M + 3) / 4), dim3(256), 0, stream,
                               Mm, invn);
            hipLaunchKernelGGL(knn_gemm_select, dim3(QTILES * ns2), dim3(256), 0, stream,
                               Qh, Mm, invn, cand, tpbn, ns2);
            hipLaunchKernelGGL(knn_top16, dim3(T_Q), dim3(64), 0, stream,
                               cand, top_idx, ns2 * NC);
            hipLaunchKernelGGL(knn_rescore, dim3(T_Q), dim3(256), 0, stream,
                               Qm, Mm, Sm, topk, top_idx, outp);
            return;
        }
    }

    // ---- last resort: zero-workspace brute force ----
    hipLaunchKernelGGL(knn_all, dim3(T_Q), dim3(256), 0, stream,
                       Qm, Mm, Sm, topk, outp);
}

// Round 13
// 1334.183 us; speedup vs baseline: 27.2503x; 1.0651x over previous
//
#include <hip/hip_runtime.h>
#include <math.h>

#define T_Q    2000
#define N_M    100000
#define D_DIM  1024
#define QTILES 16
#define NTILES 782          // ceil(100000/128)
#define MPAD   (NTILES * 128)   // 100096 zero-padded fp16 M rows
#define BK     32           // middle-path K-step
#define KSTEPS (D_DIM / BK)
#define BK2    64           // main-path K-step
#define KST2   (D_DIM / BK2)    // 16
#define LDH    40           // middle-path A/B LDS row stride in halves (80 B)
#define SSW    72           // middle-path score tile row stride in halves
#define NC     16           // rescore candidate superset per query
#define QPAD   2048
#define TK     4            // per-thread per-query kept candidates (main path)

typedef _Float16 f16x8 __attribute__((ext_vector_type(8)));
typedef _Float16 f16x4 __attribute__((ext_vector_type(4)));
typedef float    f32x4 __attribute__((ext_vector_type(4)));
typedef unsigned int u32;

struct __align__(8) Cand { float v; int i; };
static_assert(sizeof(Cand) == 8, "cand size");

__device__ __forceinline__ bool better(float av, int ai, float bv, int bi) {
    return (av > bv) || (av == bv && ai < bi);
}

__device__ __forceinline__ f32x4 zero4() {
    f32x4 z; z[0] = 0.f; z[1] = 0.f; z[2] = 0.f; z[3] = 0.f; return z;
}

// async global->LDS, 16 B per lane (dest pattern: wave-uniform base + lane*16)
__device__ __forceinline__ void gload16(const _Float16* g, _Float16* l) {
    const __attribute__((address_space(1))) u32* gp =
        (const __attribute__((address_space(1))) u32*)g;
    __attribute__((address_space(3))) u32* lp =
        (__attribute__((address_space(3))) u32*)l;
    __builtin_amdgcn_global_load_lds(gp, lp, 16, 0, 0);
}

// ---------------------------------------------------------------------------
// Kernel Q (main path): fp16 convert + PER-GROUP CHUNK SWIZZLE.
// Within each 128B group (8 x 16B chunks) of a row, data chunk c is stored at
// position c ^ (row & 7). gload_lds stages linearly; the GEMM fragment read
// applies the same XOR -> conflict-free ds_read_b128 (rule: linear dest +
// inverse-swizzled source + swizzled read).
// ---------------------------------------------------------------------------
__global__ __launch_bounds__(256)
void knn_qcvt(const float* __restrict__ Qm, _Float16* __restrict__ Qh)
{
    const size_t base = (size_t)blockIdx.x * 2048 + (size_t)threadIdx.x * 8;
    const int row = (int)(base >> 10);
    const int hr  = (int)(base & 1023);         // half index within row
    f16x8 h;
    if (row < T_Q) {
        f32x4 a = *(const f32x4*)(Qm + base);
        f32x4 b = *(const f32x4*)(Qm + base + 4);
#pragma unroll
        for (int j = 0; j < 4; ++j) { h[j] = (_Float16)a[j]; h[4 + j] = (_Float16)b[j]; }
    } else {
#pragma unroll
        for (int j = 0; j < 8; ++j) h[j] = (_Float16)0.f;
    }
    const int g = hr >> 3;                      // 16B chunk index in row
    const int p = (g & ~7) | ((g & 7) ^ (row & 7));
    *(f16x8*)(Qh + ((size_t)row << 10) + p * 8) = h;
}

// plain (unswizzled) variant for the middle path
__global__ __launch_bounds__(256)
void knn_qcvt_plain(const float* __restrict__ Qm, _Float16* __restrict__ Qh)
{
    const size_t base = (size_t)blockIdx.x * 2048 + (size_t)threadIdx.x * 8;
    const int row = (int)(base >> 10);
    f16x8 h;
    if (row < T_Q) {
        f32x4 a = *(const f32x4*)(Qm + base);
        f32x4 b = *(const f32x4*)(Qm + base + 4);
#pragma unroll
        for (int j = 0; j < 4; ++j) { h[j] = (_Float16)a[j]; h[4 + j] = (_Float16)b[j]; }
    } else {
#pragma unroll
        for (int j = 0; j < 8; ++j) h[j] = (_Float16)0.f;
    }
    *(f16x8*)(Qh + base) = h;
}

// ---------------------------------------------------------------------------
// Kernel M: fused norm + prescale + fp16 convert + zero-pad + chunk swizzle.
// ---------------------------------------------------------------------------
__global__ __launch_bounds__(256)
void knn_mcvt(const float* __restrict__ Mm, _Float16* __restrict__ Mh)
{
    const int wid  = threadIdx.x >> 6;
    const int lane = threadIdx.x & 63;
    const int r    = blockIdx.x * 4 + wid;   // grid covers MPAD rows
    f16x8 h0, h1;
    if (r < N_M) {
        const f32x4* mp = (const f32x4*)(Mm + (size_t)r * D_DIM) + lane * 4;
        f32x4 v0 = mp[0], v1 = mp[1], v2 = mp[2], v3 = mp[3];
        float ss = 0.f;
#pragma unroll
        for (int u = 0; u < 4; ++u)
            ss += v0[u] * v0[u] + v1[u] * v1[u] + v2[u] * v2[u] + v3[u] * v3[u];
#pragma unroll
        for (int off = 1; off <= 32; off <<= 1) ss += __shfl_xor(ss, off, 64);
        const float inv = ss > 0.f ? rsqrtf(ss) : 0.f;
#pragma unroll
        for (int u = 0; u < 4; ++u) {
            h0[u]     = (_Float16)(v0[u] * inv);
            h0[4 + u] = (_Float16)(v1[u] * inv);
            h1[u]     = (_Float16)(v2[u] * inv);
            h1[4 + u] = (_Float16)(v3[u] * inv);
        }
    } else {
#pragma unroll
        for (int j = 0; j < 8; ++j) { h0[j] = (_Float16)0.f; h1[j] = (_Float16)0.f; }
    }
    const int s  = r & 7;
    const int g0 = 2 * lane;                 // 16B chunk indices (0..127)
    const int g1 = g0 + 1;
    const int p0 = (g0 & ~7) | ((g0 & 7) ^ s);
    const int p1 = (g1 & ~7) | ((g1 & 7) ^ s);
    _Float16* base = Mh + (size_t)r * D_DIM;
    *(f16x8*)(base + p0 * 8) = h0;
    *(f16x8*)(base + p1 * 8) = h1;
}

// ---------------------------------------------------------------------------
// Kernel 1 (main): fp16 MFMA scores, BK=64 K-steps (half the barrier drains),
// swizzle-free-bank fragment reads, in-register running top-4 select.
// ---------------------------------------------------------------------------
__global__ __launch_bounds__(256)
void knn_gemm_select_h(const _Float16* __restrict__ Qh,
                       const _Float16* __restrict__ Mh,
                       Cand* __restrict__ cand, int tpbn, int nsuper)
{
    __shared__ _Float16 As[128][64];    // 16 KiB
    __shared__ _Float16 Bs[128][64];    // 16 KiB  (total 32 KiB)

    // XCD-aware mapping: hardware assigns bid%8 -> XCD (round-robin).
    const int bid   = blockIdx.x;
    const int c8    = bid & 7;
    const int jj0   = bid >> 3;
    const int qtile = jj0 & 15;
    const int sup   = c8 + 8 * (jj0 >> 4);

    const int nt0 = sup * tpbn;
    int nt1 = nt0 + tpbn;
    if (nt1 > NTILES) nt1 = NTILES;

    const int tid  = threadIdx.x;
    const int lane = tid & 63;
    const int wid  = tid >> 6;
    const int wr   = wid >> 1;
    const int wc   = wid & 1;
    const int l15  = lane & 15;
    const int lg   = lane >> 4;

    // staging geometry: thread t -> LDS halves [t*8 + rnd*2048, +8) (linear)
    const int srow   = tid >> 3;        // 0..31
    const int schunk = tid & 7;         // position chunk within the row

    _Float16* AdstB = &As[0][0];
    _Float16* BdstB = &Bs[0][0];

    const _Float16* Bb = Qh + ((size_t)(qtile * 128 + srow) << 10) + schunk * 8;

    // swizzled read chunk for ks=0: (0*4+lg) ^ (l15&7); ks=1 is ^4
    const int cp0 = (lg ^ (l15 & 7)) * 8;           // half offset
    const int cp1 = ((4 | lg) ^ (l15 & 7)) * 8;

    // per-thread running top-4 for each of this thread's 4 query columns
    float rv[4][TK]; int ri[4][TK];
#pragma unroll
    for (int q = 0; q < 4; ++q)
#pragma unroll
        for (int k = 0; k < TK; ++k) { rv[q][k] = -INFINITY; ri[q][k] = 0; }

#pragma unroll 1
    for (int ntile = nt0; ntile < nt1; ++ntile) {
        const _Float16* Ab = Mh + ((size_t)(ntile * 128 + srow) << 10) + schunk * 8;

        f32x4 acc[4][4];
#pragma unroll
        for (int i = 0; i < 4; ++i)
#pragma unroll
            for (int j = 0; j < 4; ++j) acc[i][j] = zero4();

        for (int t = 0; t < KST2; ++t) {
            const int k0 = t * BK2;
#pragma unroll
            for (int r = 0; r < 4; ++r) {
                gload16(Ab + (size_t)(r * 32) * 1024 + k0, AdstB + tid * 8 + r * 2048);
                gload16(Bb + (size_t)(r * 32) * 1024 + k0, BdstB + tid * 8 + r * 2048);
            }

            __syncthreads();   // drains vmcnt -> staged data visible

#pragma unroll
            for (int ks = 0; ks < 2; ++ks) {
                const int cp = ks ? cp1 : cp0;
                f16x8 af[4], bf[4];
#pragma unroll
                for (int f = 0; f < 4; ++f) {
                    af[f] = *(const f16x8*)&As[wr * 64 + f * 16 + l15][cp];
                    bf[f] = *(const f16x8*)&Bs[wc * 64 + f * 16 + l15][cp];
                }
#pragma unroll
                for (int i = 0; i < 4; ++i)
#pragma unroll
                    for (int j = 0; j < 4; ++j)
                        acc[i][j] = __builtin_amdgcn_mfma_f32_16x16x32_f16(
                            af[i], bf[j], acc[i][j], 0, 0, 0);
            }

            __syncthreads();   // readers done before next-step staging
        }

        // fold this tile's 16 scores per query into the running top-4
        const int rowbase = ntile * 128 + wr * 64 + lg * 4;
#pragma unroll
        for (int q = 0; q < 4; ++q) {
            float mx = acc[0][q][0];
#pragma unroll
            for (int i = 0; i < 4; ++i)
#pragma unroll
                for (int r = 0; r < 4; ++r) mx = fmaxf(mx, acc[i][q][r]);
            if (mx >= rv[q][TK - 1]) {          // rare: tile can contribute
#pragma unroll
                for (int i = 0; i < 4; ++i)
#pragma unroll
                    for (int r = 0; r < 4; ++r) {
                        const int ng = rowbase + i * 16 + r;
                        float cv = acc[i][q][r];
                        if (ng < N_M && better(cv, ng, rv[q][TK - 1], ri[q][TK - 1])) {
                            int ci = ng;
#pragma unroll
                            for (int k = 0; k < TK; ++k) {
                                bool b = better(cv, ci, rv[q][k], ri[q][k]);
                                float nv = b ? cv : rv[q][k]; int ni = b ? ci : ri[q][k];
                                float ov = b ? rv[q][k] : cv; int oi = b ? ri[q][k] : ci;
                                rv[q][k] = nv; ri[q][k] = ni; cv = ov; ci = oi;
                            }
                        }
                    }
            }
        }
    }

    // write per-thread sorted-4 lists; 8 owner threads per query column.
    const int owner = wr * 4 + lg;      // 0..7
#pragma unroll
    for (int q = 0; q < 4; ++q) {
        const int qg = qtile * 128 + wc * 64 + q * 16 + l15;
        Cand* dst = cand + (((size_t)qg * nsuper + sup) * 8 + owner) * TK;
#pragma unroll
        for (int k = 0; k < TK; ++k) {
            Cand c; c.v = rv[q][k]; c.i = ri[q][k];
            dst[k] = c;
        }
    }
}

// ---------------------------------------------------------------------------
// Kernel 2: per query, reduce ncand candidates to global approx top-16.
// ---------------------------------------------------------------------------
__global__ __launch_bounds__(64)
void knn_top16(const Cand* __restrict__ cand, int* __restrict__ top_idx, int ncand)
{
    __shared__ float lv[64][NC];
    __shared__ int   li[64][NC];

    const int q = blockIdx.x;
    const int lane = threadIdx.x;
    const Cand* rowp = cand + (size_t)q * ncand;

    float tv[NC]; int ti[NC];
#pragma unroll
    for (int k = 0; k < NC; ++k) { tv[k] = -INFINITY; ti[k] = 0; }

#pragma unroll 1
    for (int e = lane; e < ncand; e += 64) {
        Cand c = rowp[e];
        if (better(c.v, c.i, tv[NC - 1], ti[NC - 1])) {
            float cv = c.v; int ci = c.i;
#pragma unroll
            for (int k = 0; k < NC; ++k) {
                bool b = better(cv, ci, tv[k], ti[k]);
                float nv = b ? cv : tv[k]; int ni = b ? ci : ti[k];
                float ov = b ? tv[k] : cv; int oi = b ? ti[k] : ci;
                tv[k] = nv; ti[k] = ni; cv = ov; ci = oi;
            }
        }
    }

#pragma unroll
    for (int k = 0; k < NC; ++k) { lv[lane][k] = tv[k]; li[lane][k] = ti[k]; }
    __syncthreads();

    if (lane == 0) {
#pragma unroll 1
        for (int l = 1; l < 64; ++l) {
#pragma unroll 1
            for (int k = 0; k < NC; ++k) {
                float v = lv[l][k]; int i = li[l][k];
                if (!better(v, i, tv[NC - 1], ti[NC - 1])) break; // lists sorted desc
                float cv = v; int ci = i;
#pragma unroll
                for (int kk = 0; kk < NC; ++kk) {
                    bool b = better(cv, ci, tv[kk], ti[kk]);
                    float nv = b ? cv : tv[kk]; int ni = b ? ci : ti[kk];
                    float ov = b ? tv[kk] : cv; int oi = b ? ti[kk] : ci;
                    tv[kk] = nv; ti[kk] = ni; cv = ov; ci = oi;
                }
            }
        }
#pragma unroll
        for (int k = 0; k < NC; ++k) top_idx[q * NC + k] = ti[k];
    }
}

// ---------------------------------------------------------------------------
// Kernel 3: exact fp64 rescore of the 16 candidates, top-k, gather-average.
// ---------------------------------------------------------------------------
__global__ __launch_bounds__(256)
void knn_rescore(const float* __restrict__ Qm, const float* __restrict__ Mm,
                 const float* __restrict__ Sm, const int* __restrict__ topk_p,
                 const int* __restrict__ top_idx, float* __restrict__ outp)
{
    const int q   = blockIdx.x;
    const int tid = threadIdx.x;
    const int wid = tid >> 6, lane = tid & 63;

    __shared__ double sval[NC];
    __shared__ int    sidx[NC];
    __shared__ int    chosen[NC];

    int k = *topk_p;
    if (k > NC) k = NC;
    if (k < 1)  k = 1;

    const float* qrow = Qm + (size_t)q * D_DIM;
#pragma unroll 1
    for (int ci = wid; ci < NC; ci += 4) {
        int idx = top_idx[q * NC + ci];
        if (idx < 0)    idx = 0;
        if (idx >= N_M) idx = N_M - 1;
        const f32x4* mp = (const f32x4*)(Mm + (size_t)idx * D_DIM) + lane * 4;
        const f32x4* qp = (const f32x4*)qrow + lane * 4;
        double dot = 0.0, ss = 0.0;
#pragma unroll
        for (int j = 0; j < 4; ++j) {
            f32x4 mv = mp[j], qv = qp[j];
#pragma unroll
            for (int u = 0; u < 4; ++u) {
                dot += (double)mv[u] * (double)qv[u];
                ss  += (double)mv[u] * (double)mv[u];
            }
        }
#pragma unroll
        for (int off = 1; off <= 32; off <<= 1) {
            dot += __shfl_xor(dot, off, 64);
            ss  += __shfl_xor(ss, off, 64);
        }
        if (lane == 0) { sval[ci] = ss > 0.0 ? dot / sqrt(ss) : -1e300; sidx[ci] = idx; }
    }
    __syncthreads();

    if (tid == 0) {
        unsigned used = 0;
        for (int j = 0; j < k; ++j) {
            int best = -1;
            for (int i = 0; i < NC; ++i) {
                if (used & (1u << i)) continue;
                if (best < 0 || sval[i] > sval[best] ||
                    (sval[i] == sval[best] && sidx[i] < sidx[best])) best = i;
            }
            used |= 1u << best;
            chosen[j] = sidx[best];
        }
    }
    __syncthreads();

    const int d0 = tid * 4;
    f32x4 a = zero4();
    for (int j = 0; j < k; ++j) {
        f32x4 s4 = *(const f32x4*)(Sm + (size_t)chosen[j] * D_DIM + d0);
        a = a + s4;
    }
    const float inv = 1.0f / (float)k;
    a = a * inv;
    *(f32x4*)(outp + (size_t)q * D_DIM + d0) = a;
}

// ---------------------------------------------------------------------------
// Middle path (round-7 verbatim, proven): norms + fp32-staged GEMM select.
// Uses PLAIN (unswizzled) Qh.
// ---------------------------------------------------------------------------
__global__ __launch_bounds__(256)
void knn_norms(const float* __restrict__ Mm, float* __restrict__ invn)
{
    const int wid  = threadIdx.x >> 6;
    const int lane = threadIdx.x & 63;
    const int r    = blockIdx.x * 4 + wid;
    if (r >= N_M) return;
    const f32x4* mp = (const f32x4*)(Mm + (size_t)r * D_DIM) + lane * 4;
    float ss = 0.f;
#pragma unroll
    for (int j = 0; j < 4; ++j) {
        f32x4 v = mp[j];
#pragma unroll
        for (int u = 0; u < 4; ++u) ss += v[u] * v[u];
    }
#pragma unroll
    for (int off = 1; off <= 32; off <<= 1) ss += __shfl_xor(ss, off, 64);
    if (lane == 0) invn[r] = ss > 0.f ? rsqrtf(ss) : 0.f;
}

__global__ __launch_bounds__(256)
void knn_gemm_select(const _Float16* __restrict__ Qh, const float* __restrict__ Mm,
                     const float* __restrict__ invn, Cand* __restrict__ cand,
                     int tpbn, int nsuper)
{
    __shared__ _Float16 As[128][LDH];
    __shared__ _Float16 Bs[128][LDH];
    __shared__ _Float16 Ss[128][SSW];
    __shared__ float    sinv[128];

    const int qtile = blockIdx.x & (QTILES - 1);
    const int sup   = blockIdx.x >> 4;
    const int nt0   = sup * tpbn;
    int nt1 = nt0 + tpbn;
    if (nt1 > NTILES) nt1 = NTILES;

    const int tid = threadIdx.x;
    const int row = tid >> 1;
    const int kh  = tid & 1;

    const int qrow_g = qtile * 128 + row;
    const _Float16* bbase = Qh + (size_t)qrow_g * D_DIM + kh * 16;

    const int lane = tid & 63;
    const int wid  = tid >> 6;
    const int wr   = wid >> 1;
    const int wc   = wid & 1;
    const int l15  = lane & 15;
    const int lg   = lane >> 4;

    float rv[NC]; int ri[NC];
#pragma unroll
    for (int k = 0; k < NC; ++k) { rv[k] = -INFINITY; ri[k] = 0; }

#pragma unroll 1
    for (int ntile = nt0; ntile < nt1; ++ntile) {
        const int nrow_g = ntile * 128 + row;
        const bool a_ok  = nrow_g < N_M;
        const float* abase = Mm + (size_t)nrow_g * D_DIM + kh * 16;

        f32x4 acc[4][4];
#pragma unroll
        for (int i = 0; i < 4; ++i)
#pragma unroll
            for (int j = 0; j < 4; ++j) acc[i][j] = zero4();

        f32x4 ar[4];
        f16x8 brh[2];
#pragma unroll
        for (int i = 0; i < 4; ++i) ar[i] = a_ok ? ((const f32x4*)abase)[i] : zero4();
        brh[0] = *(const f16x8*)(bbase);
        brh[1] = *(const f16x8*)(bbase + 8);

#pragma unroll 1
        for (int t = 0; t < KSTEPS; ++t) {
            __syncthreads();

            f16x8 ha0, ha1;
#pragma unroll
            for (int i = 0; i < 2; ++i)
#pragma unroll
                for (int j = 0; j < 4; ++j) {
                    ha0[i * 4 + j] = (_Float16)ar[i][j];
                    ha1[i * 4 + j] = (_Float16)ar[i + 2][j];
                }
            *(f16x8*)&As[row][kh * 16]     = ha0;
            *(f16x8*)&As[row][kh * 16 + 8] = ha1;
            *(f16x8*)&Bs[row][kh * 16]     = brh[0];
            *(f16x8*)&Bs[row][kh * 16 + 8] = brh[1];

            __syncthreads();

            if (t + 1 < KSTEPS) {
                const float*    ap = abase + (t + 1) * BK;
                const _Float16* bp = bbase + (t + 1) * BK;
#pragma unroll
                for (int i = 0; i < 4; ++i) ar[i] = a_ok ? ((const f32x4*)ap)[i] : zero4();
                brh[0] = *(const f16x8*)(bp);
                brh[1] = *(const f16x8*)(bp + 8);
            }

            f16x8 af[4], bf[4];
#pragma unroll
            for (int f = 0; f < 4; ++f) {
                af[f] = *(const f16x8*)&As[wr * 64 + f * 16 + l15][lg * 8];
                bf[f] = *(const f16x8*)&Bs[wc * 64 + f * 16 + l15][lg * 8];
            }
#pragma unroll
            for (int i = 0; i < 4; ++i)
#pragma unroll
                for (int j = 0; j < 4; ++j)
                    acc[i][j] = __builtin_amdgcn_mfma_f32_16x16x32_f16(
                        af[i], bf[j], acc[i][j], 0, 0, 0);
        }

        if (tid < 128) {
            const int r = ntile * 128 + tid;
            sinv[tid] = (r < N_M) ? invn[r] : 0.f;
        }

#pragma unroll 1
        for (int h = 0; h < 2; ++h) {
            __syncthreads();
            if (wr == h) {
#pragma unroll
                for (int fr = 0; fr < 4; ++fr)
#pragma unroll
                    for (int fc = 0; fc < 4; ++fc) {
                        f16x4 v;
#pragma unroll
                        for (int r = 0; r < 4; ++r) v[r] = (_Float16)acc[fr][fc][r];
                        *(f16x4*)&Ss[wc * 64 + fc * 16 + l15][fr * 16 + lg * 4] = v;
                    }
            }
            __syncthreads();

            if (tid < 128) {
                const int base = ntile * 128 + h * 64;
                int nval = N_M - base;
                if (nval > 64) nval = 64;
#pragma unroll 1
                for (int c = 0; c < nval; c += 8) {
                    f16x8 sv = *(const f16x8*)&Ss[tid][c];
                    f32x4 sa = *(const f32x4*)&sinv[h * 64 + c];
                    f32x4 sb = *(const f32x4*)&sinv[h * 64 + c + 4];
                    const int lim = (nval - c >= 8) ? 8 : (nval - c);
                    float s[8];
#pragma unroll
                    for (int j = 0; j < 4; ++j) {
                        s[j]     = (float)sv[j] * sa[j];
                        s[4 + j] = (float)sv[4 + j] * sb[j];
                    }
                    if (lim < 8)
#pragma unroll
                        for (int j = 0; j < 8; ++j)
                            if (j >= lim) s[j] = -INFINITY;
                    float m01 = fmaxf(s[0], s[1]), m23 = fmaxf(s[2], s[3]);
                    float m45 = fmaxf(s[4], s[5]), m67 = fmaxf(s[6], s[7]);
                    float mx = fmaxf(fmaxf(m01, m23), fmaxf(m45, m67));
                    if (mx >= rv[NC - 1]) {
#pragma unroll 1
                        for (int j = 0; j < 8; ++j) {
                            if (j >= lim) break;
                            float cv = s[j]; int ci = base + c + j;
                            if (better(cv, ci, rv[NC - 1], ri[NC - 1])) {
#pragma unroll
                                for (int k = 0; k < NC; ++k) {
                                    bool b = better(cv, ci, rv[k], ri[k]);
                                    float nv = b ? cv : rv[k]; int ni = b ? ci : ri[k];
                                    float ov = b ? rv[k] : cv; int oi = b ? ri[k] : ci;
                                    rv[k] = nv; ri[k] = ni; cv = ov; ci = oi;
                                }
                            }
                        }
                    }
                }
            }
        }
    }

    if (tid < 128) {
        const int qg = qtile * 128 + tid;
        Cand* dst = cand + ((size_t)qg * nsuper + sup) * NC;
#pragma unroll
        for (int k = 0; k < NC; ++k) { Cand c; c.v = rv[k]; c.i = ri[k]; dst[k] = c; }
    }
}

// ---------------------------------------------------------------------------
// Fallback: round-5 brute force, verbatim (proven: passed, absmax 0.0).
// ---------------------------------------------------------------------------
#define FNC 8
__global__ __launch_bounds__(256)
void knn_all(const float* __restrict__ Qm, const float* __restrict__ Mm,
             const float* __restrict__ Sm, const int* __restrict__ topk_p,
             float* __restrict__ outp)
{
    __shared__ float  qs[D_DIM];
    __shared__ float  wv[4][FNC];
    __shared__ int    wi[4][FNC];
    __shared__ int    cand8[FNC];
    __shared__ double dval[FNC];
    __shared__ int    chosen[FNC];
    __shared__ int    sk;

    const int q    = blockIdx.x;
    const int tid  = threadIdx.x;
    const int wid  = tid >> 6;
    const int lane = tid & 63;

    for (int i = tid; i < D_DIM / 4; i += 256)
        ((f32x4*)qs)[i] = ((const f32x4*)(Qm + (size_t)q * D_DIM))[i];
    __syncthreads();

    float tv[FNC]; int ti[FNC];
#pragma unroll
    for (int k = 0; k < FNC; ++k) { tv[k] = -INFINITY; ti[k] = 0; }

    for (int r = wid; r < N_M; r += 4) {
        const f32x4* mp = (const f32x4*)(Mm + (size_t)r * D_DIM) + lane * 4;
        const f32x4* qp = (const f32x4*)qs + lane * 4;
        float dot = 0.f, ss = 0.f;
#pragma unroll
        for (int j = 0; j < 4; ++j) {
            f32x4 mv = mp[j], qv = qp[j];
#pragma unroll
            for (int u = 0; u < 4; ++u) { dot += mv[u] * qv[u]; ss += mv[u] * mv[u]; }
        }
#pragma unroll
        for (int off = 1; off <= 32; off <<= 1) {
            dot += __shfl_xor(dot, off, 64);
            ss  += __shfl_xor(ss,  off, 64);
        }
        float s = ss > 0.f ? dot * rsqrtf(ss) : -INFINITY;
        if (better(s, r, tv[FNC - 1], ti[FNC - 1])) {
            float cv = s; int ci = r;
#pragma unroll
            for (int k = 0; k < FNC; ++k) {
                bool b = better(cv, ci, tv[k], ti[k]);
                float nv = b ? cv : tv[k]; int ni = b ? ci : ti[k];
                float ov = b ? tv[k] : cv; int oi = b ? ti[k] : ci;
                tv[k] = nv; ti[k] = ni; cv = ov; ci = oi;
            }
        }
    }

    if (lane == 0)
#pragma unroll
        for (int k = 0; k < FNC; ++k) { wv[wid][k] = tv[k]; wi[wid][k] = ti[k]; }
    __syncthreads();

    if (tid == 0) {
        unsigned used = 0;
        for (int j = 0; j < FNC; ++j) {
            float bv = -INFINITY; int bi = 0; int bs = -1;
            for (int s = 0; s < 4 * FNC; ++s) {
                if (used & (1u << s)) continue;
                float v = wv[s >> 3][s & 7]; int i = wi[s >> 3][s & 7];
                if (bs < 0 || better(v, i, bv, bi)) { bv = v; bi = i; bs = s; }
            }
            used |= 1u << bs;
            cand8[j] = bi;
        }
        int kk = *topk_p;
        if (kk < 1) kk = 1;
        if (kk > FNC) kk = FNC;
        sk = kk;
    }
    __syncthreads();

    for (int ci = wid; ci < FNC; ci += 4) {
        int idx = cand8[ci];
        if (idx < 0)     idx = 0;
        if (idx >= N_M)  idx = N_M - 1;
        const f32x4* mp = (const f32x4*)(Mm + (size_t)idx * D_DIM) + lane * 4;
        const f32x4* qp = (const f32x4*)qs + lane * 4;
        double dot = 0.0, ss = 0.0;
#pragma unroll
        for (int j = 0; j < 4; ++j) {
            f32x4 mv = mp[j], qv = qp[j];
#pragma unroll
            for (int u = 0; u < 4; ++u) {
                dot += (double)mv[u] * (double)qv[u];
                ss  += (double)mv[u] * (double)mv[u];
            }
        }
#pragma unroll
        for (int off = 1; off <= 32; off <<= 1) {
            dot += __shfl_xor(dot, off, 64);
            ss  += __shfl_xor(ss, off, 64);
        }
        if (lane == 0) dval[ci] = ss > 0.0 ? dot / sqrt(ss) : -1e300;
    }
    __syncthreads();

    if (tid == 0) {
        int kk = sk;
        unsigned used = 0;
        for (int j = 0; j < kk; ++j) {
            int best = -1;
            for (int i = 0; i < FNC; ++i) {
                if (used & (1u << i)) continue;
                if (best < 0 || dval[i] > dval[best] ||
                    (dval[i] == dval[best] && cand8[i] < cand8[best])) best = i;
            }
            used |= 1u << best;
            chosen[j] = cand8[best];
        }
    }
    __syncthreads();

    const int kk = sk;
    const int d0 = tid * 4;
    f32x4 a = zero4();
    for (int j = 0; j < kk; ++j) {
        f32x4 s4 = *(const f32x4*)(Sm + (size_t)chosen[j] * D_DIM + d0);
        a = a + s4;
    }
    const float inv = 1.0f / (float)kk;
    a = a * inv;
    *(f32x4*)(outp + (size_t)q * D_DIM + d0) = a;
}

// ---------------------------------------------------------------------------
extern "C" void kernel_launch(void* const* d_in, const int* in_sizes, int n_in,
                              void* d_out, int out_size, void* d_ws, size_t ws_size,
                              hipStream_t stream)
{
    (void)in_sizes; (void)n_in; (void)out_size;

    const float* Qm   = (const float*)d_in[0];
    const float* Mm   = (const float*)d_in[1];
    const float* Sm   = (const float*)d_in[2];
    const int*   topk = (const int*)d_in[3];
    float*       outp = (float*)d_out;

    const size_t A511      = 511;
    const size_t mh_bytes  = (((size_t)MPAD * D_DIM * sizeof(_Float16)) + A511) & ~A511;
    const size_t qh_bytes  = (size_t)QPAD * D_DIM * sizeof(_Float16);                 // 4 MiB
    const size_t inv_bytes = ((size_t)N_M * sizeof(float) + A511) & ~A511;
    const size_t ti_bytes  = (((size_t)T_Q * NC * sizeof(int)) + A511) & ~A511;
    const size_t per_sup_m = (size_t)QPAD * 8 * TK * sizeof(Cand);    // main: 512 KiB
    const size_t per_sup_s = (size_t)QPAD * NC * sizeof(Cand);        // middle: 256 KiB

    if (d_ws != nullptr) {
        // ---- main path: ns must be a multiple of 8 (XCD grouping) ----
        const int ns_opts[4] = { 48, 24, 16, 8 };
        int ns = 0;
        for (int i = 0; i < 4; ++i) {
            size_t need = mh_bytes + qh_bytes + ti_bytes + (size_t)ns_opts[i] * per_sup_m;
            if (need <= ws_size) { ns = ns_opts[i]; break; }
        }
        if (ns >= 8) {
            const int tpbn = (NTILES + ns - 1) / ns;

            _Float16* Mh      = (_Float16*)d_ws;
            _Float16* Qh      = (_Float16*)((char*)d_ws + mh_bytes);
            int*      top_idx = (int*)((char*)d_ws + mh_bytes + qh_bytes);
            Cand*     cand    = (Cand*)((char*)d_ws + mh_bytes + qh_bytes + ti_bytes);

            hipLaunchKernelGGL(knn_qcvt, dim3(QPAD * D_DIM / 2048), dim3(256), 0, stream,
                               Qm, Qh);
            hipLaunchKernelGGL(knn_mcvt, dim3(MPAD / 4), dim3(256), 0, stream,
                               Mm, Mh);
            hipLaunchKernelGGL(knn_gemm_select_h, dim3(QTILES * ns), dim3(256), 0, stream,
                               Qh, Mh, cand, tpbn, ns);
            hipLaunchKernelGGL(knn_top16, dim3(T_Q), dim3(64), 0, stream,
                               cand, top_idx, ns * 8 * TK);
            hipLaunchKernelGGL(knn_rescore, dim3(T_Q), dim3(256), 0, stream,
                               Qm, Mm, Sm, topk, top_idx, outp);
            return;
        }

        // ---- middle path: round-7 structure (~20 MB of workspace) ----
        long long avail = (long long)ws_size
                        - (long long)(inv_bytes + qh_bytes + ti_bytes);
        int ns2 = avail > 0 ? (int)(avail / (long long)per_sup_s) : 0;
        if (ns2 > 64) ns2 = 64;
        if (ns2 >= 1) {
            int tpbn = (NTILES + ns2 - 1) / ns2;
            ns2 = (NTILES + tpbn - 1) / tpbn;

            float*    invn    = (float*)d_ws;
            _Float16* Qh      = (_Float16*)((char*)d_ws + inv_bytes);
            int*      top_idx = (int*)((char*)d_ws + inv_bytes + qh_bytes);
            Cand*     cand    = (Cand*)((char*)d_ws + inv_bytes + qh_bytes + ti_bytes);

            hipLaunchKernelGGL(knn_qcvt_plain, dim3(QPAD * D_DIM / 2048), dim3(256), 0, stream,
                               Qm, Qh);
            hipLaunchKernelGGL(knn_norms, dim3((N_M + 3) / 4), dim3(256), 0, stream,
                               Mm, invn);
            hipLaunchKernelGGL(knn_gemm_select, dim3(QTILES * ns2), dim3(256), 0, stream,
                               Qh, Mm, invn, cand, tpbn, ns2);
            hipLaunchKernelGGL(knn_top16, dim3(T_Q), dim3(64), 0, stream,
                               cand, top_idx, ns2 * NC);
            hipLaunchKernelGGL(knn_rescore, dim3(T_Q), dim3(256), 0, stream,
                               Qm, Mm, Sm, topk, top_idx, outp);
            return;
        }
    }

    // ---- last resort: zero-workspace brute force ----
    hipLaunchKernelGGL(knn_all, dim3(T_Q), dim3(256), 0, stream,
                       Qm, Mm, Sm, topk, outp);
}

// Round 14
// 1166.711 us; speedup vs baseline: 31.1619x; 1.1435x over previous
//
#include <hip/hip_runtime.h>
#include <math.h>

#define T_Q    2000
#define N_M    100000
#define D_DIM  1024
#define QTILES 16
#define NTILES 782          // ceil(100000/128)
#define MPAD   (NTILES * 128)   // 100096 zero-padded fp16 M rows
#define BK     32           // middle-path K-step
#define KSTEPS (D_DIM / BK)
#define BK2    64           // main-path K-step
#define KST2   (D_DIM / BK2)    // 16
#define LDH    40           // middle-path A/B LDS row stride in halves (80 B)
#define SSW    72           // middle-path score tile row stride in halves
#define NC     16           // rescore candidate superset per query
#define QPAD   2048
#define TK     4            // per-thread per-query kept candidates (main path)

typedef _Float16 f16x8 __attribute__((ext_vector_type(8)));
typedef _Float16 f16x4 __attribute__((ext_vector_type(4)));
typedef float    f32x4 __attribute__((ext_vector_type(4)));
typedef unsigned int u32;

struct __align__(8) Cand { float v; int i; };
static_assert(sizeof(Cand) == 8, "cand size");

__device__ __forceinline__ bool better(float av, int ai, float bv, int bi) {
    return (av > bv) || (av == bv && ai < bi);
}

__device__ __forceinline__ f32x4 zero4() {
    f32x4 z; z[0] = 0.f; z[1] = 0.f; z[2] = 0.f; z[3] = 0.f; return z;
}

// async global->LDS, 16 B per lane (dest pattern: wave-uniform base + lane*16)
__device__ __forceinline__ void gload16(const _Float16* g, _Float16* l) {
    const __attribute__((address_space(1))) u32* gp =
        (const __attribute__((address_space(1))) u32*)g;
    __attribute__((address_space(3))) u32* lp =
        (__attribute__((address_space(3))) u32*)l;
    __builtin_amdgcn_global_load_lds(gp, lp, 16, 0, 0);
}

// ---------------------------------------------------------------------------
// Kernel Q (main path): fp16 convert + per-group chunk swizzle (chunk c of
// each 128B group stored at c ^ (row & 7)); GEMM read applies the same XOR.
// ---------------------------------------------------------------------------
__global__ __launch_bounds__(256)
void knn_qcvt(const float* __restrict__ Qm, _Float16* __restrict__ Qh)
{
    const size_t base = (size_t)blockIdx.x * 2048 + (size_t)threadIdx.x * 8;
    const int row = (int)(base >> 10);
    const int hr  = (int)(base & 1023);
    f16x8 h;
    if (row < T_Q) {
        f32x4 a = *(const f32x4*)(Qm + base);
        f32x4 b = *(const f32x4*)(Qm + base + 4);
#pragma unroll
        for (int j = 0; j < 4; ++j) { h[j] = (_Float16)a[j]; h[4 + j] = (_Float16)b[j]; }
    } else {
#pragma unroll
        for (int j = 0; j < 8; ++j) h[j] = (_Float16)0.f;
    }
    const int g = hr >> 3;
    const int p = (g & ~7) | ((g & 7) ^ (row & 7));
    *(f16x8*)(Qh + ((size_t)row << 10) + p * 8) = h;
}

// plain (unswizzled) variant for the middle path
__global__ __launch_bounds__(256)
void knn_qcvt_plain(const float* __restrict__ Qm, _Float16* __restrict__ Qh)
{
    const size_t base = (size_t)blockIdx.x * 2048 + (size_t)threadIdx.x * 8;
    const int row = (int)(base >> 10);
    f16x8 h;
    if (row < T_Q) {
        f32x4 a = *(const f32x4*)(Qm + base);
        f32x4 b = *(const f32x4*)(Qm + base + 4);
#pragma unroll
        for (int j = 0; j < 4; ++j) { h[j] = (_Float16)a[j]; h[4 + j] = (_Float16)b[j]; }
    } else {
#pragma unroll
        for (int j = 0; j < 8; ++j) h[j] = (_Float16)0.f;
    }
    *(f16x8*)(Qh + base) = h;
}

// ---------------------------------------------------------------------------
// Kernel M: fused norm + prescale + fp16 convert + zero-pad + chunk swizzle.
// ---------------------------------------------------------------------------
__global__ __launch_bounds__(256)
void knn_mcvt(const float* __restrict__ Mm, _Float16* __restrict__ Mh)
{
    const int wid  = threadIdx.x >> 6;
    const int lane = threadIdx.x & 63;
    const int r    = blockIdx.x * 4 + wid;   // grid covers MPAD rows
    f16x8 h0, h1;
    if (r < N_M) {
        const f32x4* mp = (const f32x4*)(Mm + (size_t)r * D_DIM) + lane * 4;
        f32x4 v0 = mp[0], v1 = mp[1], v2 = mp[2], v3 = mp[3];
        float ss = 0.f;
#pragma unroll
        for (int u = 0; u < 4; ++u)
            ss += v0[u] * v0[u] + v1[u] * v1[u] + v2[u] * v2[u] + v3[u] * v3[u];
#pragma unroll
        for (int off = 1; off <= 32; off <<= 1) ss += __shfl_xor(ss, off, 64);
        const float inv = ss > 0.f ? rsqrtf(ss) : 0.f;
#pragma unroll
        for (int u = 0; u < 4; ++u) {
            h0[u]     = (_Float16)(v0[u] * inv);
            h0[4 + u] = (_Float16)(v1[u] * inv);
            h1[u]     = (_Float16)(v2[u] * inv);
            h1[4 + u] = (_Float16)(v3[u] * inv);
        }
    } else {
#pragma unroll
        for (int j = 0; j < 8; ++j) { h0[j] = (_Float16)0.f; h1[j] = (_Float16)0.f; }
    }
    const int s  = r & 7;
    const int g0 = 2 * lane;
    const int g1 = g0 + 1;
    const int p0 = (g0 & ~7) | ((g0 & 7) ^ s);
    const int p1 = (g1 & ~7) | ((g1 & 7) ^ s);
    _Float16* base = Mh + (size_t)r * D_DIM;
    *(f16x8*)(base + p0 * 8) = h0;
    *(f16x8*)(base + p1 * 8) = h1;
}

// ---------------------------------------------------------------------------
// Kernel 1 (main): fp16 MFMA scores, BK=64, DOUBLE-BUFFERED 2-phase pipeline:
// issue next-step gloads -> compute current buffer -> one __syncthreads.
// Load latency hides under the ds_read+MFMA phase. Swizzled conflict-free
// reads; in-register running top-4 select (proven absmax 0.0).
// ---------------------------------------------------------------------------
__global__ __launch_bounds__(256)
void knn_gemm_select_h(const _Float16* __restrict__ Qh,
                       const _Float16* __restrict__ Mh,
                       Cand* __restrict__ cand, int tpbn, int nsuper)
{
    __shared__ _Float16 As[2][128][64];   // 32 KiB
    __shared__ _Float16 Bs[2][128][64];   // 32 KiB  (total 64 KiB)

    // XCD-aware mapping: hardware assigns bid%8 -> XCD (round-robin).
    const int bid   = blockIdx.x;
    const int c8    = bid & 7;
    const int jj0   = bid >> 3;
    const int qtile = jj0 & 15;
    const int sup   = c8 + 8 * (jj0 >> 4);

    const int nt0 = sup * tpbn;
    int nt1 = nt0 + tpbn;
    if (nt1 > NTILES) nt1 = NTILES;

    const int tid  = threadIdx.x;
    const int lane = tid & 63;
    const int wid  = tid >> 6;
    const int wr   = wid >> 1;
    const int wc   = wid & 1;
    const int l15  = lane & 15;
    const int lg   = lane >> 4;

    // staging geometry: thread t covers 16 B at linear LDS offset t*16 (+r*4KB)
    const int srow   = tid >> 3;        // 0..31
    const int schunk = tid & 7;

    const _Float16* Bb = Qh + ((size_t)(qtile * 128 + srow) << 10) + schunk * 8;

    // swizzled read chunk offsets (ks=0 / ks=1)
    const int cp0 = (lg ^ (l15 & 7)) * 8;
    const int cp1 = ((4 | lg) ^ (l15 & 7)) * 8;

#define ISSUE_STEP(Abase, koff, bi) do {                                       \
        _Float16* ad_ = &As[bi][0][0] + tid * 8;                               \
        _Float16* bd_ = &Bs[bi][0][0] + tid * 8;                               \
        _Pragma("unroll")                                                      \
        for (int r_ = 0; r_ < 4; ++r_) {                                       \
            gload16((Abase) + (size_t)(r_ * 32) * 1024 + (koff), ad_ + r_ * 2048); \
            gload16(Bb + (size_t)(r_ * 32) * 1024 + (koff), bd_ + r_ * 2048);  \
        }                                                                      \
    } while (0)

    float rv[4][TK]; int ri[4][TK];
#pragma unroll
    for (int q = 0; q < 4; ++q)
#pragma unroll
        for (int k = 0; k < TK; ++k) { rv[q][k] = -INFINITY; ri[q][k] = 0; }

    const _Float16* Ab = Mh + ((size_t)(nt0 * 128 + srow) << 10) + schunk * 8;
    int buf = 0;

    // prologue: stage tile nt0 / step 0 into buf 0
    ISSUE_STEP(Ab, 0, 0);
    __syncthreads();

#pragma unroll 1
    for (int ntile = nt0; ntile < nt1; ++ntile) {
        const _Float16* AbNext = Ab + ((size_t)128 << 10);

        f32x4 acc[4][4];
#pragma unroll
        for (int i = 0; i < 4; ++i)
#pragma unroll
            for (int j = 0; j < 4; ++j) acc[i][j] = zero4();

#pragma unroll 1
        for (int t = 0; t < KST2; ++t) {
            // phase 1: issue next-step loads into the other buffer
            if (t + 1 < KST2)            ISSUE_STEP(Ab, (t + 1) * BK2, buf ^ 1);
            else if (ntile + 1 < nt1)    ISSUE_STEP(AbNext, 0, buf ^ 1);

            // phase 2: compute current buffer
#pragma unroll
            for (int ks = 0; ks < 2; ++ks) {
                const int cp = ks ? cp1 : cp0;
                f16x8 af[4], bf[4];
#pragma unroll
                for (int f = 0; f < 4; ++f) {
                    af[f] = *(const f16x8*)&As[buf][wr * 64 + f * 16 + l15][cp];
                    bf[f] = *(const f16x8*)&Bs[buf][wc * 64 + f * 16 + l15][cp];
                }
#pragma unroll
                for (int i = 0; i < 4; ++i)
#pragma unroll
                    for (int j = 0; j < 4; ++j)
                        acc[i][j] = __builtin_amdgcn_mfma_f32_16x16x32_f16(
                            af[i], bf[j], acc[i][j], 0, 0, 0);
            }

            __syncthreads();   // drains vmcnt (next-step loads landed) + sync
            buf ^= 1;
        }
        Ab = AbNext;

        // fold this tile's 16 scores per query into the running top-4
        // (register-only: no LDS, no barriers — pipeline flows across tiles)
        const int rowbase = ntile * 128 + wr * 64 + lg * 4;
#pragma unroll
        for (int q = 0; q < 4; ++q) {
            float mx = acc[0][q][0];
#pragma unroll
            for (int i = 0; i < 4; ++i)
#pragma unroll
                for (int r = 0; r < 4; ++r) mx = fmaxf(mx, acc[i][q][r]);
            if (mx >= rv[q][TK - 1]) {          // rare: tile can contribute
#pragma unroll
                for (int i = 0; i < 4; ++i)
#pragma unroll
                    for (int r = 0; r < 4; ++r) {
                        const int ng = rowbase + i * 16 + r;
                        float cv = acc[i][q][r];
                        if (ng < N_M && better(cv, ng, rv[q][TK - 1], ri[q][TK - 1])) {
                            int ci = ng;
#pragma unroll
                            for (int k = 0; k < TK; ++k) {
                                bool b = better(cv, ci, rv[q][k], ri[q][k]);
                                float nv = b ? cv : rv[q][k]; int ni = b ? ci : ri[q][k];
                                float ov = b ? rv[q][k] : cv; int oi = b ? ri[q][k] : ci;
                                rv[q][k] = nv; ri[q][k] = ni; cv = ov; ci = oi;
                            }
                        }
                    }
            }
        }
    }
#undef ISSUE_STEP

    // write per-thread sorted-4 lists; 8 owner threads per query column.
    const int owner = wr * 4 + lg;      // 0..7
#pragma unroll
    for (int q = 0; q < 4; ++q) {
        const int qg = qtile * 128 + wc * 64 + q * 16 + l15;
        Cand* dst = cand + (((size_t)qg * nsuper + sup) * 8 + owner) * TK;
#pragma unroll
        for (int k = 0; k < TK; ++k) {
            Cand c; c.v = rv[q][k]; c.i = ri[q][k];
            dst[k] = c;
        }
    }
}

// ---------------------------------------------------------------------------
// Kernel 2: per query, reduce ncand candidates to global approx top-16.
// ---------------------------------------------------------------------------
__global__ __launch_bounds__(64)
void knn_top16(const Cand* __restrict__ cand, int* __restrict__ top_idx, int ncand)
{
    __shared__ float lv[64][NC];
    __shared__ int   li[64][NC];

    const int q = blockIdx.x;
    const int lane = threadIdx.x;
    const Cand* rowp = cand + (size_t)q * ncand;

    float tv[NC]; int ti[NC];
#pragma unroll
    for (int k = 0; k < NC; ++k) { tv[k] = -INFINITY; ti[k] = 0; }

#pragma unroll 1
    for (int e = lane; e < ncand; e += 64) {
        Cand c = rowp[e];
        if (better(c.v, c.i, tv[NC - 1], ti[NC - 1])) {
            float cv = c.v; int ci = c.i;
#pragma unroll
            for (int k = 0; k < NC; ++k) {
                bool b = better(cv, ci, tv[k], ti[k]);
                float nv = b ? cv : tv[k]; int ni = b ? ci : ti[k];
                float ov = b ? tv[k] : cv; int oi = b ? ti[k] : ci;
                tv[k] = nv; ti[k] = ni; cv = ov; ci = oi;
            }
        }
    }

#pragma unroll
    for (int k = 0; k < NC; ++k) { lv[lane][k] = tv[k]; li[lane][k] = ti[k]; }
    __syncthreads();

    if (lane == 0) {
#pragma unroll 1
        for (int l = 1; l < 64; ++l) {
#pragma unroll 1
            for (int k = 0; k < NC; ++k) {
                float v = lv[l][k]; int i = li[l][k];
                if (!better(v, i, tv[NC - 1], ti[NC - 1])) break; // lists sorted desc
                float cv = v; int ci = i;
#pragma unroll
                for (int kk = 0; kk < NC; ++kk) {
                    bool b = better(cv, ci, tv[kk], ti[kk]);
                    float nv = b ? cv : tv[kk]; int ni = b ? ci : ti[kk];
                    float ov = b ? tv[kk] : cv; int oi = b ? ti[kk] : ci;
                    tv[kk] = nv; ti[kk] = ni; cv = ov; ci = oi;
                }
            }
        }
#pragma unroll
        for (int k = 0; k < NC; ++k) top_idx[q * NC + k] = ti[k];
    }
}

// ---------------------------------------------------------------------------
// Kernel 3: exact fp64 rescore of the 16 candidates, top-k, gather-average.
// ---------------------------------------------------------------------------
__global__ __launch_bounds__(256)
void knn_rescore(const float* __restrict__ Qm, const float* __restrict__ Mm,
                 const float* __restrict__ Sm, const int* __restrict__ topk_p,
                 const int* __restrict__ top_idx, float* __restrict__ outp)
{
    const int q   = blockIdx.x;
    const int tid = threadIdx.x;
    const int wid = tid >> 6, lane = tid & 63;

    __shared__ double sval[NC];
    __shared__ int    sidx[NC];
    __shared__ int    chosen[NC];

    int k = *topk_p;
    if (k > NC) k = NC;
    if (k < 1)  k = 1;

    const float* qrow = Qm + (size_t)q * D_DIM;
#pragma unroll 1
    for (int ci = wid; ci < NC; ci += 4) {
        int idx = top_idx[q * NC + ci];
        if (idx < 0)    idx = 0;
        if (idx >= N_M) idx = N_M - 1;
        const f32x4* mp = (const f32x4*)(Mm + (size_t)idx * D_DIM) + lane * 4;
        const f32x4* qp = (const f32x4*)qrow + lane * 4;
        double dot = 0.0, ss = 0.0;
#pragma unroll
        for (int j = 0; j < 4; ++j) {
            f32x4 mv = mp[j], qv = qp[j];
#pragma unroll
            for (int u = 0; u < 4; ++u) {
                dot += (double)mv[u] * (double)qv[u];
                ss  += (double)mv[u] * (double)mv[u];
            }
        }
#pragma unroll
        for (int off = 1; off <= 32; off <<= 1) {
            dot += __shfl_xor(dot, off, 64);
            ss  += __shfl_xor(ss, off, 64);
        }
        if (lane == 0) { sval[ci] = ss > 0.0 ? dot / sqrt(ss) : -1e300; sidx[ci] = idx; }
    }
    __syncthreads();

    if (tid == 0) {
        unsigned used = 0;
        for (int j = 0; j < k; ++j) {
            int best = -1;
            for (int i = 0; i < NC; ++i) {
                if (used & (1u << i)) continue;
                if (best < 0 || sval[i] > sval[best] ||
                    (sval[i] == sval[best] && sidx[i] < sidx[best])) best = i;
            }
            used |= 1u << best;
            chosen[j] = sidx[best];
        }
    }
    __syncthreads();

    const int d0 = tid * 4;
    f32x4 a = zero4();
    for (int j = 0; j < k; ++j) {
        f32x4 s4 = *(const f32x4*)(Sm + (size_t)chosen[j] * D_DIM + d0);
        a = a + s4;
    }
    const float inv = 1.0f / (float)k;
    a = a * inv;
    *(f32x4*)(outp + (size_t)q * D_DIM + d0) = a;
}

// ---------------------------------------------------------------------------
// Middle path (round-7 verbatim, proven): norms + fp32-staged GEMM select.
// Uses PLAIN (unswizzled) Qh.
// ---------------------------------------------------------------------------
__global__ __launch_bounds__(256)
void knn_norms(const float* __restrict__ Mm, float* __restrict__ invn)
{
    const int wid  = threadIdx.x >> 6;
    const int lane = threadIdx.x & 63;
    const int r    = blockIdx.x * 4 + wid;
    if (r >= N_M) return;
    const f32x4* mp = (const f32x4*)(Mm + (size_t)r * D_DIM) + lane * 4;
    float ss = 0.f;
#pragma unroll
    for (int j = 0; j < 4; ++j) {
        f32x4 v = mp[j];
#pragma unroll
        for (int u = 0; u < 4; ++u) ss += v[u] * v[u];
    }
#pragma unroll
    for (int off = 1; off <= 32; off <<= 1) ss += __shfl_xor(ss, off, 64);
    if (lane == 0) invn[r] = ss > 0.f ? rsqrtf(ss) : 0.f;
}

__global__ __launch_bounds__(256)
void knn_gemm_select(const _Float16* __restrict__ Qh, const float* __restrict__ Mm,
                     const float* __restrict__ invn, Cand* __restrict__ cand,
                     int tpbn, int nsuper)
{
    __shared__ _Float16 As[128][LDH];
    __shared__ _Float16 Bs[128][LDH];
    __shared__ _Float16 Ss[128][SSW];
    __shared__ float    sinv[128];

    const int qtile = blockIdx.x & (QTILES - 1);
    const int sup   = blockIdx.x >> 4;
    const int nt0   = sup * tpbn;
    int nt1 = nt0 + tpbn;
    if (nt1 > NTILES) nt1 = NTILES;

    const int tid = threadIdx.x;
    const int row = tid >> 1;
    const int kh  = tid & 1;

    const int qrow_g = qtile * 128 + row;
    const _Float16* bbase = Qh + (size_t)qrow_g * D_DIM + kh * 16;

    const int lane = tid & 63;
    const int wid  = tid >> 6;
    const int wr   = wid >> 1;
    const int wc   = wid & 1;
    const int l15  = lane & 15;
    const int lg   = lane >> 4;

    float rv[NC]; int ri[NC];
#pragma unroll
    for (int k = 0; k < NC; ++k) { rv[k] = -INFINITY; ri[k] = 0; }

#pragma unroll 1
    for (int ntile = nt0; ntile < nt1; ++ntile) {
        const int nrow_g = ntile * 128 + row;
        const bool a_ok  = nrow_g < N_M;
        const float* abase = Mm + (size_t)nrow_g * D_DIM + kh * 16;

        f32x4 acc[4][4];
#pragma unroll
        for (int i = 0; i < 4; ++i)
#pragma unroll
            for (int j = 0; j < 4; ++j) acc[i][j] = zero4();

        f32x4 ar[4];
        f16x8 brh[2];
#pragma unroll
        for (int i = 0; i < 4; ++i) ar[i] = a_ok ? ((const f32x4*)abase)[i] : zero4();
        brh[0] = *(const f16x8*)(bbase);
        brh[1] = *(const f16x8*)(bbase + 8);

#pragma unroll 1
        for (int t = 0; t < KSTEPS; ++t) {
            __syncthreads();

            f16x8 ha0, ha1;
#pragma unroll
            for (int i = 0; i < 2; ++i)
#pragma unroll
                for (int j = 0; j < 4; ++j) {
                    ha0[i * 4 + j] = (_Float16)ar[i][j];
                    ha1[i * 4 + j] = (_Float16)ar[i + 2][j];
                }
            *(f16x8*)&As[row][kh * 16]     = ha0;
            *(f16x8*)&As[row][kh * 16 + 8] = ha1;
            *(f16x8*)&Bs[row][kh * 16]     = brh[0];
            *(f16x8*)&Bs[row][kh * 16 + 8] = brh[1];

            __syncthreads();

            if (t + 1 < KSTEPS) {
                const float*    ap = abase + (t + 1) * BK;
                const _Float16* bp = bbase + (t + 1) * BK;
#pragma unroll
                for (int i = 0; i < 4; ++i) ar[i] = a_ok ? ((const f32x4*)ap)[i] : zero4();
                brh[0] = *(const f16x8*)(bp);
                brh[1] = *(const f16x8*)(bp + 8);
            }

            f16x8 af[4], bf[4];
#pragma unroll
            for (int f = 0; f < 4; ++f) {
                af[f] = *(const f16x8*)&As[wr * 64 + f * 16 + l15][lg * 8];
                bf[f] = *(const f16x8*)&Bs[wc * 64 + f * 16 + l15][lg * 8];
            }
#pragma unroll
            for (int i = 0; i < 4; ++i)
#pragma unroll
                for (int j = 0; j < 4; ++j)
                    acc[i][j] = __builtin_amdgcn_mfma_f32_16x16x32_f16(
                        af[i], bf[j], acc[i][j], 0, 0, 0);
        }

        if (tid < 128) {
            const int r = ntile * 128 + tid;
            sinv[tid] = (r < N_M) ? invn[r] : 0.f;
        }

#pragma unroll 1
        for (int h = 0; h < 2; ++h) {
            __syncthreads();
            if (wr == h) {
#pragma unroll
                for (int fr = 0; fr < 4; ++fr)
#pragma unroll
                    for (int fc = 0; fc < 4; ++fc) {
                        f16x4 v;
#pragma unroll
                        for (int r = 0; r < 4; ++r) v[r] = (_Float16)acc[fr][fc][r];
                        *(f16x4*)&Ss[wc * 64 + fc * 16 + l15][fr * 16 + lg * 4] = v;
                    }
            }
            __syncthreads();

            if (tid < 128) {
                const int base = ntile * 128 + h * 64;
                int nval = N_M - base;
                if (nval > 64) nval = 64;
#pragma unroll 1
                for (int c = 0; c < nval; c += 8) {
                    f16x8 sv = *(const f16x8*)&Ss[tid][c];
                    f32x4 sa = *(const f32x4*)&sinv[h * 64 + c];
                    f32x4 sb = *(const f32x4*)&sinv[h * 64 + c + 4];
                    const int lim = (nval - c >= 8) ? 8 : (nval - c);
                    float s[8];
#pragma unroll
                    for (int j = 0; j < 4; ++j) {
                        s[j]     = (float)sv[j] * sa[j];
                        s[4 + j] = (float)sv[4 + j] * sb[j];
                    }
                    if (lim < 8)
#pragma unroll
                        for (int j = 0; j < 8; ++j)
                            if (j >= lim) s[j] = -INFINITY;
                    float m01 = fmaxf(s[0], s[1]), m23 = fmaxf(s[2], s[3]);
                    float m45 = fmaxf(s[4], s[5]), m67 = fmaxf(s[6], s[7]);
                    float mx = fmaxf(fmaxf(m01, m23), fmaxf(m45, m67));
                    if (mx >= rv[NC - 1]) {
#pragma unroll 1
                        for (int j = 0; j < 8; ++j) {
                            if (j >= lim) break;
                            float cv = s[j]; int ci = base + c + j;
                            if (better(cv, ci, rv[NC - 1], ri[NC - 1])) {
#pragma unroll
                                for (int k = 0; k < NC; ++k) {
                                    bool b = better(cv, ci, rv[k], ri[k]);
                                    float nv = b ? cv : rv[k]; int ni = b ? ci : ri[k];
                                    float ov = b ? rv[k] : cv; int oi = b ? ri[k] : ci;
                                    rv[k] = nv; ri[k] = ni; cv = ov; ci = oi;
                                }
                            }
                        }
                    }
                }
            }
        }
    }

    if (tid < 128) {
        const int qg = qtile * 128 + tid;
        Cand* dst = cand + ((size_t)qg * nsuper + sup) * NC;
#pragma unroll
        for (int k = 0; k < NC; ++k) { Cand c; c.v = rv[k]; c.i = ri[k]; dst[k] = c; }
    }
}

// ---------------------------------------------------------------------------
// Fallback: round-5 brute force, verbatim (proven: passed, absmax 0.0).
// ---------------------------------------------------------------------------
#define FNC 8
__global__ __launch_bounds__(256)
void knn_all(const float* __restrict__ Qm, const float* __restrict__ Mm,
             const float* __restrict__ Sm, const int* __restrict__ topk_p,
             float* __restrict__ outp)
{
    __shared__ float  qs[D_DIM];
    __shared__ float  wv[4][FNC];
    __shared__ int    wi[4][FNC];
    __shared__ int    cand8[FNC];
    __shared__ double dval[FNC];
    __shared__ int    chosen[FNC];
    __shared__ int    sk;

    const int q    = blockIdx.x;
    const int tid  = threadIdx.x;
    const int wid  = tid >> 6;
    const int lane = tid & 63;

    for (int i = tid; i < D_DIM / 4; i += 256)
        ((f32x4*)qs)[i] = ((const f32x4*)(Qm + (size_t)q * D_DIM))[i];
    __syncthreads();

    float tv[FNC]; int ti[FNC];
#pragma unroll
    for (int k = 0; k < FNC; ++k) { tv[k] = -INFINITY; ti[k] = 0; }

    for (int r = wid; r < N_M; r += 4) {
        const f32x4* mp = (const f32x4*)(Mm + (size_t)r * D_DIM) + lane * 4;
        const f32x4* qp = (const f32x4*)qs + lane * 4;
        float dot = 0.f, ss = 0.f;
#pragma unroll
        for (int j = 0; j < 4; ++j) {
            f32x4 mv = mp[j], qv = qp[j];
#pragma unroll
            for (int u = 0; u < 4; ++u) { dot += mv[u] * qv[u]; ss += mv[u] * mv[u]; }
        }
#pragma unroll
        for (int off = 1; off <= 32; off <<= 1) {
            dot += __shfl_xor(dot, off, 64);
            ss  += __shfl_xor(ss,  off, 64);
        }
        float s = ss > 0.f ? dot * rsqrtf(ss) : -INFINITY;
        if (better(s, r, tv[FNC - 1], ti[FNC - 1])) {
            float cv = s; int ci = r;
#pragma unroll
            for (int k = 0; k < FNC; ++k) {
                bool b = better(cv, ci, tv[k], ti[k]);
                float nv = b ? cv : tv[k]; int ni = b ? ci : ti[k];
                float ov = b ? tv[k] : cv; int oi = b ? ti[k] : ci;
                tv[k] = nv; ti[k] = ni; cv = ov; ci = oi;
            }
        }
    }

    if (lane == 0)
#pragma unroll
        for (int k = 0; k < FNC; ++k) { wv[wid][k] = tv[k]; wi[wid][k] = ti[k]; }
    __syncthreads();

    if (tid == 0) {
        unsigned used = 0;
        for (int j = 0; j < FNC; ++j) {
            float bv = -INFINITY; int bi = 0; int bs = -1;
            for (int s = 0; s < 4 * FNC; ++s) {
                if (used & (1u << s)) continue;
                float v = wv[s >> 3][s & 7]; int i = wi[s >> 3][s & 7];
                if (bs < 0 || better(v, i, bv, bi)) { bv = v; bi = i; bs = s; }
            }
            used |= 1u << bs;
            cand8[j] = bi;
        }
        int kk = *topk_p;
        if (kk < 1) kk = 1;
        if (kk > FNC) kk = FNC;
        sk = kk;
    }
    __syncthreads();

    for (int ci = wid; ci < FNC; ci += 4) {
        int idx = cand8[ci];
        if (idx < 0)     idx = 0;
        if (idx >= N_M)  idx = N_M - 1;
        const f32x4* mp = (const f32x4*)(Mm + (size_t)idx * D_DIM) + lane * 4;
        const f32x4* qp = (const f32x4*)qs + lane * 4;
        double dot = 0.0, ss = 0.0;
#pragma unroll
        for (int j = 0; j < 4; ++j) {
            f32x4 mv = mp[j], qv = qp[j];
#pragma unroll
            for (int u = 0; u < 4; ++u) {
                dot += (double)mv[u] * (double)qv[u];
                ss  += (double)mv[u] * (double)mv[u];
            }
        }
#pragma unroll
        for (int off = 1; off <= 32; off <<= 1) {
            dot += __shfl_xor(dot, off, 64);
            ss  += __shfl_xor(ss, off, 64);
        }
        if (lane == 0) dval[ci] = ss > 0.0 ? dot / sqrt(ss) : -1e300;
    }
    __syncthreads();

    if (tid == 0) {
        int kk = sk;
        unsigned used = 0;
        for (int j = 0; j < kk; ++j) {
            int best = -1;
            for (int i = 0; i < FNC; ++i) {
                if (used & (1u << i)) continue;
                if (best < 0 || dval[i] > dval[best] ||
                    (dval[i] == dval[best] && cand8[i] < cand8[best])) best = i;
            }
            used |= 1u << best;
            chosen[j] = cand8[best];
        }
    }
    __syncthreads();

    const int kk = sk;
    const int d0 = tid * 4;
    f32x4 a = zero4();
    for (int j = 0; j < kk; ++j) {
        f32x4 s4 = *(const f32x4*)(Sm + (size_t)chosen[j] * D_DIM + d0);
        a = a + s4;
    }
    const float inv = 1.0f / (float)kk;
    a = a * inv;
    *(f32x4*)(outp + (size_t)q * D_DIM + d0) = a;
}

// ---------------------------------------------------------------------------
extern "C" void kernel_launch(void* const* d_in, const int* in_sizes, int n_in,
                              void* d_out, int out_size, void* d_ws, size_t ws_size,
                              hipStream_t stream)
{
    (void)in_sizes; (void)n_in; (void)out_size;

    const float* Qm   = (const float*)d_in[0];
    const float* Mm   = (const float*)d_in[1];
    const float* Sm   = (const float*)d_in[2];
    const int*   topk = (const int*)d_in[3];
    float*       outp = (float*)d_out;

    const size_t A511      = 511;
    const size_t mh_bytes  = (((size_t)MPAD * D_DIM * sizeof(_Float16)) + A511) & ~A511;
    const size_t qh_bytes  = (size_t)QPAD * D_DIM * sizeof(_Float16);                 // 4 MiB
    const size_t inv_bytes = ((size_t)N_M * sizeof(float) + A511) & ~A511;
    const size_t ti_bytes  = (((size_t)T_Q * NC * sizeof(int)) + A511) & ~A511;
    const size_t per_sup_m = (size_t)QPAD * 8 * TK * sizeof(Cand);    // main: 512 KiB
    const size_t per_sup_s = (size_t)QPAD * NC * sizeof(Cand);        // middle: 256 KiB

    if (d_ws != nullptr) {
        // ---- main path: ns must be a multiple of 8 (XCD grouping) ----
        const int ns_opts[4] = { 48, 24, 16, 8 };
        int ns = 0;
        for (int i = 0; i < 4; ++i) {
            size_t need = mh_bytes + qh_bytes + ti_bytes + (size_t)ns_opts[i] * per_sup_m;
            if (need <= ws_size) { ns = ns_opts[i]; break; }
        }
        if (ns >= 8) {
            const int tpbn = (NTILES + ns - 1) / ns;

            _Float16* Mh      = (_Float16*)d_ws;
            _Float16* Qh      = (_Float16*)((char*)d_ws + mh_bytes);
            int*      top_idx = (int*)((char*)d_ws + mh_bytes + qh_bytes);
            Cand*     cand    = (Cand*)((char*)d_ws + mh_bytes + qh_bytes + ti_bytes);

            hipLaunchKernelGGL(knn_qcvt, dim3(QPAD * D_DIM / 2048), dim3(256), 0, stream,
                               Qm, Qh);
            hipLaunchKernelGGL(knn_mcvt, dim3(MPAD / 4), dim3(256), 0, stream,
                               Mm, Mh);
            hipLaunchKernelGGL(knn_gemm_select_h, dim3(QTILES * ns), dim3(256), 0, stream,
                               Qh, Mh, cand, tpbn, ns);
            hipLaunchKernelGGL(knn_top16, dim3(T_Q), dim3(64), 0, stream,
                               cand, top_idx, ns * 8 * TK);
            hipLaunchKernelGGL(knn_rescore, dim3(T_Q), dim3(256), 0, stream,
                               Qm, Mm, Sm, topk, top_idx, outp);
            return;
        }

        // ---- middle path: round-7 structure (~20 MB of workspace) ----
        long long avail = (long long)ws_size
                        - (long long)(inv_bytes + qh_bytes + ti_bytes);
        int ns2 = avail > 0 ? (int)(avail / (long long)per_sup_s) : 0;
        if (ns2 > 64) ns2 = 64;
        if (ns2 >= 1) {
            int tpbn = (NTILES + ns2 - 1) / ns2;
            ns2 = (NTILES + tpbn - 1) / tpbn;

            float*    invn    = (float*)d_ws;
            _Float16* Qh      = (_Float16*)((char*)d_ws + inv_bytes);
            int*      top_idx = (int*)((char*)d_ws + inv_bytes + qh_bytes);
            Cand*     cand    = (Cand*)((char*)d_ws + inv_bytes + qh_bytes + ti_bytes);

            hipLaunchKernelGGL(knn_qcvt_plain, dim3(QPAD * D_DIM / 2048), dim3(256), 0, stream,
                               Qm, Qh);
            hipLaunchKernelGGL(knn_norms, dim3((N_M + 3) / 4), dim3(256), 0, stream,
                               Mm, invn);
            hipLaunchKernelGGL(knn_gemm_select, dim3(QTILES * ns2), dim3(256), 0, stream,
                               Qh, Mm, invn, cand, tpbn, ns2);
            hipLaunchKernelGGL(knn_top16, dim3(T_Q), dim3(64), 0, stream,
                               cand, top_idx, ns2 * NC);
            hipLaunchKernelGGL(knn_rescore, dim3(T_Q), dim3(256), 0, stream,
                               Qm, Mm, Sm, topk, top_idx, outp);
            return;
        }
    }

    // ---- last resort: zero-workspace brute force ----
    hipLaunchKernelGGL(knn_all, dim3(T_Q), dim3(256), 0, stream,
                       Qm, Mm, Sm, topk, outp);
}

// Round 15
// 886.520 us; speedup vs baseline: 41.0108x; 1.3161x over previous
//
#include <hip/hip_runtime.h>
#include <math.h>

#define T_Q    2000
#define N_M    100000
#define D_DIM  1024
#define QTILES 16
#define NTILES 782          // ceil(100000/128)
#define MPAD   (NTILES * 128)   // 100096 zero-padded fp16 M rows
#define BK     32           // middle-path K-step
#define KSTEPS (D_DIM / BK)
#define KST3   32           // main-path steps per tile (BK=32)
#define LDH    40           // middle-path A/B LDS row stride in halves (80 B)
#define SSW    72           // middle-path score tile row stride in halves
#define NC     16           // rescore candidate superset per query
#define QPAD   2048
#define TK     4            // per-thread per-query kept candidates (main path)

typedef _Float16 f16x8 __attribute__((ext_vector_type(8)));
typedef _Float16 f16x4 __attribute__((ext_vector_type(4)));
typedef float    f32x4 __attribute__((ext_vector_type(4)));
typedef unsigned int u32;

struct __align__(8) Cand { float v; int i; };
static_assert(sizeof(Cand) == 8, "cand size");

__device__ __forceinline__ bool better(float av, int ai, float bv, int bi) {
    return (av > bv) || (av == bv && ai < bi);
}

__device__ __forceinline__ f32x4 zero4() {
    f32x4 z; z[0] = 0.f; z[1] = 0.f; z[2] = 0.f; z[3] = 0.f; return z;
}

// async global->LDS, 16 B per lane (dest pattern: wave-uniform base + lane*16)
__device__ __forceinline__ void gload16(const _Float16* g, _Float16* l) {
    const __attribute__((address_space(1))) u32* gp =
        (const __attribute__((address_space(1))) u32*)g;
    __attribute__((address_space(3))) u32* lp =
        (__attribute__((address_space(3))) u32*)l;
    __builtin_amdgcn_global_load_lds(gp, lp, 16, 0, 0);
}

// swizzle helper: within each 64B group (4 x 16B chunks) of a row, data
// chunk c is stored at position (c&~3) | ((c&3) ^ s), s = (row&3)^((row>>2)&1).
// Verified bank-mapping: every fragment ds_read_b128 lands 2 lanes/bank-quad
// (2-way aliasing = free). Staging is linear; the read applies the same XOR.
__device__ __forceinline__ int swz_s(int row) {
    return (row & 3) ^ ((row >> 2) & 1);
}

// ---------------------------------------------------------------------------
// Kernel Q (main path): fp16 convert + 4-chunk swizzle.
// ---------------------------------------------------------------------------
__global__ __launch_bounds__(256)
void knn_qcvt(const float* __restrict__ Qm, _Float16* __restrict__ Qh)
{
    const size_t base = (size_t)blockIdx.x * 2048 + (size_t)threadIdx.x * 8;
    const int row = (int)(base >> 10);
    const int hr  = (int)(base & 1023);
    f16x8 h;
    if (row < T_Q) {
        f32x4 a = *(const f32x4*)(Qm + base);
        f32x4 b = *(const f32x4*)(Qm + base + 4);
#pragma unroll
        for (int j = 0; j < 4; ++j) { h[j] = (_Float16)a[j]; h[4 + j] = (_Float16)b[j]; }
    } else {
#pragma unroll
        for (int j = 0; j < 8; ++j) h[j] = (_Float16)0.f;
    }
    const int g = hr >> 3;
    const int p = (g & ~3) | ((g & 3) ^ swz_s(row));
    *(f16x8*)(Qh + ((size_t)row << 10) + p * 8) = h;
}

// plain (unswizzled) variant for the middle path
__global__ __launch_bounds__(256)
void knn_qcvt_plain(const float* __restrict__ Qm, _Float16* __restrict__ Qh)
{
    const size_t base = (size_t)blockIdx.x * 2048 + (size_t)threadIdx.x * 8;
    const int row = (int)(base >> 10);
    f16x8 h;
    if (row < T_Q) {
        f32x4 a = *(const f32x4*)(Qm + base);
        f32x4 b = *(const f32x4*)(Qm + base + 4);
#pragma unroll
        for (int j = 0; j < 4; ++j) { h[j] = (_Float16)a[j]; h[4 + j] = (_Float16)b[j]; }
    } else {
#pragma unroll
        for (int j = 0; j < 8; ++j) h[j] = (_Float16)0.f;
    }
    *(f16x8*)(Qh + base) = h;
}

// ---------------------------------------------------------------------------
// Kernel M: fused norm + prescale + fp16 convert + zero-pad + 4-chunk swizzle.
// ---------------------------------------------------------------------------
__global__ __launch_bounds__(256)
void knn_mcvt(const float* __restrict__ Mm, _Float16* __restrict__ Mh)
{
    const int wid  = threadIdx.x >> 6;
    const int lane = threadIdx.x & 63;
    const int r    = blockIdx.x * 4 + wid;   // grid covers MPAD rows
    f16x8 h0, h1;
    if (r < N_M) {
        const f32x4* mp = (const f32x4*)(Mm + (size_t)r * D_DIM) + lane * 4;
        f32x4 v0 = mp[0], v1 = mp[1], v2 = mp[2], v3 = mp[3];
        float ss = 0.f;
#pragma unroll
        for (int u = 0; u < 4; ++u)
            ss += v0[u] * v0[u] + v1[u] * v1[u] + v2[u] * v2[u] + v3[u] * v3[u];
#pragma unroll
        for (int off = 1; off <= 32; off <<= 1) ss += __shfl_xor(ss, off, 64);
        const float inv = ss > 0.f ? rsqrtf(ss) : 0.f;
#pragma unroll
        for (int u = 0; u < 4; ++u) {
            h0[u]     = (_Float16)(v0[u] * inv);
            h0[4 + u] = (_Float16)(v1[u] * inv);
            h1[u]     = (_Float16)(v2[u] * inv);
            h1[4 + u] = (_Float16)(v3[u] * inv);
        }
    } else {
#pragma unroll
        for (int j = 0; j < 8; ++j) { h0[j] = (_Float16)0.f; h1[j] = (_Float16)0.f; }
    }
    const int s  = swz_s(r);
    const int g0 = 2 * lane;
    const int g1 = g0 + 1;
    const int p0 = (g0 & ~3) | ((g0 & 3) ^ s);
    const int p1 = (g1 & ~3) | ((g1 & 3) ^ s);
    _Float16* base = Mh + (size_t)r * D_DIM;
    *(f16x8*)(base + p0 * 8) = h0;
    *(f16x8*)(base + p1 * 8) = h1;
}

// ---------------------------------------------------------------------------
// Kernel 1 (main): fp16 MFMA scores, BK=32 double-buffered 2-phase pipeline
// (LDS 32 KiB -> 4 blocks/CU), conflict-free swizzled reads, in-register
// running top-4 select (proven absmax 0.0).
// ---------------------------------------------------------------------------
__global__ __launch_bounds__(256, 4)
void knn_gemm_select_h(const _Float16* __restrict__ Qh,
                       const _Float16* __restrict__ Mh,
                       Cand* __restrict__ cand, int tpbn, int nsuper)
{
    __shared__ _Float16 As[2][128][32];   // 16 KiB
    __shared__ _Float16 Bs[2][128][32];   // 16 KiB  (total 32 KiB)

    // XCD-aware mapping: hardware assigns bid%8 -> XCD (round-robin).
    const int bid   = blockIdx.x;
    const int c8    = bid & 7;
    const int jj0   = bid >> 3;
    const int qtile = jj0 & 15;
    const int sup   = c8 + 8 * (jj0 >> 4);

    const int nt0 = sup * tpbn;
    int nt1 = nt0 + tpbn;
    if (nt1 > NTILES) nt1 = NTILES;

    const int tid  = threadIdx.x;
    const int lane = tid & 63;
    const int wid  = tid >> 6;
    const int wr   = wid >> 1;
    const int wc   = wid & 1;
    const int l15  = lane & 15;
    const int lg   = lane >> 4;

    // writeout geometry
    const int owner = wr * 4 + lg;      // 0..7

    float rv[4][TK]; int ri[4][TK];
#pragma unroll
    for (int q = 0; q < 4; ++q)
#pragma unroll
        for (int k = 0; k < TK; ++k) { rv[q][k] = -INFINITY; ri[q][k] = 0; }

    if (nt0 >= nt1) {   // empty sup: emit -INF candidates, no loads
#pragma unroll
        for (int q = 0; q < 4; ++q) {
            const int qg = qtile * 128 + wc * 64 + q * 16 + l15;
            Cand* dst = cand + (((size_t)qg * nsuper + sup) * 8 + owner) * TK;
#pragma unroll
            for (int k = 0; k < TK; ++k) { Cand c; c.v = rv[q][k]; c.i = ri[q][k]; dst[k] = c; }
        }
        return;
    }

    // staging geometry: thread t covers 16 B at linear LDS offset t*16
    // (rows 0..63), second instr covers rows 64..127 (offset +4 KiB).
    const int srow   = tid >> 2;        // 0..63
    const int schunk = tid & 3;         // position chunk within the 64B slab

    const _Float16* Bb = Qh + ((size_t)(qtile * 128 + srow) << 10) + schunk * 8;

    // swizzled read chunk offset (halves): lane wants data chunk lg of its row
    const int cp = (lg ^ (l15 & 3) ^ ((l15 >> 2) & 1)) * 8;

#define ISSUE_STEP(Abase, koff, bi) do {                                   \
        _Float16* ad_ = &As[bi][0][0] + tid * 8;                           \
        _Float16* bd_ = &Bs[bi][0][0] + tid * 8;                           \
        gload16((Abase) + (koff),               ad_);                      \
        gload16((Abase) + (64 << 10) + (koff),  ad_ + 2048);               \
        gload16(Bb + (koff),                    bd_);                      \
        gload16(Bb + (64 << 10) + (koff),       bd_ + 2048);               \
    } while (0)

    const _Float16* Ab = Mh + ((size_t)(nt0 * 128 + srow) << 10) + schunk * 8;
    int buf = 0;

    // prologue: stage tile nt0 / step 0 into buf 0
    ISSUE_STEP(Ab, 0, 0);
    __syncthreads();

#pragma unroll 1
    for (int ntile = nt0; ntile < nt1; ++ntile) {
        const _Float16* AbNext = Ab + ((size_t)128 << 10);

        f32x4 acc[4][4];
#pragma unroll
        for (int i = 0; i < 4; ++i)
#pragma unroll
            for (int j = 0; j < 4; ++j) acc[i][j] = zero4();

#pragma unroll 1
        for (int t = 0; t < KST3; ++t) {
            // phase 1: issue next-step loads into the other buffer
            if (t + 1 < KST3)            ISSUE_STEP(Ab, (t + 1) * 32, buf ^ 1);
            else if (ntile + 1 < nt1)    ISSUE_STEP(AbNext, 0, buf ^ 1);

            // phase 2: compute current buffer (one K=32 MFMA slab)
            f16x8 af[4], bf[4];
#pragma unroll
            for (int f = 0; f < 4; ++f) {
                af[f] = *(const f16x8*)&As[buf][wr * 64 + f * 16 + l15][cp];
                bf[f] = *(const f16x8*)&Bs[buf][wc * 64 + f * 16 + l15][cp];
            }
#pragma unroll
            for (int i = 0; i < 4; ++i)
#pragma unroll
                for (int j = 0; j < 4; ++j)
                    acc[i][j] = __builtin_amdgcn_mfma_f32_16x16x32_f16(
                        af[i], bf[j], acc[i][j], 0, 0, 0);

            __syncthreads();   // readers done + next-step loads landed
            buf ^= 1;
        }
        Ab = AbNext;

        // fold this tile's 16 scores per query into the running top-4
        const int rowbase = ntile * 128 + wr * 64 + lg * 4;
#pragma unroll
        for (int q = 0; q < 4; ++q) {
            float mx = acc[0][q][0];
#pragma unroll
            for (int i = 0; i < 4; ++i)
#pragma unroll
                for (int r = 0; r < 4; ++r) mx = fmaxf(mx, acc[i][q][r]);
            if (mx >= rv[q][TK - 1]) {          // rare: tile can contribute
#pragma unroll
                for (int i = 0; i < 4; ++i)
#pragma unroll
                    for (int r = 0; r < 4; ++r) {
                        const int ng = rowbase + i * 16 + r;
                        float cv = acc[i][q][r];
                        if (ng < N_M && better(cv, ng, rv[q][TK - 1], ri[q][TK - 1])) {
                            int ci = ng;
#pragma unroll
                            for (int k = 0; k < TK; ++k) {
                                bool b = better(cv, ci, rv[q][k], ri[q][k]);
                                float nv = b ? cv : rv[q][k]; int ni = b ? ci : ri[q][k];
                                float ov = b ? rv[q][k] : cv; int oi = b ? ri[q][k] : ci;
                                rv[q][k] = nv; ri[q][k] = ni; cv = ov; ci = oi;
                            }
                        }
                    }
            }
        }
    }
#undef ISSUE_STEP

    // write per-thread sorted-4 lists; 8 owner threads per query column.
#pragma unroll
    for (int q = 0; q < 4; ++q) {
        const int qg = qtile * 128 + wc * 64 + q * 16 + l15;
        Cand* dst = cand + (((size_t)qg * nsuper + sup) * 8 + owner) * TK;
#pragma unroll
        for (int k = 0; k < TK; ++k) {
            Cand c; c.v = rv[q][k]; c.i = ri[q][k];
            dst[k] = c;
        }
    }
}

// ---------------------------------------------------------------------------
// Kernel 2: per query, reduce ncand candidates to global approx top-16.
// ---------------------------------------------------------------------------
__global__ __launch_bounds__(64)
void knn_top16(const Cand* __restrict__ cand, int* __restrict__ top_idx, int ncand)
{
    __shared__ float lv[64][NC];
    __shared__ int   li[64][NC];

    const int q = blockIdx.x;
    const int lane = threadIdx.x;
    const Cand* rowp = cand + (size_t)q * ncand;

    float tv[NC]; int ti[NC];
#pragma unroll
    for (int k = 0; k < NC; ++k) { tv[k] = -INFINITY; ti[k] = 0; }

#pragma unroll 1
    for (int e = lane; e < ncand; e += 64) {
        Cand c = rowp[e];
        if (better(c.v, c.i, tv[NC - 1], ti[NC - 1])) {
            float cv = c.v; int ci = c.i;
#pragma unroll
            for (int k = 0; k < NC; ++k) {
                bool b = better(cv, ci, tv[k], ti[k]);
                float nv = b ? cv : tv[k]; int ni = b ? ci : ti[k];
                float ov = b ? tv[k] : cv; int oi = b ? ti[k] : ci;
                tv[k] = nv; ti[k] = ni; cv = ov; ci = oi;
            }
        }
    }

#pragma unroll
    for (int k = 0; k < NC; ++k) { lv[lane][k] = tv[k]; li[lane][k] = ti[k]; }
    __syncthreads();

    if (lane == 0) {
#pragma unroll 1
        for (int l = 1; l < 64; ++l) {
#pragma unroll 1
            for (int k = 0; k < NC; ++k) {
                float v = lv[l][k]; int i = li[l][k];
                if (!better(v, i, tv[NC - 1], ti[NC - 1])) break; // lists sorted desc
                float cv = v; int ci = i;
#pragma unroll
                for (int kk = 0; kk < NC; ++kk) {
                    bool b = better(cv, ci, tv[kk], ti[kk]);
                    float nv = b ? cv : tv[kk]; int ni = b ? ci : ti[kk];
                    float ov = b ? tv[kk] : cv; int oi = b ? ti[kk] : ci;
                    tv[kk] = nv; ti[kk] = ni; cv = ov; ci = oi;
                }
            }
        }
#pragma unroll
        for (int k = 0; k < NC; ++k) top_idx[q * NC + k] = ti[k];
    }
}

// ---------------------------------------------------------------------------
// Kernel 3: exact fp64 rescore of the 16 candidates, top-k, gather-average.
// ---------------------------------------------------------------------------
__global__ __launch_bounds__(256)
void knn_rescore(const float* __restrict__ Qm, const float* __restrict__ Mm,
                 const float* __restrict__ Sm, const int* __restrict__ topk_p,
                 const int* __restrict__ top_idx, float* __restrict__ outp)
{
    const int q   = blockIdx.x;
    const int tid = threadIdx.x;
    const int wid = tid >> 6, lane = tid & 63;

    __shared__ double sval[NC];
    __shared__ int    sidx[NC];
    __shared__ int    chosen[NC];

    int k = *topk_p;
    if (k > NC) k = NC;
    if (k < 1)  k = 1;

    const float* qrow = Qm + (size_t)q * D_DIM;
#pragma unroll 1
    for (int ci = wid; ci < NC; ci += 4) {
        int idx = top_idx[q * NC + ci];
        if (idx < 0)    idx = 0;
        if (idx >= N_M) idx = N_M - 1;
        const f32x4* mp = (const f32x4*)(Mm + (size_t)idx * D_DIM) + lane * 4;
        const f32x4* qp = (const f32x4*)qrow + lane * 4;
        double dot = 0.0, ss = 0.0;
#pragma unroll
        for (int j = 0; j < 4; ++j) {
            f32x4 mv = mp[j], qv = qp[j];
#pragma unroll
            for (int u = 0; u < 4; ++u) {
                dot += (double)mv[u] * (double)qv[u];
                ss  += (double)mv[u] * (double)mv[u];
            }
        }
#pragma unroll
        for (int off = 1; off <= 32; off <<= 1) {
            dot += __shfl_xor(dot, off, 64);
            ss  += __shfl_xor(ss, off, 64);
        }
        if (lane == 0) { sval[ci] = ss > 0.0 ? dot / sqrt(ss) : -1e300; sidx[ci] = idx; }
    }
    __syncthreads();

    if (tid == 0) {
        unsigned used = 0;
        for (int j = 0; j < k; ++j) {
            int best = -1;
            for (int i = 0; i < NC; ++i) {
                if (used & (1u << i)) continue;
                if (best < 0 || sval[i] > sval[best] ||
                    (sval[i] == sval[best] && sidx[i] < sidx[best])) best = i;
            }
            used |= 1u << best;
            chosen[j] = sidx[best];
        }
    }
    __syncthreads();

    const int d0 = tid * 4;
    f32x4 a = zero4();
    for (int j = 0; j < k; ++j) {
        f32x4 s4 = *(const f32x4*)(Sm + (size_t)chosen[j] * D_DIM + d0);
        a = a + s4;
    }
    const float inv = 1.0f / (float)k;
    a = a * inv;
    *(f32x4*)(outp + (size_t)q * D_DIM + d0) = a;
}

// ---------------------------------------------------------------------------
// Middle path (round-7 verbatim, proven): norms + fp32-staged GEMM select.
// Uses PLAIN (unswizzled) Qh.
// ---------------------------------------------------------------------------
__global__ __launch_bounds__(256)
void knn_norms(const float* __restrict__ Mm, float* __restrict__ invn)
{
    const int wid  = threadIdx.x >> 6;
    const int lane = threadIdx.x & 63;
    const int r    = blockIdx.x * 4 + wid;
    if (r >= N_M) return;
    const f32x4* mp = (const f32x4*)(Mm + (size_t)r * D_DIM) + lane * 4;
    float ss = 0.f;
#pragma unroll
    for (int j = 0; j < 4; ++j) {
        f32x4 v = mp[j];
#pragma unroll
        for (int u = 0; u < 4; ++u) ss += v[u] * v[u];
    }
#pragma unroll
    for (int off = 1; off <= 32; off <<= 1) ss += __shfl_xor(ss, off, 64);
    if (lane == 0) invn[r] = ss > 0.f ? rsqrtf(ss) : 0.f;
}

__global__ __launch_bounds__(256)
void knn_gemm_select(const _Float16* __restrict__ Qh, const float* __restrict__ Mm,
                     const float* __restrict__ invn, Cand* __restrict__ cand,
                     int tpbn, int nsuper)
{
    __shared__ _Float16 As[128][LDH];
    __shared__ _Float16 Bs[128][LDH];
    __shared__ _Float16 Ss[128][SSW];
    __shared__ float    sinv[128];

    const int qtile = blockIdx.x & (QTILES - 1);
    const int sup   = blockIdx.x >> 4;
    const int nt0   = sup * tpbn;
    int nt1 = nt0 + tpbn;
    if (nt1 > NTILES) nt1 = NTILES;

    const int tid = threadIdx.x;
    const int row = tid >> 1;
    const int kh  = tid & 1;

    const int qrow_g = qtile * 128 + row;
    const _Float16* bbase = Qh + (size_t)qrow_g * D_DIM + kh * 16;

    const int lane = tid & 63;
    const int wid  = tid >> 6;
    const int wr   = wid >> 1;
    const int wc   = wid & 1;
    const int l15  = lane & 15;
    const int lg   = lane >> 4;

    float rv[NC]; int ri[NC];
#pragma unroll
    for (int k = 0; k < NC; ++k) { rv[k] = -INFINITY; ri[k] = 0; }

#pragma unroll 1
    for (int ntile = nt0; ntile < nt1; ++ntile) {
        const int nrow_g = ntile * 128 + row;
        const bool a_ok  = nrow_g < N_M;
        const float* abase = Mm + (size_t)nrow_g * D_DIM + kh * 16;

        f32x4 acc[4][4];
#pragma unroll
        for (int i = 0; i < 4; ++i)
#pragma unroll
            for (int j = 0; j < 4; ++j) acc[i][j] = zero4();

        f32x4 ar[4];
        f16x8 brh[2];
#pragma unroll
        for (int i = 0; i < 4; ++i) ar[i] = a_ok ? ((const f32x4*)abase)[i] : zero4();
        brh[0] = *(const f16x8*)(bbase);
        brh[1] = *(const f16x8*)(bbase + 8);

#pragma unroll 1
        for (int t = 0; t < KSTEPS; ++t) {
            __syncthreads();

            f16x8 ha0, ha1;
#pragma unroll
            for (int i = 0; i < 2; ++i)
#pragma unroll
                for (int j = 0; j < 4; ++j) {
                    ha0[i * 4 + j] = (_Float16)ar[i][j];
                    ha1[i * 4 + j] = (_Float16)ar[i + 2][j];
                }
            *(f16x8*)&As[row][kh * 16]     = ha0;
            *(f16x8*)&As[row][kh * 16 + 8] = ha1;
            *(f16x8*)&Bs[row][kh * 16]     = brh[0];
            *(f16x8*)&Bs[row][kh * 16 + 8] = brh[1];

            __syncthreads();

            if (t + 1 < KSTEPS) {
                const float*    ap = abase + (t + 1) * BK;
                const _Float16* bp = bbase + (t + 1) * BK;
#pragma unroll
                for (int i = 0; i < 4; ++i) ar[i] = a_ok ? ((const f32x4*)ap)[i] : zero4();
                brh[0] = *(const f16x8*)(bp);
                brh[1] = *(const f16x8*)(bp + 8);
            }

            f16x8 af[4], bf[4];
#pragma unroll
            for (int f = 0; f < 4; ++f) {
                af[f] = *(const f16x8*)&As[wr * 64 + f * 16 + l15][lg * 8];
                bf[f] = *(const f16x8*)&Bs[wc * 64 + f * 16 + l15][lg * 8];
            }
#pragma unroll
            for (int i = 0; i < 4; ++i)
#pragma unroll
                for (int j = 0; j < 4; ++j)
                    acc[i][j] = __builtin_amdgcn_mfma_f32_16x16x32_f16(
                        af[i], bf[j], acc[i][j], 0, 0, 0);
        }

        if (tid < 128) {
            const int r = ntile * 128 + tid;
            sinv[tid] = (r < N_M) ? invn[r] : 0.f;
        }

#pragma unroll 1
        for (int h = 0; h < 2; ++h) {
            __syncthreads();
            if (wr == h) {
#pragma unroll
                for (int fr = 0; fr < 4; ++fr)
#pragma unroll
                    for (int fc = 0; fc < 4; ++fc) {
                        f16x4 v;
#pragma unroll
                        for (int r = 0; r < 4; ++r) v[r] = (_Float16)acc[fr][fc][r];
                        *(f16x4*)&Ss[wc * 64 + fc * 16 + l15][fr * 16 + lg * 4] = v;
                    }
            }
            __syncthreads();

            if (tid < 128) {
                const int base = ntile * 128 + h * 64;
                int nval = N_M - base;
                if (nval > 64) nval = 64;
#pragma unroll 1
                for (int c = 0; c < nval; c += 8) {
                    f16x8 sv = *(const f16x8*)&Ss[tid][c];
                    f32x4 sa = *(const f32x4*)&sinv[h * 64 + c];
                    f32x4 sb = *(const f32x4*)&sinv[h * 64 + c + 4];
                    const int lim = (nval - c >= 8) ? 8 : (nval - c);
                    float s[8];
#pragma unroll
                    for (int j = 0; j < 4; ++j) {
                        s[j]     = (float)sv[j] * sa[j];
                        s[4 + j] = (float)sv[4 + j] * sb[j];
                    }
                    if (lim < 8)
#pragma unroll
                        for (int j = 0; j < 8; ++j)
                            if (j >= lim) s[j] = -INFINITY;
                    float m01 = fmaxf(s[0], s[1]), m23 = fmaxf(s[2], s[3]);
                    float m45 = fmaxf(s[4], s[5]), m67 = fmaxf(s[6], s[7]);
                    float mx = fmaxf(fmaxf(m01, m23), fmaxf(m45, m67));
                    if (mx >= rv[NC - 1]) {
#pragma unroll 1
                        for (int j = 0; j < 8; ++j) {
                            if (j >= lim) break;
                            float cv = s[j]; int ci = base + c + j;
                            if (better(cv, ci, rv[NC - 1], ri[NC - 1])) {
#pragma unroll
                                for (int k = 0; k < NC; ++k) {
                                    bool b = better(cv, ci, rv[k], ri[k]);
                                    float nv = b ? cv : rv[k]; int ni = b ? ci : ri[k];
                                    float ov = b ? rv[k] : cv; int oi = b ? ri[k] : ci;
                                    rv[k] = nv; ri[k] = ni; cv = ov; ci = oi;
                                }
                            }
                        }
                    }
                }
            }
        }
    }

    if (tid < 128) {
        const int qg = qtile * 128 + tid;
        Cand* dst = cand + ((size_t)qg * nsuper + sup) * NC;
#pragma unroll
        for (int k = 0; k < NC; ++k) { Cand c; c.v = rv[k]; c.i = ri[k]; dst[k] = c; }
    }
}

// ---------------------------------------------------------------------------
// Fallback: round-5 brute force, verbatim (proven: passed, absmax 0.0).
// ---------------------------------------------------------------------------
#define FNC 8
__global__ __launch_bounds__(256)
void knn_all(const float* __restrict__ Qm, const float* __restrict__ Mm,
             const float* __restrict__ Sm, const int* __restrict__ topk_p,
             float* __restrict__ outp)
{
    __shared__ float  qs[D_DIM];
    __shared__ float  wv[4][FNC];
    __shared__ int    wi[4][FNC];
    __shared__ int    cand8[FNC];
    __shared__ double dval[FNC];
    __shared__ int    chosen[FNC];
    __shared__ int    sk;

    const int q    = blockIdx.x;
    const int tid  = threadIdx.x;
    const int wid  = tid >> 6;
    const int lane = tid & 63;

    for (int i = tid; i < D_DIM / 4; i += 256)
        ((f32x4*)qs)[i] = ((const f32x4*)(Qm + (size_t)q * D_DIM))[i];
    __syncthreads();

    float tv[FNC]; int ti[FNC];
#pragma unroll
    for (int k = 0; k < FNC; ++k) { tv[k] = -INFINITY; ti[k] = 0; }

    for (int r = wid; r < N_M; r += 4) {
        const f32x4* mp = (const f32x4*)(Mm + (size_t)r * D_DIM) + lane * 4;
        const f32x4* qp = (const f32x4*)qs + lane * 4;
        float dot = 0.f, ss = 0.f;
#pragma unroll
        for (int j = 0; j < 4; ++j) {
            f32x4 mv = mp[j], qv = qp[j];
#pragma unroll
            for (int u = 0; u < 4; ++u) { dot += mv[u] * qv[u]; ss += mv[u] * mv[u]; }
        }
#pragma unroll
        for (int off = 1; off <= 32; off <<= 1) {
            dot += __shfl_xor(dot, off, 64);
            ss  += __shfl_xor(ss,  off, 64);
        }
        float s = ss > 0.f ? dot * rsqrtf(ss) : -INFINITY;
        if (better(s, r, tv[FNC - 1], ti[FNC - 1])) {
            float cv = s; int ci = r;
#pragma unroll
            for (int k = 0; k < FNC; ++k) {
                bool b = better(cv, ci, tv[k], ti[k]);
                float nv = b ? cv : tv[k]; int ni = b ? ci : ti[k];
                float ov = b ? tv[k] : cv; int oi = b ? ti[k] : ci;
                tv[k] = nv; ti[k] = ni; cv = ov; ci = oi;
            }
        }
    }

    if (lane == 0)
#pragma unroll
        for (int k = 0; k < FNC; ++k) { wv[wid][k] = tv[k]; wi[wid][k] = ti[k]; }
    __syncthreads();

    if (tid == 0) {
        unsigned used = 0;
        for (int j = 0; j < FNC; ++j) {
            float bv = -INFINITY; int bi = 0; int bs = -1;
            for (int s = 0; s < 4 * FNC; ++s) {
                if (used & (1u << s)) continue;
                float v = wv[s >> 3][s & 7]; int i = wi[s >> 3][s & 7];
                if (bs < 0 || better(v, i, bv, bi)) { bv = v; bi = i; bs = s; }
            }
            used |= 1u << bs;
            cand8[j] = bi;
        }
        int kk = *topk_p;
        if (kk < 1) kk = 1;
        if (kk > FNC) kk = FNC;
        sk = kk;
    }
    __syncthreads();

    for (int ci = wid; ci < FNC; ci += 4) {
        int idx = cand8[ci];
        if (idx < 0)     idx = 0;
        if (idx >= N_M)  idx = N_M - 1;
        const f32x4* mp = (const f32x4*)(Mm + (size_t)idx * D_DIM) + lane * 4;
        const f32x4* qp = (const f32x4*)qs + lane * 4;
        double dot = 0.0, ss = 0.0;
#pragma unroll
        for (int j = 0; j < 4; ++j) {
            f32x4 mv = mp[j], qv = qp[j];
#pragma unroll
            for (int u = 0; u < 4; ++u) {
                dot += (double)mv[u] * (double)qv[u];
                ss  += (double)mv[u] * (double)mv[u];
            }
        }
#pragma unroll
        for (int off = 1; off <= 32; off <<= 1) {
            dot += __shfl_xor(dot, off, 64);
            ss  += __shfl_xor(ss, off, 64);
        }
        if (lane == 0) dval[ci] = ss > 0.0 ? dot / sqrt(ss) : -1e300;
    }
    __syncthreads();

    if (tid == 0) {
        int kk = sk;
        unsigned used = 0;
        for (int j = 0; j < kk; ++j) {
            int best = -1;
            for (int i = 0; i < FNC; ++i) {
                if (used & (1u << i)) continue;
                if (best < 0 || dval[i] > dval[best] ||
                    (dval[i] == dval[best] && cand8[i] < cand8[best])) best = i;
            }
            used |= 1u << best;
            chosen[j] = cand8[best];
        }
    }
    __syncthreads();

    const int kk = sk;
    const int d0 = tid * 4;
    f32x4 a = zero4();
    for (int j = 0; j < kk; ++j) {
        f32x4 s4 = *(const f32x4*)(Sm + (size_t)chosen[j] * D_DIM + d0);
        a = a + s4;
    }
    const float inv = 1.0f / (float)kk;
    a = a * inv;
    *(f32x4*)(outp + (size_t)q * D_DIM + d0) = a;
}

// ---------------------------------------------------------------------------
extern "C" void kernel_launch(void* const* d_in, const int* in_sizes, int n_in,
                              void* d_out, int out_size, void* d_ws, size_t ws_size,
                              hipStream_t stream)
{
    (void)in_sizes; (void)n_in; (void)out_size;

    const float* Qm   = (const float*)d_in[0];
    const float* Mm   = (const float*)d_in[1];
    const float* Sm   = (const float*)d_in[2];
    const int*   topk = (const int*)d_in[3];
    float*       outp = (float*)d_out;

    const size_t A511      = 511;
    const size_t mh_bytes  = (((size_t)MPAD * D_DIM * sizeof(_Float16)) + A511) & ~A511;
    const size_t qh_bytes  = (size_t)QPAD * D_DIM * sizeof(_Float16);                 // 4 MiB
    const size_t inv_bytes = ((size_t)N_M * sizeof(float) + A511) & ~A511;
    const size_t ti_bytes  = (((size_t)T_Q * NC * sizeof(int)) + A511) & ~A511;
    const size_t per_sup_m = (size_t)QPAD * 8 * TK * sizeof(Cand);    // main: 512 KiB
    const size_t per_sup_s = (size_t)QPAD * NC * sizeof(Cand);        // middle: 256 KiB

    if (d_ws != nullptr) {
        // ---- main path: ns must be a multiple of 8 (XCD grouping) ----
        const int ns_opts[5] = { 64, 48, 32, 16, 8 };
        int ns = 0;
        for (int i = 0; i < 5; ++i) {
            size_t need = mh_bytes + qh_bytes + ti_bytes + (size_t)ns_opts[i] * per_sup_m;
            if (need <= ws_size) { ns = ns_opts[i]; break; }
        }
        if (ns >= 8) {
            const int tpbn = (NTILES + ns - 1) / ns;

            _Float16* Mh      = (_Float16*)d_ws;
            _Float16* Qh      = (_Float16*)((char*)d_ws + mh_bytes);
            int*      top_idx = (int*)((char*)d_ws + mh_bytes + qh_bytes);
            Cand*     cand    = (Cand*)((char*)d_ws + mh_bytes + qh_bytes + ti_bytes);

            hipLaunchKernelGGL(knn_qcvt, dim3(QPAD * D_DIM / 2048), dim3(256), 0, stream,
                               Qm, Qh);
            hipLaunchKernelGGL(knn_mcvt, dim3(MPAD / 4), dim3(256), 0, stream,
                               Mm, Mh);
            hipLaunchKernelGGL(knn_gemm_select_h, dim3(QTILES * ns), dim3(256), 0, stream,
                               Qh, Mh, cand, tpbn, ns);
            hipLaunchKernelGGL(knn_top16, dim3(T_Q), dim3(64), 0, stream,
                               cand, top_idx, ns * 8 * TK);
            hipLaunchKernelGGL(knn_rescore, dim3(T_Q), dim3(256), 0, stream,
                               Qm, Mm, Sm, topk, top_idx, outp);
            return;
        }

        // ---- middle path: round-7 structure (~20 MB of workspace) ----
        long long avail = (long long)ws_size
                        - (long long)(inv_bytes + qh_bytes + ti_bytes);
        int ns2 = avail > 0 ? (int)(avail / (long long)per_sup_s) : 0;
        if (ns2 > 64) ns2 = 64;
        if (ns2 >= 1) {
            int tpbn = (NTILES + ns2 - 1) / ns2;
            ns2 = (NTILES + tpbn - 1) / tpbn;

            float*    invn    = (float*)d_ws;
            _Float16* Qh      = (_Float16*)((char*)d_ws + inv_bytes);
            int*      top_idx = (int*)((char*)d_ws + inv_bytes + qh_bytes);
            Cand*     cand    = (Cand*)((char*)d_ws + inv_bytes + qh_bytes + ti_bytes);

            hipLaunchKernelGGL(knn_qcvt_plain, dim3(QPAD * D_DIM / 2048), dim3(256), 0, stream,
                               Qm, Qh);
            hipLaunchKernelGGL(knn_norms, dim3((N_M + 3) / 4), dim3(256), 0, stream,
                               Mm, invn);
            hipLaunchKernelGGL(knn_gemm_select, dim3(QTILES * ns2), dim3(256), 0, stream,
                               Qh, Mm, invn, cand, tpbn, ns2);
            hipLaunchKernelGGL(knn_top16, dim3(T_Q), dim3(64), 0, stream,
                               cand, top_idx, ns2 * NC);
            hipLaunchKernelGGL(knn_rescore, dim3(T_Q), dim3(256), 0, stream,
                               Qm, Mm, Sm, topk, top_idx, outp);
            return;
        }
    }

    // ---- last resort: zero-workspace brute force ----
    hipLaunchKernelGGL(knn_all, dim3(T_Q), dim3(256), 0, stream,
                       Qm, Mm, Sm, topk, outp);
}